// Round 6
// baseline (4990.196 us; speedup 1.0000x reference)
//
#include <hip/hip_runtime.h>
#include <hip/hip_bf16.h>

// DeeperGCN on MI355X — round 6: LDS-free direct-global MFMA GEMM (B is L2-resident),
// parallel CSR scan. VN path fp32, node path bf16 storage + hi/lo W.
// N=150000, E=300000, G=4096, H=256, L=7.

#define Ncnt 150000
#define Ecnt 300000
#define Gcnt 4096
#define Hc 256
#define Lcnt 7
#define BN_EPS 1e-5f
#define MSG_EPS 1e-7f

typedef __hip_bfloat16 bf16;
typedef __attribute__((ext_vector_type(8))) short bf16x8;
typedef __attribute__((ext_vector_type(4))) float f32x4;

static __device__ __forceinline__ int imin(int a, int b) { return a < b ? a : b; }

static __device__ __forceinline__ float bs2f(unsigned short s) {
  unsigned u = ((unsigned)s) << 16;
  union { unsigned u; float f; } c; c.u = u; return c.f;
}
static __device__ __forceinline__ unsigned short f2bs(float f) {
  bf16 h = __float2bfloat16(f);
  union { bf16 h; unsigned short s; } c; c.h = h; return c.s;
}
static __device__ __forceinline__ float4 bf4tof4(ushort4 u) {
  float4 r; r.x = bs2f(u.x); r.y = bs2f(u.y); r.z = bs2f(u.z); r.w = bs2f(u.w); return r;
}
static __device__ __forceinline__ ushort4 f4tobf4(float4 v) {
  ushort4 u; u.x = f2bs(v.x); u.y = f2bs(v.y); u.z = f2bs(v.z); u.w = f2bs(v.w); return u;
}

__global__ __launch_bounds__(256) void k_zero(float* __restrict__ p, int n) {
  int i = blockIdx.x * 256 + threadIdx.x;
  if (i < n) p[i] = 0.f;
}
__global__ __launch_bounds__(256) void k_zero_int(int* __restrict__ p, int n) {
  int i = blockIdx.x * 256 + threadIdx.x;
  if (i < n) p[i] = 0;
}
__global__ __launch_bounds__(256) void k_copy(float* __restrict__ dst, const float* __restrict__ src, int n) {
  int i = blockIdx.x * 256 + threadIdx.x;
  if (i < n) dst[i] = src[i];
}
__global__ void k_diag(float* __restrict__ out, float v) { out[0] = v; }

// ---- CSR build (counting sort by dst) ----
__global__ __launch_bounds__(256) void k_count(const int* __restrict__ ei, int* __restrict__ cnt) {
  int e = blockIdx.x * 256 + threadIdx.x;
  if (e < Ecnt) atomicAdd(&cnt[ei[Ecnt + e]], 1);
}
// phase 1: per-block exclusive scan of 256 counts; rowptr gets local prefix; bsum gets block total
__global__ __launch_bounds__(256) void k_scan1(const int* __restrict__ cnt, int* __restrict__ rowptr,
                                               int* __restrict__ bsum, int n) {
  __shared__ int sh[256];
  int t = threadIdx.x;
  int i = blockIdx.x * 256 + t;
  int v = (i < n) ? cnt[i] : 0;
  sh[t] = v;
  __syncthreads();
#pragma unroll
  for (int off = 1; off < 256; off <<= 1) {
    int u = (t >= off) ? sh[t - off] : 0;
    __syncthreads();
    sh[t] += u;
    __syncthreads();
  }
  if (i < n) rowptr[i] = sh[t] - v;
  if (t == 255) bsum[blockIdx.x] = sh[255];
}
// phase 2: single block exclusive scan of block sums (nb <= 1024)
__global__ __launch_bounds__(1024) void k_scan2(int* __restrict__ bsum, int nb) {
  __shared__ int sh[1024];
  int t = threadIdx.x;
  int v = (t < nb) ? bsum[t] : 0;
  sh[t] = v;
  __syncthreads();
#pragma unroll
  for (int off = 1; off < 1024; off <<= 1) {
    int u = (t >= off) ? sh[t - off] : 0;
    __syncthreads();
    sh[t] += u;
    __syncthreads();
  }
  if (t < nb) bsum[t] = sh[t] - v;
}
// phase 3: add block offsets; mirror to cursor; set rowptr[N]=E
__global__ __launch_bounds__(256) void k_scan3(int* __restrict__ rowptr, int* __restrict__ cursor,
                                               const int* __restrict__ bsum, int n) {
  int i = blockIdx.x * 256 + threadIdx.x;
  if (i < n) {
    int v = rowptr[i] + bsum[blockIdx.x];
    rowptr[i] = v;
    cursor[i] = v;
  }
  if (i == 0) rowptr[n] = Ecnt;
}
__global__ __launch_bounds__(256) void k_scatter(const int* __restrict__ ei, int* __restrict__ cursor,
                                                 int* __restrict__ eidx) {
  int e = blockIdx.x * 256 + threadIdx.x;
  if (e < Ecnt) {
    int d = ei[Ecnt + e];
    int pos = atomicAdd(&cursor[d], 1);
    eidx[pos] = e;
  }
}

// ---- weight prep: conv W[k][n] fp32 -> transposed bf16 hi/lo Wt[n][k] ----
__global__ __launch_bounds__(256) void k_prep_w(const float* __restrict__ W, bf16* __restrict__ hi,
                                                bf16* __restrict__ lo, int nmats) {
  int idx = blockIdx.x * 256 + threadIdx.x;
  if (idx >= nmats * 65536) return;
  int m = idx >> 16;
  int r = idx & 65535;
  int n = r >> 8, k = r & 255;
  float w = W[(size_t)m * 65536 + (size_t)k * 256 + n];
  bf16 h = __float2bfloat16(w);
  float res = w - __bfloat162float(h);
  hi[idx] = h;
  lo[idx] = __float2bfloat16(res);
}

// ---- encoders (1 wave per node, 4 ch/lane) ----
__global__ __launch_bounds__(256) void k_atom_encode(const int* __restrict__ x,
                                                     const float* __restrict__ aemb,
                                                     const float* __restrict__ vnw,
                                                     bf16* __restrict__ P) {
  int wave = threadIdx.x >> 6, lane = threadIdx.x & 63;
  int r = blockIdx.x * 4 + wave;
  if (r >= Ncnt) return;
  int c4 = lane * 4;
  const int* xr = x + (size_t)r * 9;
  float4 v = *(const float4*)&vnw[c4];
#pragma unroll
  for (int f = 0; f < 9; ++f) {
    float4 e = *(const float4*)&aemb[(size_t)((f << 6) + xr[f]) * Hc + c4];
    v.x += e.x; v.y += e.y; v.z += e.z; v.w += e.w;
  }
  *(ushort4*)&P[(size_t)r * Hc + c4] = f4tobf4(v);
}

__global__ __launch_bounds__(256) void k_init_vn(float* __restrict__ vn, const float* __restrict__ vnw) {
  int idx = blockIdx.x * 256 + threadIdx.x;  // G*Hc total
  vn[idx] = vnw[idx & (Hc - 1)];
}

// ---- aggregation: T[r] = h2(r) + sum_{e: dst=r} (relu(h2(src)+bond_emb)+eps)
// h2(n) = P[n] (stats==null) or relu(bn(P[n]))+vn[batch[n]].  1 wave/node.
__global__ __launch_bounds__(256) void k_agg(const bf16* __restrict__ P, bf16* __restrict__ T,
                                             const int* __restrict__ rowptr, const int* __restrict__ eidx,
                                             const int* __restrict__ ei, const int* __restrict__ ea,
                                             const float* __restrict__ bemb,
                                             const float* __restrict__ vn, const int* __restrict__ batch,
                                             const float* __restrict__ stats,
                                             const float* __restrict__ gamma, const float* __restrict__ beta,
                                             float invM) {
  int wave = threadIdx.x >> 6, lane = threadIdx.x & 63;
  int r = blockIdx.x * 4 + wave;
  if (r >= Ncnt) return;
  int c4 = lane * 4;
  bool hasbn = (stats != nullptr);
  float4 scv = make_float4(1.f, 1.f, 1.f, 1.f), bbv = make_float4(0.f, 0.f, 0.f, 0.f);
  if (hasbn) {
    float4 sv = *(const float4*)&stats[c4];
    float4 qv = *(const float4*)&stats[Hc + c4];
    float4 gv = *(const float4*)&gamma[c4];
    float4 bv = *(const float4*)&beta[c4];
    float mu, var;
    mu = sv.x * invM; var = qv.x * invM - mu * mu; scv.x = rsqrtf(var + BN_EPS) * gv.x; bbv.x = bv.x - mu * scv.x;
    mu = sv.y * invM; var = qv.y * invM - mu * mu; scv.y = rsqrtf(var + BN_EPS) * gv.y; bbv.y = bv.y - mu * scv.y;
    mu = sv.z * invM; var = qv.z * invM - mu * mu; scv.z = rsqrtf(var + BN_EPS) * gv.z; bbv.z = bv.z - mu * scv.z;
    mu = sv.w * invM; var = qv.w * invM - mu * mu; scv.w = rsqrtf(var + BN_EPS) * gv.w; bbv.w = bv.w - mu * scv.w;
  }
  float4 acc;
  {
    float4 v = bf4tof4(*(const ushort4*)&P[(size_t)r * Hc + c4]);
    if (hasbn) {
      v.x = fmaxf(fmaf(v.x, scv.x, bbv.x), 0.f); v.y = fmaxf(fmaf(v.y, scv.y, bbv.y), 0.f);
      v.z = fmaxf(fmaf(v.z, scv.z, bbv.z), 0.f); v.w = fmaxf(fmaf(v.w, scv.w, bbv.w), 0.f);
      const float4 w = *(const float4*)&vn[(size_t)batch[r] * Hc + c4];
      v.x += w.x; v.y += w.y; v.z += w.z; v.w += w.w;
    }
    acc = v;
  }
  int j1 = rowptr[r + 1];
  for (int j = rowptr[r]; j < j1; ++j) {
    int e = eidx[j];
    int s = ei[e];
    int a0 = ea[e * 3], a1 = ea[e * 3 + 1], a2 = ea[e * 3 + 2];
    float4 em = *(const float4*)&bemb[(size_t)a0 * Hc + c4];
    float4 e1 = *(const float4*)&bemb[(size_t)(8 + a1) * Hc + c4];
    float4 e2 = *(const float4*)&bemb[(size_t)(16 + a2) * Hc + c4];
    em.x += e1.x + e2.x; em.y += e1.y + e2.y; em.z += e1.z + e2.z; em.w += e1.w + e2.w;
    float4 v = bf4tof4(*(const ushort4*)&P[(size_t)s * Hc + c4]);
    if (hasbn) {
      v.x = fmaxf(fmaf(v.x, scv.x, bbv.x), 0.f); v.y = fmaxf(fmaf(v.y, scv.y, bbv.y), 0.f);
      v.z = fmaxf(fmaf(v.z, scv.z, bbv.z), 0.f); v.w = fmaxf(fmaf(v.w, scv.w, bbv.w), 0.f);
      const float4 w = *(const float4*)&vn[(size_t)batch[s] * Hc + c4];
      v.x += w.x; v.y += w.y; v.z += w.z; v.w += w.w;
    }
    acc.x += fmaxf(v.x + em.x, 0.f) + MSG_EPS;
    acc.y += fmaxf(v.y + em.y, 0.f) + MSG_EPS;
    acc.z += fmaxf(v.z + em.z, 0.f) + MSG_EPS;
    acc.w += fmaxf(v.w + em.w, 0.f) + MSG_EPS;
  }
  *(ushort4*)&T[(size_t)r * Hc + c4] = f4tobf4(acc);
}

// ---- segment-sum of relu(bn(P)) by sorted batch into vnt (pre-init with vn). 1 wave / 64 rows.
__global__ __launch_bounds__(256) void k_seg_vn(const bf16* __restrict__ P, const int* __restrict__ batch,
                                                float* __restrict__ vnt, const float* __restrict__ stats,
                                                const float* __restrict__ gamma, const float* __restrict__ beta,
                                                float invM) {
  int wave = threadIdx.x >> 6, lane = threadIdx.x & 63;
  int base = (blockIdx.x * 4 + wave) * 64;
  if (base >= Ncnt) return;
  int c4 = lane * 4;
  float4 sv = *(const float4*)&stats[c4];
  float4 qv = *(const float4*)&stats[Hc + c4];
  float4 gv = *(const float4*)&gamma[c4];
  float4 bv = *(const float4*)&beta[c4];
  float4 scv, bbv;
  float mu, var;
  mu = sv.x * invM; var = qv.x * invM - mu * mu; scv.x = rsqrtf(var + BN_EPS) * gv.x; bbv.x = bv.x - mu * scv.x;
  mu = sv.y * invM; var = qv.y * invM - mu * mu; scv.y = rsqrtf(var + BN_EPS) * gv.y; bbv.y = bv.y - mu * scv.y;
  mu = sv.z * invM; var = qv.z * invM - mu * mu; scv.z = rsqrtf(var + BN_EPS) * gv.z; bbv.z = bv.z - mu * scv.z;
  mu = sv.w * invM; var = qv.w * invM - mu * mu; scv.w = rsqrtf(var + BN_EPS) * gv.w; bbv.w = bv.w - mu * scv.w;
  int end = imin(base + 64, Ncnt);
  float4 acc = make_float4(0.f, 0.f, 0.f, 0.f);
  int curg = batch[base];
  for (int r = base; r < end; ++r) {
    int g = batch[r];
    float4 v = bf4tof4(*(const ushort4*)&P[(size_t)r * Hc + c4]);
    v.x = fmaxf(fmaf(v.x, scv.x, bbv.x), 0.f); v.y = fmaxf(fmaf(v.y, scv.y, bbv.y), 0.f);
    v.z = fmaxf(fmaf(v.z, scv.z, bbv.z), 0.f); v.w = fmaxf(fmaf(v.w, scv.w, bbv.w), 0.f);
    if (g != curg) {
      float* d = &vnt[(size_t)curg * Hc + c4];
      atomicAdd(d, acc.x); atomicAdd(d + 1, acc.y); atomicAdd(d + 2, acc.z); atomicAdd(d + 3, acc.w);
      acc = make_float4(0.f, 0.f, 0.f, 0.f);
      curg = g;
    }
    acc.x += v.x; acc.y += v.y; acc.z += v.z; acc.w += v.w;
  }
  float* d = &vnt[(size_t)curg * Hc + c4];
  atomicAdd(d, acc.x); atomicAdd(d + 1, acc.y); atomicAdd(d + 2, acc.z); atomicAdd(d + 3, acc.w);
}

// ---- BN stats over fp32 rows (VN path; stats pre-zeroed) ----
__global__ __launch_bounds__(256) void k_bn_stats_f(const float* __restrict__ h, float* __restrict__ stats, int M) {
  int c = threadIdx.x;
  int r0 = blockIdx.x * 256;
  if (r0 >= M) return;
  int r1 = imin(r0 + 256, M);
  float s = 0.f, q = 0.f;
  for (int r = r0; r < r1; ++r) {
    float v = h[(size_t)r * Hc + c];
    s += v;
    q = fmaf(v, v, q);
  }
  atomicAdd(&stats[c], s);
  atomicAdd(&stats[Hc + c], q);
}

// ---- VN elementwise relu(bn(.)) fp32->fp32 ----
__global__ __launch_bounds__(256) void k_vn_relu(const float* __restrict__ in, float* __restrict__ out,
                                                 const float* __restrict__ stats,
                                                 const float* __restrict__ gamma, const float* __restrict__ beta,
                                                 float invM) {
  int idx = blockIdx.x * 256 + threadIdx.x;
  int c = idx & (Hc - 1);
  float mu = stats[c] * invM;
  float var = stats[Hc + c] * invM - mu * mu;
  float sc = rsqrtf(var + BN_EPS) * gamma[c];
  float bb = beta[c] - mu * sc;
  out[idx] = fmaxf(fmaf(in[idx], sc, bb), 0.f);
}

// ---- final bn + global_add_pool (out pre-zeroed). 1 wave / 64 rows.
__global__ __launch_bounds__(256) void k_bn_pool(const bf16* __restrict__ P, const int* __restrict__ batch,
                                                 float* __restrict__ out, const float* __restrict__ stats,
                                                 const float* __restrict__ gamma, const float* __restrict__ beta,
                                                 float invM) {
  int wave = threadIdx.x >> 6, lane = threadIdx.x & 63;
  int base = (blockIdx.x * 4 + wave) * 64;
  if (base >= Ncnt) return;
  int c4 = lane * 4;
  float4 sv = *(const float4*)&stats[c4];
  float4 qv = *(const float4*)&stats[Hc + c4];
  float4 gv = *(const float4*)&gamma[c4];
  float4 bv = *(const float4*)&beta[c4];
  float4 scv, bbv;
  float mu, var;
  mu = sv.x * invM; var = qv.x * invM - mu * mu; scv.x = rsqrtf(var + BN_EPS) * gv.x; bbv.x = bv.x - mu * scv.x;
  mu = sv.y * invM; var = qv.y * invM - mu * mu; scv.y = rsqrtf(var + BN_EPS) * gv.y; bbv.y = bv.y - mu * scv.y;
  mu = sv.z * invM; var = qv.z * invM - mu * mu; scv.z = rsqrtf(var + BN_EPS) * gv.z; bbv.z = bv.z - mu * scv.z;
  mu = sv.w * invM; var = qv.w * invM - mu * mu; scv.w = rsqrtf(var + BN_EPS) * gv.w; bbv.w = bv.w - mu * scv.w;
  int end = imin(base + 64, Ncnt);
  float4 acc = make_float4(0.f, 0.f, 0.f, 0.f);
  int curg = batch[base];
  for (int r = base; r < end; ++r) {
    int g = batch[r];
    float4 v = bf4tof4(*(const ushort4*)&P[(size_t)r * Hc + c4]);
    v.x = fmaf(v.x, scv.x, bbv.x); v.y = fmaf(v.y, scv.y, bbv.y);
    v.z = fmaf(v.z, scv.z, bbv.z); v.w = fmaf(v.w, scv.w, bbv.w);
    if (g != curg) {
      float* d = &out[(size_t)curg * Hc + c4];
      atomicAdd(d, acc.x); atomicAdd(d + 1, acc.y); atomicAdd(d + 2, acc.z); atomicAdd(d + 3, acc.w);
      acc = make_float4(0.f, 0.f, 0.f, 0.f);
      curg = g;
    }
    acc.x += v.x; acc.y += v.y; acc.z += v.z; acc.w += v.w;
  }
  float* d = &out[(size_t)curg * Hc + c4];
  atomicAdd(d, acc.x); atomicAdd(d + 1, acc.y); atomicAdd(d + 2, acc.z); atomicAdd(d + 3, acc.w);
}

// ---- LDS-free MFMA node GEMM: C[M,256] = A @ (Whi+Wlo) + bias (+R), fused BN-stats.
// Wt layout [n][k] bf16. Block = 128 rows x 128 cols, 4 waves x (32 rows x 128 cols).
// A and B fragments loaded straight from global (B is 128 KB, L2-resident; no LDS, no barriers).
__global__ __launch_bounds__(256) void k_gemm_mfma(const bf16* __restrict__ A, const bf16* __restrict__ Whi,
                                                   const bf16* __restrict__ Wlo, const float* __restrict__ bias,
                                                   const bf16* __restrict__ R, bf16* __restrict__ C,
                                                   float* __restrict__ stats, int M) {
  int tid = threadIdx.x;
  int wave = tid >> 6, lane = tid & 63;
  int quad = lane >> 4, l15 = lane & 15;
  int row0 = blockIdx.x * 128 + wave * 32;
  int n0 = blockIdx.y * 128;

  const bf16* aptr[2];
#pragma unroll
  for (int mi = 0; mi < 2; ++mi) {
    int r = row0 + mi * 16 + l15;
    if (r > M - 1) r = M - 1;  // clamp: OOB rows compute garbage that is never stored
    aptr[mi] = A + (size_t)r * Hc + quad * 8;
  }
  const bf16* bh0 = Whi + (size_t)(n0 + l15) * Hc + quad * 8;
  const bf16* bl0 = Wlo + (size_t)(n0 + l15) * Hc + quad * 8;

  f32x4 acc[2][8];
#pragma unroll
  for (int mi = 0; mi < 2; ++mi)
#pragma unroll
    for (int ni = 0; ni < 8; ++ni) acc[mi][ni] = (f32x4){0.f, 0.f, 0.f, 0.f};

#pragma unroll
  for (int kk = 0; kk < 256; kk += 32) {
    bf16x8 a0 = *(const bf16x8*)(aptr[0] + kk);
    bf16x8 a1 = *(const bf16x8*)(aptr[1] + kk);
#pragma unroll
    for (int ni = 0; ni < 8; ++ni) {
      bf16x8 bh = *(const bf16x8*)(bh0 + (size_t)ni * 16 * Hc + kk);
      bf16x8 bl = *(const bf16x8*)(bl0 + (size_t)ni * 16 * Hc + kk);
      acc[0][ni] = __builtin_amdgcn_mfma_f32_16x16x32_bf16(a0, bh, acc[0][ni], 0, 0, 0);
      acc[1][ni] = __builtin_amdgcn_mfma_f32_16x16x32_bf16(a1, bh, acc[1][ni], 0, 0, 0);
      acc[0][ni] = __builtin_amdgcn_mfma_f32_16x16x32_bf16(a0, bl, acc[0][ni], 0, 0, 0);
      acc[1][ni] = __builtin_amdgcn_mfma_f32_16x16x32_bf16(a1, bl, acc[1][ni], 0, 0, 0);
    }
  }

#pragma unroll
  for (int ni = 0; ni < 8; ++ni) {
    int col = n0 + ni * 16 + l15;
    float bcol = bias[col];
    float ssum = 0.f, ssq = 0.f;
#pragma unroll
    for (int mi = 0; mi < 2; ++mi) {
#pragma unroll
      for (int j = 0; j < 4; ++j) {
        int row = row0 + mi * 16 + quad * 4 + j;
        if (row < M) {
          float v = acc[mi][ni][j] + bcol;
          if (R) v += __bfloat162float(R[(size_t)row * Hc + col]);
          C[(size_t)row * Hc + col] = __float2bfloat16(v);
          ssum += v;
          ssq = fmaf(v, v, ssq);
        }
      }
    }
    ssum += __shfl_xor(ssum, 16); ssum += __shfl_xor(ssum, 32);
    ssq += __shfl_xor(ssq, 16); ssq += __shfl_xor(ssq, 32);
    if (quad == 0) {
      atomicAdd(&stats[col], ssum);
      atomicAdd(&stats[Hc + col], ssq);
    }
  }
}

// ---- fp32 SIMT GEMM for the VN MLP: C[M,256] = A @ W + bias. 64x64 tile. ----
__global__ __launch_bounds__(256) void k_gemm_f32(const float* __restrict__ A, const float* __restrict__ W,
                                                  const float* __restrict__ bias, float* __restrict__ C, int M) {
  __shared__ float As[64][68];
  __shared__ float Ws[64][68];
  int tid = threadIdx.x;
  int row0 = blockIdx.x * 64;
  int col0 = blockIdx.y * 64;
  int tx = tid & 15, ty = tid >> 4;
  float acc[4][4] = {{0.f}};
  for (int k0 = 0; k0 < 256; k0 += 64) {
#pragma unroll
    for (int i = 0; i < 4; ++i) {
      int lin = tid + i * 256;
      int r = lin >> 4;
      int c4 = (lin & 15) << 2;
      int gr = row0 + r;
      float4 v = make_float4(0.f, 0.f, 0.f, 0.f);
      if (gr < M) v = *(const float4*)&A[(size_t)gr * Hc + k0 + c4];
      As[r][c4] = v.x; As[r][c4 + 1] = v.y; As[r][c4 + 2] = v.z; As[r][c4 + 3] = v.w;
      float4 w = *(const float4*)&W[(size_t)(k0 + r) * Hc + col0 + c4];
      Ws[r][c4] = w.x; Ws[r][c4 + 1] = w.y; Ws[r][c4 + 2] = w.z; Ws[r][c4 + 3] = w.w;
    }
    __syncthreads();
#pragma unroll
    for (int k = 0; k < 64; ++k) {
      float a[4], w[4];
#pragma unroll
      for (int i = 0; i < 4; ++i) a[i] = As[ty * 4 + i][k];
#pragma unroll
      for (int j = 0; j < 4; ++j) w[j] = Ws[k][tx * 4 + j];
#pragma unroll
      for (int i = 0; i < 4; ++i)
#pragma unroll
        for (int j = 0; j < 4; ++j) acc[i][j] = fmaf(a[i], w[j], acc[i][j]);
    }
    __syncthreads();
  }
#pragma unroll
  for (int i = 0; i < 4; ++i) {
    int gr = row0 + ty * 4 + i;
    if (gr >= M) break;
#pragma unroll
    for (int j = 0; j < 4; ++j) {
      int gc = col0 + tx * 4 + j;
      C[(size_t)gr * Hc + gc] = acc[i][j] + bias[gc];
    }
  }
}

extern "C" void kernel_launch(void* const* d_in, const int* in_sizes, int n_in,
                              void* d_out, int out_size, void* d_ws, size_t ws_size,
                              hipStream_t stream) {
  const int* x = (const int*)d_in[0];
  const int* ei = (const int*)d_in[1];
  const int* ea = (const int*)d_in[2];
  const int* batch = (const int*)d_in[3];
  const float* aemb = (const float*)d_in[4];
  const float* bemb = (const float*)d_in[5];
  const float* vnw = (const float*)d_in[6];
  const float* conv_w = (const float*)d_in[7];
  const float* conv_b = (const float*)d_in[8];
  const float* ngamma = (const float*)d_in[9];
  const float* nbeta = (const float*)d_in[10];
  const float* vn_w = (const float*)d_in[11];
  const float* vn_b = (const float*)d_in[12];
  const float* vn_g = (const float*)d_in[13];
  const float* vn_be = (const float*)d_in[14];
  float* out = (float*)d_out;

  const size_t NODE = (size_t)Ncnt * Hc;
  const size_t GH = (size_t)Gcnt * Hc;
  const int nScanBlk = (Ncnt + 255) / 256;  // 586

  size_t off = 0;
  char* base = (char*)d_ws;
  auto take = [&](size_t bytes) { size_t o = off; off += (bytes + 15) & ~(size_t)15; return o; };
  float* vn = (float*)(base + take(GH * 4));
  float* vnt = (float*)(base + take(GH * 4));
  float* vnu = (float*)(base + take(GH * 4));
  float* vnv = (float*)(base + take(GH * 4));
  float* statsN = (float*)(base + take(2 * Hc * 4));
  float* statsV = (float*)(base + take(2 * Hc * 4));
  int* rowptr = (int*)(base + take((size_t)(Ncnt + 1) * 4));
  int* cursor = (int*)(base + take((size_t)Ncnt * 4));
  int* eidx = (int*)(base + take((size_t)Ecnt * 4));
  int* bsum = (int*)(base + take((size_t)nScanBlk * 4));
  bf16* P = (bf16*)(base + take(NODE * 2));
  bf16* T = (bf16*)(base + take(NODE * 2));
  bf16* WhiC = (bf16*)(base + take((size_t)Lcnt * 65536 * 2));
  bf16* WloC = (bf16*)(base + take((size_t)Lcnt * 65536 * 2));
  const size_t NEED = off;
  if (ws_size < NEED) {
    k_zero<<<(int)((GH + 255) / 256), 256, 0, stream>>>(out, (int)GH);
    k_diag<<<1, 1, 0, stream>>>(out, 100000.f + (float)(ws_size / (1024.0 * 1024.0)));
    return;
  }

  const int eBlk = (Ecnt + 255) / 256;
  const int nWaveBlk = (Ncnt + 3) / 4;
  const int segBlk = (Ncnt + 255) / 256;
  const int gBlk256 = (Gcnt + 255) / 256;
  const dim3 ggN((Ncnt + 127) / 128, 2);
  const dim3 gv(Gcnt / 64, 4);
  const float invN = 1.f / Ncnt;
  const float invG = 1.f / Gcnt;

  // CSR build (parallel scan)
  k_zero_int<<<nScanBlk, 256, 0, stream>>>(cursor, Ncnt);
  k_count<<<eBlk, 256, 0, stream>>>(ei, cursor);
  k_scan1<<<nScanBlk, 256, 0, stream>>>(cursor, rowptr, bsum, Ncnt);
  k_scan2<<<1, 1024, 0, stream>>>(bsum, nScanBlk);
  k_scan3<<<nScanBlk, 256, 0, stream>>>(rowptr, cursor, bsum, Ncnt);
  k_scatter<<<eBlk, 256, 0, stream>>>(ei, cursor, eidx);

  // conv weight prep (hi/lo, transposed)
  k_prep_w<<<(Lcnt * 65536 + 255) / 256, 256, 0, stream>>>(conv_w, WhiC, WloC, Lcnt);

  // Encoders + conv0 (stats fused for layer-1 BN)
  k_atom_encode<<<nWaveBlk, 256, 0, stream>>>(x, aemb, vnw, P);
  k_init_vn<<<(int)(GH / 256), 256, 0, stream>>>(vn, vnw);
  k_agg<<<nWaveBlk, 256, 0, stream>>>(P, T, rowptr, eidx, ei, ea, bemb,
                                      nullptr, nullptr, nullptr, nullptr, nullptr, 0.f);
  k_zero<<<2, 256, 0, stream>>>(statsN, 2 * Hc);
  k_gemm_mfma<<<ggN, 256, 0, stream>>>(T, WhiC, WloC, conv_b, nullptr, P, statsN, Ncnt);

  for (int l = 1; l < Lcnt; ++l) {
    int p = l - 1;
    const float* g = ngamma + (size_t)p * Hc;
    const float* b = nbeta + (size_t)p * Hc;
    // vn_t = vn + segsum(relu(bn(P)))
    k_copy<<<(int)(GH / 256), 256, 0, stream>>>(vnt, vn, (int)GH);
    k_seg_vn<<<segBlk, 256, 0, stream>>>(P, batch, vnt, statsN, g, b, invN);
    // VN MLP j=0 (fp32 SIMT)
    k_gemm_f32<<<gv, 256, 0, stream>>>(vnt, vn_w + (size_t)(2 * p) * 65536,
                                       vn_b + (size_t)(2 * p) * Hc, vnu, Gcnt);
    k_zero<<<2, 256, 0, stream>>>(statsV, 2 * Hc);
    k_bn_stats_f<<<gBlk256, 256, 0, stream>>>(vnu, statsV, Gcnt);
    k_vn_relu<<<(int)(GH / 256), 256, 0, stream>>>(vnu, vnv, statsV,
                                                   vn_g + (size_t)(2 * p) * Hc,
                                                   vn_be + (size_t)(2 * p) * Hc, invG);
    // VN MLP j=1 -> vn
    k_gemm_f32<<<gv, 256, 0, stream>>>(vnv, vn_w + (size_t)(2 * p + 1) * 65536,
                                       vn_b + (size_t)(2 * p + 1) * Hc, vnu, Gcnt);
    k_zero<<<2, 256, 0, stream>>>(statsV, 2 * Hc);
    k_bn_stats_f<<<gBlk256, 256, 0, stream>>>(vnu, statsV, Gcnt);
    k_vn_relu<<<(int)(GH / 256), 256, 0, stream>>>(vnu, vn, statsV,
                                                   vn_g + (size_t)(2 * p + 1) * Hc,
                                                   vn_be + (size_t)(2 * p + 1) * Hc, invG);
    // T = h2 + agg(h2), h2 = relu(bn(P)) + vn[batch]
    k_agg<<<nWaveBlk, 256, 0, stream>>>(P, T, rowptr, eidx, ei, ea, bemb, vn, batch, statsN, g, b, invN);
    // P = T @ W + bias + P (stats fused for next BN)
    k_zero<<<2, 256, 0, stream>>>(statsN, 2 * Hc);
    k_gemm_mfma<<<ggN, 256, 0, stream>>>(T, WhiC + (size_t)l * 65536, WloC + (size_t)l * 65536,
                                         conv_b + (size_t)l * Hc, P, P, statsN, Ncnt);
  }

  // Final BN + global add pool
  k_zero<<<(int)((GH + 255) / 256), 256, 0, stream>>>(out, (int)GH);
  k_bn_pool<<<segBlk, 256, 0, stream>>>(P, batch, out, statsN,
                                        ngamma + (size_t)(Lcnt - 1) * Hc, nbeta + (size_t)(Lcnt - 1) * Hc,
                                        invN);
}

// Round 7
// 3867.685 us; speedup vs baseline: 1.2902x; 1.2902x over previous
//
#include <hip/hip_runtime.h>
#include <hip/hip_bf16.h>

// DeeperGCN on MI355X — round 7: m97-style MFMA GEMM (global_load_lds width16 +
// XOR-swizzled LDS, 128x128 tile, BK=64). VN path fp32, node path bf16 + hi/lo W.
// N=150000, E=300000, G=4096, H=256, L=7.

#define Ncnt 150000
#define Ecnt 300000
#define Gcnt 4096
#define Hc 256
#define Lcnt 7
#define BN_EPS 1e-5f
#define MSG_EPS 1e-7f

typedef __hip_bfloat16 bf16;
typedef __attribute__((ext_vector_type(8))) short bf16x8;
typedef __attribute__((ext_vector_type(4))) float f32x4;

static __device__ __forceinline__ int imin(int a, int b) { return a < b ? a : b; }

static __device__ __forceinline__ float bs2f(unsigned short s) {
  unsigned u = ((unsigned)s) << 16;
  union { unsigned u; float f; } c; c.u = u; return c.f;
}
static __device__ __forceinline__ unsigned short f2bs(float f) {
  bf16 h = __float2bfloat16(f);
  union { bf16 h; unsigned short s; } c; c.h = h; return c.s;
}
static __device__ __forceinline__ float4 bf4tof4(ushort4 u) {
  float4 r; r.x = bs2f(u.x); r.y = bs2f(u.y); r.z = bs2f(u.z); r.w = bs2f(u.w); return r;
}
static __device__ __forceinline__ ushort4 f4tobf4(float4 v) {
  ushort4 u; u.x = f2bs(v.x); u.y = f2bs(v.y); u.z = f2bs(v.z); u.w = f2bs(v.w); return u;
}

// async global->LDS, 16B per lane; lds dst must be the wave-uniform chunk base.
static __device__ __forceinline__ void gll16(const bf16* g, const short* l) {
  __builtin_amdgcn_global_load_lds((const __attribute__((address_space(1))) void*)g,
                                   (__attribute__((address_space(3))) void*)l, 16, 0, 0);
}

__global__ __launch_bounds__(256) void k_zero(float* __restrict__ p, int n) {
  int i = blockIdx.x * 256 + threadIdx.x;
  if (i < n) p[i] = 0.f;
}
__global__ __launch_bounds__(256) void k_zero_int(int* __restrict__ p, int n) {
  int i = blockIdx.x * 256 + threadIdx.x;
  if (i < n) p[i] = 0;
}
__global__ __launch_bounds__(256) void k_copy(float* __restrict__ dst, const float* __restrict__ src, int n) {
  int i = blockIdx.x * 256 + threadIdx.x;
  if (i < n) dst[i] = src[i];
}
__global__ void k_diag(float* __restrict__ out, float v) { out[0] = v; }

// ---- CSR build (counting sort by dst) ----
__global__ __launch_bounds__(256) void k_count(const int* __restrict__ ei, int* __restrict__ cnt) {
  int e = blockIdx.x * 256 + threadIdx.x;
  if (e < Ecnt) atomicAdd(&cnt[ei[Ecnt + e]], 1);
}
__global__ __launch_bounds__(256) void k_scan1(const int* __restrict__ cnt, int* __restrict__ rowptr,
                                               int* __restrict__ bsum, int n) {
  __shared__ int sh[256];
  int t = threadIdx.x;
  int i = blockIdx.x * 256 + t;
  int v = (i < n) ? cnt[i] : 0;
  sh[t] = v;
  __syncthreads();
#pragma unroll
  for (int off = 1; off < 256; off <<= 1) {
    int u = (t >= off) ? sh[t - off] : 0;
    __syncthreads();
    sh[t] += u;
    __syncthreads();
  }
  if (i < n) rowptr[i] = sh[t] - v;
  if (t == 255) bsum[blockIdx.x] = sh[255];
}
__global__ __launch_bounds__(1024) void k_scan2(int* __restrict__ bsum, int nb) {
  __shared__ int sh[1024];
  int t = threadIdx.x;
  int v = (t < nb) ? bsum[t] : 0;
  sh[t] = v;
  __syncthreads();
#pragma unroll
  for (int off = 1; off < 1024; off <<= 1) {
    int u = (t >= off) ? sh[t - off] : 0;
    __syncthreads();
    sh[t] += u;
    __syncthreads();
  }
  if (t < nb) bsum[t] = sh[t] - v;
}
__global__ __launch_bounds__(256) void k_scan3(int* __restrict__ rowptr, int* __restrict__ cursor,
                                               const int* __restrict__ bsum, int n) {
  int i = blockIdx.x * 256 + threadIdx.x;
  if (i < n) {
    int v = rowptr[i] + bsum[blockIdx.x];
    rowptr[i] = v;
    cursor[i] = v;
  }
  if (i == 0) rowptr[n] = Ecnt;
}
__global__ __launch_bounds__(256) void k_scatter(const int* __restrict__ ei, int* __restrict__ cursor,
                                                 int* __restrict__ eidx) {
  int e = blockIdx.x * 256 + threadIdx.x;
  if (e < Ecnt) {
    int d = ei[Ecnt + e];
    int pos = atomicAdd(&cursor[d], 1);
    eidx[pos] = e;
  }
}

// ---- weight prep: conv W[k][n] fp32 -> transposed bf16 hi/lo Wt[n][k] ----
__global__ __launch_bounds__(256) void k_prep_w(const float* __restrict__ W, bf16* __restrict__ hi,
                                                bf16* __restrict__ lo, int nmats) {
  int idx = blockIdx.x * 256 + threadIdx.x;
  if (idx >= nmats * 65536) return;
  int m = idx >> 16;
  int r = idx & 65535;
  int n = r >> 8, k = r & 255;
  float w = W[(size_t)m * 65536 + (size_t)k * 256 + n];
  bf16 h = __float2bfloat16(w);
  float res = w - __bfloat162float(h);
  hi[idx] = h;
  lo[idx] = __float2bfloat16(res);
}

// ---- encoders (1 wave per node, 4 ch/lane) ----
__global__ __launch_bounds__(256) void k_atom_encode(const int* __restrict__ x,
                                                     const float* __restrict__ aemb,
                                                     const float* __restrict__ vnw,
                                                     bf16* __restrict__ P) {
  int wave = threadIdx.x >> 6, lane = threadIdx.x & 63;
  int r = blockIdx.x * 4 + wave;
  if (r >= Ncnt) return;
  int c4 = lane * 4;
  const int* xr = x + (size_t)r * 9;
  float4 v = *(const float4*)&vnw[c4];
#pragma unroll
  for (int f = 0; f < 9; ++f) {
    float4 e = *(const float4*)&aemb[(size_t)((f << 6) + xr[f]) * Hc + c4];
    v.x += e.x; v.y += e.y; v.z += e.z; v.w += e.w;
  }
  *(ushort4*)&P[(size_t)r * Hc + c4] = f4tobf4(v);
}

__global__ __launch_bounds__(256) void k_init_vn(float* __restrict__ vn, const float* __restrict__ vnw) {
  int idx = blockIdx.x * 256 + threadIdx.x;  // G*Hc total
  vn[idx] = vnw[idx & (Hc - 1)];
}

// ---- aggregation: T[r] = h2(r) + sum_{e: dst=r} (relu(h2(src)+bond_emb)+eps)
// h2(n) = P[n] (stats==null) or relu(bn(P[n]))+vn[batch[n]].  1 wave/node.
__global__ __launch_bounds__(256) void k_agg(const bf16* __restrict__ P, bf16* __restrict__ T,
                                             const int* __restrict__ rowptr, const int* __restrict__ eidx,
                                             const int* __restrict__ ei, const int* __restrict__ ea,
                                             const float* __restrict__ bemb,
                                             const float* __restrict__ vn, const int* __restrict__ batch,
                                             const float* __restrict__ stats,
                                             const float* __restrict__ gamma, const float* __restrict__ beta,
                                             float invM) {
  int wave = threadIdx.x >> 6, lane = threadIdx.x & 63;
  int r = blockIdx.x * 4 + wave;
  if (r >= Ncnt) return;
  int c4 = lane * 4;
  bool hasbn = (stats != nullptr);
  float4 scv = make_float4(1.f, 1.f, 1.f, 1.f), bbv = make_float4(0.f, 0.f, 0.f, 0.f);
  if (hasbn) {
    float4 sv = *(const float4*)&stats[c4];
    float4 qv = *(const float4*)&stats[Hc + c4];
    float4 gv = *(const float4*)&gamma[c4];
    float4 bv = *(const float4*)&beta[c4];
    float mu, var;
    mu = sv.x * invM; var = qv.x * invM - mu * mu; scv.x = rsqrtf(var + BN_EPS) * gv.x; bbv.x = bv.x - mu * scv.x;
    mu = sv.y * invM; var = qv.y * invM - mu * mu; scv.y = rsqrtf(var + BN_EPS) * gv.y; bbv.y = bv.y - mu * scv.y;
    mu = sv.z * invM; var = qv.z * invM - mu * mu; scv.z = rsqrtf(var + BN_EPS) * gv.z; bbv.z = bv.z - mu * scv.z;
    mu = sv.w * invM; var = qv.w * invM - mu * mu; scv.w = rsqrtf(var + BN_EPS) * gv.w; bbv.w = bv.w - mu * scv.w;
  }
  float4 acc;
  {
    float4 v = bf4tof4(*(const ushort4*)&P[(size_t)r * Hc + c4]);
    if (hasbn) {
      v.x = fmaxf(fmaf(v.x, scv.x, bbv.x), 0.f); v.y = fmaxf(fmaf(v.y, scv.y, bbv.y), 0.f);
      v.z = fmaxf(fmaf(v.z, scv.z, bbv.z), 0.f); v.w = fmaxf(fmaf(v.w, scv.w, bbv.w), 0.f);
      const float4 w = *(const float4*)&vn[(size_t)batch[r] * Hc + c4];
      v.x += w.x; v.y += w.y; v.z += w.z; v.w += w.w;
    }
    acc = v;
  }
  int j1 = rowptr[r + 1];
  for (int j = rowptr[r]; j < j1; ++j) {
    int e = eidx[j];
    int s = ei[e];
    int a0 = ea[e * 3], a1 = ea[e * 3 + 1], a2 = ea[e * 3 + 2];
    float4 em = *(const float4*)&bemb[(size_t)a0 * Hc + c4];
    float4 e1 = *(const float4*)&bemb[(size_t)(8 + a1) * Hc + c4];
    float4 e2 = *(const float4*)&bemb[(size_t)(16 + a2) * Hc + c4];
    em.x += e1.x + e2.x; em.y += e1.y + e2.y; em.z += e1.z + e2.z; em.w += e1.w + e2.w;
    float4 v = bf4tof4(*(const ushort4*)&P[(size_t)s * Hc + c4]);
    if (hasbn) {
      v.x = fmaxf(fmaf(v.x, scv.x, bbv.x), 0.f); v.y = fmaxf(fmaf(v.y, scv.y, bbv.y), 0.f);
      v.z = fmaxf(fmaf(v.z, scv.z, bbv.z), 0.f); v.w = fmaxf(fmaf(v.w, scv.w, bbv.w), 0.f);
      const float4 w = *(const float4*)&vn[(size_t)batch[s] * Hc + c4];
      v.x += w.x; v.y += w.y; v.z += w.z; v.w += w.w;
    }
    acc.x += fmaxf(v.x + em.x, 0.f) + MSG_EPS;
    acc.y += fmaxf(v.y + em.y, 0.f) + MSG_EPS;
    acc.z += fmaxf(v.z + em.z, 0.f) + MSG_EPS;
    acc.w += fmaxf(v.w + em.w, 0.f) + MSG_EPS;
  }
  *(ushort4*)&T[(size_t)r * Hc + c4] = f4tobf4(acc);
}

// ---- segment-sum of relu(bn(P)) by sorted batch into vnt (pre-init with vn). 1 wave / 64 rows.
__global__ __launch_bounds__(256) void k_seg_vn(const bf16* __restrict__ P, const int* __restrict__ batch,
                                                float* __restrict__ vnt, const float* __restrict__ stats,
                                                const float* __restrict__ gamma, const float* __restrict__ beta,
                                                float invM) {
  int wave = threadIdx.x >> 6, lane = threadIdx.x & 63;
  int base = (blockIdx.x * 4 + wave) * 64;
  if (base >= Ncnt) return;
  int c4 = lane * 4;
  float4 sv = *(const float4*)&stats[c4];
  float4 qv = *(const float4*)&stats[Hc + c4];
  float4 gv = *(const float4*)&gamma[c4];
  float4 bv = *(const float4*)&beta[c4];
  float4 scv, bbv;
  float mu, var;
  mu = sv.x * invM; var = qv.x * invM - mu * mu; scv.x = rsqrtf(var + BN_EPS) * gv.x; bbv.x = bv.x - mu * scv.x;
  mu = sv.y * invM; var = qv.y * invM - mu * mu; scv.y = rsqrtf(var + BN_EPS) * gv.y; bbv.y = bv.y - mu * scv.y;
  mu = sv.z * invM; var = qv.z * invM - mu * mu; scv.z = rsqrtf(var + BN_EPS) * gv.z; bbv.z = bv.z - mu * scv.z;
  mu = sv.w * invM; var = qv.w * invM - mu * mu; scv.w = rsqrtf(var + BN_EPS) * gv.w; bbv.w = bv.w - mu * scv.w;
  int end = imin(base + 64, Ncnt);
  float4 acc = make_float4(0.f, 0.f, 0.f, 0.f);
  int curg = batch[base];
  for (int r = base; r < end; ++r) {
    int g = batch[r];
    float4 v = bf4tof4(*(const ushort4*)&P[(size_t)r * Hc + c4]);
    v.x = fmaxf(fmaf(v.x, scv.x, bbv.x), 0.f); v.y = fmaxf(fmaf(v.y, scv.y, bbv.y), 0.f);
    v.z = fmaxf(fmaf(v.z, scv.z, bbv.z), 0.f); v.w = fmaxf(fmaf(v.w, scv.w, bbv.w), 0.f);
    if (g != curg) {
      float* d = &vnt[(size_t)curg * Hc + c4];
      atomicAdd(d, acc.x); atomicAdd(d + 1, acc.y); atomicAdd(d + 2, acc.z); atomicAdd(d + 3, acc.w);
      acc = make_float4(0.f, 0.f, 0.f, 0.f);
      curg = g;
    }
    acc.x += v.x; acc.y += v.y; acc.z += v.z; acc.w += v.w;
  }
  float* d = &vnt[(size_t)curg * Hc + c4];
  atomicAdd(d, acc.x); atomicAdd(d + 1, acc.y); atomicAdd(d + 2, acc.z); atomicAdd(d + 3, acc.w);
}

// ---- BN stats over fp32 rows (VN path; stats pre-zeroed) ----
__global__ __launch_bounds__(256) void k_bn_stats_f(const float* __restrict__ h, float* __restrict__ stats, int M) {
  int c = threadIdx.x;
  int r0 = blockIdx.x * 256;
  if (r0 >= M) return;
  int r1 = imin(r0 + 256, M);
  float s = 0.f, q = 0.f;
  for (int r = r0; r < r1; ++r) {
    float v = h[(size_t)r * Hc + c];
    s += v;
    q = fmaf(v, v, q);
  }
  atomicAdd(&stats[c], s);
  atomicAdd(&stats[Hc + c], q);
}

// ---- VN elementwise relu(bn(.)) fp32->fp32 ----
__global__ __launch_bounds__(256) void k_vn_relu(const float* __restrict__ in, float* __restrict__ out,
                                                 const float* __restrict__ stats,
                                                 const float* __restrict__ gamma, const float* __restrict__ beta,
                                                 float invM) {
  int idx = blockIdx.x * 256 + threadIdx.x;
  int c = idx & (Hc - 1);
  float mu = stats[c] * invM;
  float var = stats[Hc + c] * invM - mu * mu;
  float sc = rsqrtf(var + BN_EPS) * gamma[c];
  float bb = beta[c] - mu * sc;
  out[idx] = fmaxf(fmaf(in[idx], sc, bb), 0.f);
}

// ---- final bn + global_add_pool (out pre-zeroed). 1 wave / 64 rows.
__global__ __launch_bounds__(256) void k_bn_pool(const bf16* __restrict__ P, const int* __restrict__ batch,
                                                 float* __restrict__ out, const float* __restrict__ stats,
                                                 const float* __restrict__ gamma, const float* __restrict__ beta,
                                                 float invM) {
  int wave = threadIdx.x >> 6, lane = threadIdx.x & 63;
  int base = (blockIdx.x * 4 + wave) * 64;
  if (base >= Ncnt) return;
  int c4 = lane * 4;
  float4 sv = *(const float4*)&stats[c4];
  float4 qv = *(const float4*)&stats[Hc + c4];
  float4 gv = *(const float4*)&gamma[c4];
  float4 bv = *(const float4*)&beta[c4];
  float4 scv, bbv;
  float mu, var;
  mu = sv.x * invM; var = qv.x * invM - mu * mu; scv.x = rsqrtf(var + BN_EPS) * gv.x; bbv.x = bv.x - mu * scv.x;
  mu = sv.y * invM; var = qv.y * invM - mu * mu; scv.y = rsqrtf(var + BN_EPS) * gv.y; bbv.y = bv.y - mu * scv.y;
  mu = sv.z * invM; var = qv.z * invM - mu * mu; scv.z = rsqrtf(var + BN_EPS) * gv.z; bbv.z = bv.z - mu * scv.z;
  mu = sv.w * invM; var = qv.w * invM - mu * mu; scv.w = rsqrtf(var + BN_EPS) * gv.w; bbv.w = bv.w - mu * scv.w;
  int end = imin(base + 64, Ncnt);
  float4 acc = make_float4(0.f, 0.f, 0.f, 0.f);
  int curg = batch[base];
  for (int r = base; r < end; ++r) {
    int g = batch[r];
    float4 v = bf4tof4(*(const ushort4*)&P[(size_t)r * Hc + c4]);
    v.x = fmaf(v.x, scv.x, bbv.x); v.y = fmaf(v.y, scv.y, bbv.y);
    v.z = fmaf(v.z, scv.z, bbv.z); v.w = fmaf(v.w, scv.w, bbv.w);
    if (g != curg) {
      float* d = &out[(size_t)curg * Hc + c4];
      atomicAdd(d, acc.x); atomicAdd(d + 1, acc.y); atomicAdd(d + 2, acc.z); atomicAdd(d + 3, acc.w);
      acc = make_float4(0.f, 0.f, 0.f, 0.f);
      curg = g;
    }
    acc.x += v.x; acc.y += v.y; acc.z += v.z; acc.w += v.w;
  }
  float* d = &out[(size_t)curg * Hc + c4];
  atomicAdd(d, acc.x); atomicAdd(d + 1, acc.y); atomicAdd(d + 2, acc.z); atomicAdd(d + 3, acc.w);
}

// ---- MFMA node GEMM, m97-style: C[M,256] = A @ (Whi+Wlo) + bias (+R), fused BN-stats.
// Wt layout [n][k] bf16. Tile 128(M) x 128(N), BK=64, 4 waves in 2x2.
// Staging via global_load_lds width16 into XOR-swizzled LDS (granule j stored at j^(row&7)):
// frag ds_read_b128 then lands on 8 distinct bank-groups per lane-octet (2-way alias = free).
__global__ __launch_bounds__(256) void k_gemm_mfma(const bf16* __restrict__ A, const bf16* __restrict__ Whi,
                                                   const bf16* __restrict__ Wlo, const float* __restrict__ bias,
                                                   const bf16* __restrict__ R, bf16* __restrict__ C,
                                                   float* __restrict__ stats, int M) {
  __shared__ __attribute__((aligned(16))) short As[128 * 64];
  __shared__ __attribute__((aligned(16))) short Bh[128 * 64];
  __shared__ __attribute__((aligned(16))) short Bl[128 * 64];
  int tid = threadIdx.x;
  int wave = tid >> 6, lane = tid & 63;
  int quad = lane >> 4, l15 = lane & 15;
  int wr = (wave & 1) * 64, wc = (wave >> 1) * 64;
  int row0 = blockIdx.x * 128;
  int n0 = blockIdx.y * 128;

  // staging slot for this thread, per instruction i: s = i*256+tid; r=s>>3; j=s&7; jg=j^(r&7)
  int sr[4], sjg[4];
#pragma unroll
  for (int i = 0; i < 4; ++i) {
    int s = i * 256 + tid;
    sr[i] = s >> 3;
    sjg[i] = (s & 7) ^ (sr[i] & 7);
  }

  f32x4 acc[4][4];
#pragma unroll
  for (int i = 0; i < 4; ++i)
#pragma unroll
    for (int j = 0; j < 4; ++j) acc[i][j] = (f32x4){0.f, 0.f, 0.f, 0.f};

  for (int kc = 0; kc < 256; kc += 64) {
#pragma unroll
    for (int i = 0; i < 4; ++i) {
      int r = sr[i];
      int ar = row0 + r; if (ar >= M) ar = M - 1;  // clamp: garbage rows never stored
      int gk = kc + sjg[i] * 8;
      int ldsbase = (i * 256 + wave * 64) * 8;  // shorts; wave-uniform chunk base
      gll16(A + (size_t)ar * Hc + gk, &As[ldsbase]);
      gll16(Whi + (size_t)(n0 + r) * Hc + gk, &Bh[ldsbase]);
      gll16(Wlo + (size_t)(n0 + r) * Hc + gk, &Bl[ldsbase]);
    }
    __syncthreads();
#pragma unroll
    for (int ks = 0; ks < 2; ++ks) {
      bf16x8 af[4], bh[4], bl[4];
      int g = ks * 4 + quad;
#pragma unroll
      for (int mi = 0; mi < 4; ++mi) {
        int row = wr + mi * 16 + l15;
        af[mi] = *(const bf16x8*)&As[row * 64 + (g ^ (row & 7)) * 8];
      }
#pragma unroll
      for (int ni = 0; ni < 4; ++ni) {
        int row = wc + ni * 16 + l15;
        int o = row * 64 + (g ^ (row & 7)) * 8;
        bh[ni] = *(const bf16x8*)&Bh[o];
        bl[ni] = *(const bf16x8*)&Bl[o];
      }
#pragma unroll
      for (int mi = 0; mi < 4; ++mi)
#pragma unroll
        for (int ni = 0; ni < 4; ++ni)
          acc[mi][ni] = __builtin_amdgcn_mfma_f32_16x16x32_bf16(af[mi], bh[ni], acc[mi][ni], 0, 0, 0);
#pragma unroll
      for (int mi = 0; mi < 4; ++mi)
#pragma unroll
        for (int ni = 0; ni < 4; ++ni)
          acc[mi][ni] = __builtin_amdgcn_mfma_f32_16x16x32_bf16(af[mi], bl[ni], acc[mi][ni], 0, 0, 0);
    }
    __syncthreads();
  }

#pragma unroll
  for (int ni = 0; ni < 4; ++ni) {
    int col = n0 + wc + ni * 16 + l15;
    float bcol = bias[col];
    float ssum = 0.f, ssq = 0.f;
#pragma unroll
    for (int mi = 0; mi < 4; ++mi) {
#pragma unroll
      for (int j = 0; j < 4; ++j) {
        int row = row0 + wr + mi * 16 + quad * 4 + j;
        if (row < M) {
          float v = acc[mi][ni][j] + bcol;
          if (R) v += __bfloat162float(R[(size_t)row * Hc + col]);
          C[(size_t)row * Hc + col] = __float2bfloat16(v);
          ssum += v;
          ssq = fmaf(v, v, ssq);
        }
      }
    }
    ssum += __shfl_xor(ssum, 16); ssum += __shfl_xor(ssum, 32);
    ssq += __shfl_xor(ssq, 16); ssq += __shfl_xor(ssq, 32);
    if (quad == 0) {
      atomicAdd(&stats[col], ssum);
      atomicAdd(&stats[Hc + col], ssq);
    }
  }
}

// ---- fp32 SIMT GEMM for the VN MLP: C[M,256] = A @ W + bias. 64x64 tile. ----
__global__ __launch_bounds__(256) void k_gemm_f32(const float* __restrict__ A, const float* __restrict__ W,
                                                  const float* __restrict__ bias, float* __restrict__ C, int M) {
  __shared__ float As[64][68];
  __shared__ float Ws[64][68];
  int tid = threadIdx.x;
  int row0 = blockIdx.x * 64;
  int col0 = blockIdx.y * 64;
  int tx = tid & 15, ty = tid >> 4;
  float acc[4][4] = {{0.f}};
  for (int k0 = 0; k0 < 256; k0 += 64) {
#pragma unroll
    for (int i = 0; i < 4; ++i) {
      int lin = tid + i * 256;
      int r = lin >> 4;
      int c4 = (lin & 15) << 2;
      int gr = row0 + r;
      float4 v = make_float4(0.f, 0.f, 0.f, 0.f);
      if (gr < M) v = *(const float4*)&A[(size_t)gr * Hc + k0 + c4];
      As[r][c4] = v.x; As[r][c4 + 1] = v.y; As[r][c4 + 2] = v.z; As[r][c4 + 3] = v.w;
      float4 w = *(const float4*)&W[(size_t)(k0 + r) * Hc + col0 + c4];
      Ws[r][c4] = w.x; Ws[r][c4 + 1] = w.y; Ws[r][c4 + 2] = w.z; Ws[r][c4 + 3] = w.w;
    }
    __syncthreads();
#pragma unroll
    for (int k = 0; k < 64; ++k) {
      float a[4], w[4];
#pragma unroll
      for (int i = 0; i < 4; ++i) a[i] = As[ty * 4 + i][k];
#pragma unroll
      for (int j = 0; j < 4; ++j) w[j] = Ws[k][tx * 4 + j];
#pragma unroll
      for (int i = 0; i < 4; ++i)
#pragma unroll
        for (int j = 0; j < 4; ++j) acc[i][j] = fmaf(a[i], w[j], acc[i][j]);
    }
    __syncthreads();
  }
#pragma unroll
  for (int i = 0; i < 4; ++i) {
    int gr = row0 + ty * 4 + i;
    if (gr >= M) break;
#pragma unroll
    for (int j = 0; j < 4; ++j) {
      int gc = col0 + tx * 4 + j;
      C[(size_t)gr * Hc + gc] = acc[i][j] + bias[gc];
    }
  }
}

extern "C" void kernel_launch(void* const* d_in, const int* in_sizes, int n_in,
                              void* d_out, int out_size, void* d_ws, size_t ws_size,
                              hipStream_t stream) {
  const int* x = (const int*)d_in[0];
  const int* ei = (const int*)d_in[1];
  const int* ea = (const int*)d_in[2];
  const int* batch = (const int*)d_in[3];
  const float* aemb = (const float*)d_in[4];
  const float* bemb = (const float*)d_in[5];
  const float* vnw = (const float*)d_in[6];
  const float* conv_w = (const float*)d_in[7];
  const float* conv_b = (const float*)d_in[8];
  const float* ngamma = (const float*)d_in[9];
  const float* nbeta = (const float*)d_in[10];
  const float* vn_w = (const float*)d_in[11];
  const float* vn_b = (const float*)d_in[12];
  const float* vn_g = (const float*)d_in[13];
  const float* vn_be = (const float*)d_in[14];
  float* out = (float*)d_out;

  const size_t NODE = (size_t)Ncnt * Hc;
  const size_t GH = (size_t)Gcnt * Hc;
  const int nScanBlk = (Ncnt + 255) / 256;  // 586

  size_t off = 0;
  char* base = (char*)d_ws;
  auto take = [&](size_t bytes) { size_t o = off; off += (bytes + 15) & ~(size_t)15; return o; };
  float* vn = (float*)(base + take(GH * 4));
  float* vnt = (float*)(base + take(GH * 4));
  float* vnu = (float*)(base + take(GH * 4));
  float* vnv = (float*)(base + take(GH * 4));
  float* statsN = (float*)(base + take(2 * Hc * 4));
  float* statsV = (float*)(base + take(2 * Hc * 4));
  int* rowptr = (int*)(base + take((size_t)(Ncnt + 1) * 4));
  int* cursor = (int*)(base + take((size_t)Ncnt * 4));
  int* eidx = (int*)(base + take((size_t)Ecnt * 4));
  int* bsum = (int*)(base + take((size_t)nScanBlk * 4));
  bf16* P = (bf16*)(base + take(NODE * 2));
  bf16* T = (bf16*)(base + take(NODE * 2));
  bf16* WhiC = (bf16*)(base + take((size_t)Lcnt * 65536 * 2));
  bf16* WloC = (bf16*)(base + take((size_t)Lcnt * 65536 * 2));
  const size_t NEED = off;
  if (ws_size < NEED) {
    k_zero<<<(int)((GH + 255) / 256), 256, 0, stream>>>(out, (int)GH);
    k_diag<<<1, 1, 0, stream>>>(out, 100000.f + (float)(ws_size / (1024.0 * 1024.0)));
    return;
  }

  const int eBlk = (Ecnt + 255) / 256;
  const int nWaveBlk = (Ncnt + 3) / 4;
  const int segBlk = (Ncnt + 255) / 256;
  const int gBlk256 = (Gcnt + 255) / 256;
  const dim3 ggN((Ncnt + 127) / 128, 2);
  const dim3 gv(Gcnt / 64, 4);
  const float invN = 1.f / Ncnt;
  const float invG = 1.f / Gcnt;

  // CSR build (parallel scan)
  k_zero_int<<<nScanBlk, 256, 0, stream>>>(cursor, Ncnt);
  k_count<<<eBlk, 256, 0, stream>>>(ei, cursor);
  k_scan1<<<nScanBlk, 256, 0, stream>>>(cursor, rowptr, bsum, Ncnt);
  k_scan2<<<1, 1024, 0, stream>>>(bsum, nScanBlk);
  k_scan3<<<nScanBlk, 256, 0, stream>>>(rowptr, cursor, bsum, Ncnt);
  k_scatter<<<eBlk, 256, 0, stream>>>(ei, cursor, eidx);

  // conv weight prep (hi/lo, transposed)
  k_prep_w<<<(Lcnt * 65536 + 255) / 256, 256, 0, stream>>>(conv_w, WhiC, WloC, Lcnt);

  // Encoders + conv0 (stats fused for layer-1 BN)
  k_atom_encode<<<nWaveBlk, 256, 0, stream>>>(x, aemb, vnw, P);
  k_init_vn<<<(int)(GH / 256), 256, 0, stream>>>(vn, vnw);
  k_agg<<<nWaveBlk, 256, 0, stream>>>(P, T, rowptr, eidx, ei, ea, bemb,
                                      nullptr, nullptr, nullptr, nullptr, nullptr, 0.f);
  k_zero<<<2, 256, 0, stream>>>(statsN, 2 * Hc);
  k_gemm_mfma<<<ggN, 256, 0, stream>>>(T, WhiC, WloC, conv_b, nullptr, P, statsN, Ncnt);

  for (int l = 1; l < Lcnt; ++l) {
    int p = l - 1;
    const float* g = ngamma + (size_t)p * Hc;
    const float* b = nbeta + (size_t)p * Hc;
    // vn_t = vn + segsum(relu(bn(P)))
    k_copy<<<(int)(GH / 256), 256, 0, stream>>>(vnt, vn, (int)GH);
    k_seg_vn<<<segBlk, 256, 0, stream>>>(P, batch, vnt, statsN, g, b, invN);
    // VN MLP j=0 (fp32 SIMT)
    k_gemm_f32<<<gv, 256, 0, stream>>>(vnt, vn_w + (size_t)(2 * p) * 65536,
                                       vn_b + (size_t)(2 * p) * Hc, vnu, Gcnt);
    k_zero<<<2, 256, 0, stream>>>(statsV, 2 * Hc);
    k_bn_stats_f<<<gBlk256, 256, 0, stream>>>(vnu, statsV, Gcnt);
    k_vn_relu<<<(int)(GH / 256), 256, 0, stream>>>(vnu, vnv, statsV,
                                                   vn_g + (size_t)(2 * p) * Hc,
                                                   vn_be + (size_t)(2 * p) * Hc, invG);
    // VN MLP j=1 -> vn
    k_gemm_f32<<<gv, 256, 0, stream>>>(vnv, vn_w + (size_t)(2 * p + 1) * 65536,
                                       vn_b + (size_t)(2 * p + 1) * Hc, vnu, Gcnt);
    k_zero<<<2, 256, 0, stream>>>(statsV, 2 * Hc);
    k_bn_stats_f<<<gBlk256, 256, 0, stream>>>(vnu, statsV, Gcnt);
    k_vn_relu<<<(int)(GH / 256), 256, 0, stream>>>(vnu, vn, statsV,
                                                   vn_g + (size_t)(2 * p + 1) * Hc,
                                                   vn_be + (size_t)(2 * p + 1) * Hc, invG);
    // T = h2 + agg(h2), h2 = relu(bn(P)) + vn[batch]
    k_agg<<<nWaveBlk, 256, 0, stream>>>(P, T, rowptr, eidx, ei, ea, bemb, vn, batch, statsN, g, b, invN);
    // P = T @ W + bias + P (stats fused for next BN)
    k_zero<<<2, 256, 0, stream>>>(statsN, 2 * Hc);
    k_gemm_mfma<<<ggN, 256, 0, stream>>>(T, WhiC + (size_t)l * 65536, WloC + (size_t)l * 65536,
                                         conv_b + (size_t)l * Hc, P, P, statsN, Ncnt);
  }

  // Final BN + global add pool
  k_zero<<<(int)((GH + 255) / 256), 256, 0, stream>>>(out, (int)GH);
  k_bn_pool<<<segBlk, 256, 0, stream>>>(P, batch, out, statsN,
                                        ngamma + (size_t)(Lcnt - 1) * Hc, nbeta + (size_t)(Lcnt - 1) * Hc,
                                        invN);
}

// Round 8
// 3803.712 us; speedup vs baseline: 1.3119x; 1.0168x over previous
//
#include <hip/hip_runtime.h>
#include <hip/hip_bf16.h>

// DeeperGCN on MI355X — round 8: node GEMM with fragment-packed direct-global B
// (coalesced, no LDS, no barrier dep) + A via global_load_lds w/ XOR swizzle (16 KB).
// VN path fp32 SIMT (unchanged, passed twice). N=150000, E=300000, G=4096, H=256, L=7.

#define Ncnt 150000
#define Ecnt 300000
#define Gcnt 4096
#define Hc 256
#define Lcnt 7
#define BN_EPS 1e-5f
#define MSG_EPS 1e-7f

typedef __hip_bfloat16 bf16;
typedef __attribute__((ext_vector_type(8))) short bf16x8;
typedef __attribute__((ext_vector_type(4))) float f32x4;

static __device__ __forceinline__ int imin(int a, int b) { return a < b ? a : b; }

static __device__ __forceinline__ float bs2f(unsigned short s) {
  unsigned u = ((unsigned)s) << 16;
  union { unsigned u; float f; } c; c.u = u; return c.f;
}
static __device__ __forceinline__ unsigned short f2bs(float f) {
  bf16 h = __float2bfloat16(f);
  union { bf16 h; unsigned short s; } c; c.h = h; return c.s;
}
static __device__ __forceinline__ float4 bf4tof4(ushort4 u) {
  float4 r; r.x = bs2f(u.x); r.y = bs2f(u.y); r.z = bs2f(u.z); r.w = bs2f(u.w); return r;
}
static __device__ __forceinline__ ushort4 f4tobf4(float4 v) {
  ushort4 u; u.x = f2bs(v.x); u.y = f2bs(v.y); u.z = f2bs(v.z); u.w = f2bs(v.w); return u;
}

// async global->LDS, 16B per lane; lds dst must be the wave-uniform chunk base.
static __device__ __forceinline__ void gll16(const bf16* g, const short* l) {
  __builtin_amdgcn_global_load_lds((const __attribute__((address_space(1))) void*)g,
                                   (__attribute__((address_space(3))) void*)l, 16, 0, 0);
}

__global__ __launch_bounds__(256) void k_zero(float* __restrict__ p, int n) {
  int i = blockIdx.x * 256 + threadIdx.x;
  if (i < n) p[i] = 0.f;
}
__global__ __launch_bounds__(256) void k_zero_int(int* __restrict__ p, int n) {
  int i = blockIdx.x * 256 + threadIdx.x;
  if (i < n) p[i] = 0;
}
// float4 copy (n multiple of 4)
__global__ __launch_bounds__(256) void k_copy4(float* __restrict__ dst, const float* __restrict__ src, int n4) {
  int i = blockIdx.x * 256 + threadIdx.x;
  if (i < n4) ((float4*)dst)[i] = ((const float4*)src)[i];
}
__global__ void k_diag(float* __restrict__ out, float v) { out[0] = v; }

// ---- CSR build (counting sort by dst) ----
__global__ __launch_bounds__(256) void k_count(const int* __restrict__ ei, int* __restrict__ cnt) {
  int e = blockIdx.x * 256 + threadIdx.x;
  if (e < Ecnt) atomicAdd(&cnt[ei[Ecnt + e]], 1);
}
__global__ __launch_bounds__(256) void k_scan1(const int* __restrict__ cnt, int* __restrict__ rowptr,
                                               int* __restrict__ bsum, int n) {
  __shared__ int sh[256];
  int t = threadIdx.x;
  int i = blockIdx.x * 256 + t;
  int v = (i < n) ? cnt[i] : 0;
  sh[t] = v;
  __syncthreads();
#pragma unroll
  for (int off = 1; off < 256; off <<= 1) {
    int u = (t >= off) ? sh[t - off] : 0;
    __syncthreads();
    sh[t] += u;
    __syncthreads();
  }
  if (i < n) rowptr[i] = sh[t] - v;
  if (t == 255) bsum[blockIdx.x] = sh[255];
}
__global__ __launch_bounds__(1024) void k_scan2(int* __restrict__ bsum, int nb) {
  __shared__ int sh[1024];
  int t = threadIdx.x;
  int v = (t < nb) ? bsum[t] : 0;
  sh[t] = v;
  __syncthreads();
#pragma unroll
  for (int off = 1; off < 1024; off <<= 1) {
    int u = (t >= off) ? sh[t - off] : 0;
    __syncthreads();
    sh[t] += u;
    __syncthreads();
  }
  if (t < nb) bsum[t] = sh[t] - v;
}
__global__ __launch_bounds__(256) void k_scan3(int* __restrict__ rowptr, int* __restrict__ cursor,
                                               const int* __restrict__ bsum, int n) {
  int i = blockIdx.x * 256 + threadIdx.x;
  if (i < n) {
    int v = rowptr[i] + bsum[blockIdx.x];
    rowptr[i] = v;
    cursor[i] = v;
  }
  if (i == 0) rowptr[n] = Ecnt;
}
__global__ __launch_bounds__(256) void k_scatter(const int* __restrict__ ei, int* __restrict__ cursor,
                                                 int* __restrict__ eidx) {
  int e = blockIdx.x * 256 + threadIdx.x;
  if (e < Ecnt) {
    int d = ei[Ecnt + e];
    int pos = atomicAdd(&cursor[d], 1);
    eidx[pos] = e;
  }
}

// ---- weight prep: conv W[k][n] fp32 -> fragment-packed bf16 hi/lo.
// Chunk c = (((m*2+ct)*8+ni)*8+kc8)*64 + lane holds 8 bf16: lane l15=col, quad*8+j = k-in-chunk.
// A wave's fragment (ct,ni,kc8) is 64 consecutive chunks = 1 KB contiguous (coalesced b128/lane).
__global__ __launch_bounds__(256) void k_prep_w(const float* __restrict__ W, bf16* __restrict__ hi,
                                                bf16* __restrict__ lo, int nmats) {
  int c = blockIdx.x * 256 + threadIdx.x;
  if (c >= nmats * 8192) return;
  int lane = c & 63;
  int t = c >> 6;
  int kc8 = t & 7;
  int ni = (t >> 3) & 7;
  int ct = (t >> 6) & 1;
  int m = t >> 7;
  int n = ct * 128 + ni * 16 + (lane & 15);
  int k0 = kc8 * 32 + (lane >> 4) * 8;
  bf16x8 hv, lv;
#pragma unroll
  for (int j = 0; j < 8; ++j) {
    float w = W[(size_t)m * 65536 + (size_t)(k0 + j) * 256 + n];
    unsigned short h = f2bs(w);
    float res = w - bs2f(h);
    hv[j] = (short)h;
    lv[j] = (short)f2bs(res);
  }
  *(bf16x8*)&hi[(size_t)c * 8] = hv;
  *(bf16x8*)&lo[(size_t)c * 8] = lv;
}

// ---- encoders (1 wave per node, 4 ch/lane) ----
__global__ __launch_bounds__(256) void k_atom_encode(const int* __restrict__ x,
                                                     const float* __restrict__ aemb,
                                                     const float* __restrict__ vnw,
                                                     bf16* __restrict__ P) {
  int wave = threadIdx.x >> 6, lane = threadIdx.x & 63;
  int r = blockIdx.x * 4 + wave;
  if (r >= Ncnt) return;
  int c4 = lane * 4;
  const int* xr = x + (size_t)r * 9;
  float4 v = *(const float4*)&vnw[c4];
#pragma unroll
  for (int f = 0; f < 9; ++f) {
    float4 e = *(const float4*)&aemb[(size_t)((f << 6) + xr[f]) * Hc + c4];
    v.x += e.x; v.y += e.y; v.z += e.z; v.w += e.w;
  }
  *(ushort4*)&P[(size_t)r * Hc + c4] = f4tobf4(v);
}

__global__ __launch_bounds__(256) void k_init_vn(float* __restrict__ vn, const float* __restrict__ vnw) {
  int idx = blockIdx.x * 256 + threadIdx.x;  // G*Hc total
  vn[idx] = vnw[idx & (Hc - 1)];
}

// ---- aggregation: T[r] = h2(r) + sum_{e: dst=r} (relu(h2(src)+bond_emb)+eps)
// h2(n) = P[n] (stats==null) or relu(bn(P[n]))+vn[batch[n]].  1 wave/node.
__global__ __launch_bounds__(256) void k_agg(const bf16* __restrict__ P, bf16* __restrict__ T,
                                             const int* __restrict__ rowptr, const int* __restrict__ eidx,
                                             const int* __restrict__ ei, const int* __restrict__ ea,
                                             const float* __restrict__ bemb,
                                             const float* __restrict__ vn, const int* __restrict__ batch,
                                             const float* __restrict__ stats,
                                             const float* __restrict__ gamma, const float* __restrict__ beta,
                                             float invM) {
  int wave = threadIdx.x >> 6, lane = threadIdx.x & 63;
  int r = blockIdx.x * 4 + wave;
  if (r >= Ncnt) return;
  int c4 = lane * 4;
  bool hasbn = (stats != nullptr);
  float4 scv = make_float4(1.f, 1.f, 1.f, 1.f), bbv = make_float4(0.f, 0.f, 0.f, 0.f);
  if (hasbn) {
    float4 sv = *(const float4*)&stats[c4];
    float4 qv = *(const float4*)&stats[Hc + c4];
    float4 gv = *(const float4*)&gamma[c4];
    float4 bv = *(const float4*)&beta[c4];
    float mu, var;
    mu = sv.x * invM; var = qv.x * invM - mu * mu; scv.x = rsqrtf(var + BN_EPS) * gv.x; bbv.x = bv.x - mu * scv.x;
    mu = sv.y * invM; var = qv.y * invM - mu * mu; scv.y = rsqrtf(var + BN_EPS) * gv.y; bbv.y = bv.y - mu * scv.y;
    mu = sv.z * invM; var = qv.z * invM - mu * mu; scv.z = rsqrtf(var + BN_EPS) * gv.z; bbv.z = bv.z - mu * scv.z;
    mu = sv.w * invM; var = qv.w * invM - mu * mu; scv.w = rsqrtf(var + BN_EPS) * gv.w; bbv.w = bv.w - mu * scv.w;
  }
  float4 acc;
  {
    float4 v = bf4tof4(*(const ushort4*)&P[(size_t)r * Hc + c4]);
    if (hasbn) {
      v.x = fmaxf(fmaf(v.x, scv.x, bbv.x), 0.f); v.y = fmaxf(fmaf(v.y, scv.y, bbv.y), 0.f);
      v.z = fmaxf(fmaf(v.z, scv.z, bbv.z), 0.f); v.w = fmaxf(fmaf(v.w, scv.w, bbv.w), 0.f);
      const float4 w = *(const float4*)&vn[(size_t)batch[r] * Hc + c4];
      v.x += w.x; v.y += w.y; v.z += w.z; v.w += w.w;
    }
    acc = v;
  }
  int j1 = rowptr[r + 1];
  for (int j = rowptr[r]; j < j1; ++j) {
    int e = eidx[j];
    int s = ei[e];
    int a0 = ea[e * 3], a1 = ea[e * 3 + 1], a2 = ea[e * 3 + 2];
    float4 em = *(const float4*)&bemb[(size_t)a0 * Hc + c4];
    float4 e1 = *(const float4*)&bemb[(size_t)(8 + a1) * Hc + c4];
    float4 e2 = *(const float4*)&bemb[(size_t)(16 + a2) * Hc + c4];
    em.x += e1.x + e2.x; em.y += e1.y + e2.y; em.z += e1.z + e2.z; em.w += e1.w + e2.w;
    float4 v = bf4tof4(*(const ushort4*)&P[(size_t)s * Hc + c4]);
    if (hasbn) {
      v.x = fmaxf(fmaf(v.x, scv.x, bbv.x), 0.f); v.y = fmaxf(fmaf(v.y, scv.y, bbv.y), 0.f);
      v.z = fmaxf(fmaf(v.z, scv.z, bbv.z), 0.f); v.w = fmaxf(fmaf(v.w, scv.w, bbv.w), 0.f);
      const float4 w = *(const float4*)&vn[(size_t)batch[s] * Hc + c4];
      v.x += w.x; v.y += w.y; v.z += w.z; v.w += w.w;
    }
    acc.x += fmaxf(v.x + em.x, 0.f) + MSG_EPS;
    acc.y += fmaxf(v.y + em.y, 0.f) + MSG_EPS;
    acc.z += fmaxf(v.z + em.z, 0.f) + MSG_EPS;
    acc.w += fmaxf(v.w + em.w, 0.f) + MSG_EPS;
  }
  *(ushort4*)&T[(size_t)r * Hc + c4] = f4tobf4(acc);
}

// ---- segment-sum of relu(bn(P)) by sorted batch into vnt (pre-init with vn). 1 wave / 64 rows.
__global__ __launch_bounds__(256) void k_seg_vn(const bf16* __restrict__ P, const int* __restrict__ batch,
                                                float* __restrict__ vnt, const float* __restrict__ stats,
                                                const float* __restrict__ gamma, const float* __restrict__ beta,
                                                float invM) {
  int wave = threadIdx.x >> 6, lane = threadIdx.x & 63;
  int base = (blockIdx.x * 4 + wave) * 64;
  if (base >= Ncnt) return;
  int c4 = lane * 4;
  float4 sv = *(const float4*)&stats[c4];
  float4 qv = *(const float4*)&stats[Hc + c4];
  float4 gv = *(const float4*)&gamma[c4];
  float4 bv = *(const float4*)&beta[c4];
  float4 scv, bbv;
  float mu, var;
  mu = sv.x * invM; var = qv.x * invM - mu * mu; scv.x = rsqrtf(var + BN_EPS) * gv.x; bbv.x = bv.x - mu * scv.x;
  mu = sv.y * invM; var = qv.y * invM - mu * mu; scv.y = rsqrtf(var + BN_EPS) * gv.y; bbv.y = bv.y - mu * scv.y;
  mu = sv.z * invM; var = qv.z * invM - mu * mu; scv.z = rsqrtf(var + BN_EPS) * gv.z; bbv.z = bv.z - mu * scv.z;
  mu = sv.w * invM; var = qv.w * invM - mu * mu; scv.w = rsqrtf(var + BN_EPS) * gv.w; bbv.w = bv.w - mu * scv.w;
  int end = imin(base + 64, Ncnt);
  float4 acc = make_float4(0.f, 0.f, 0.f, 0.f);
  int curg = batch[base];
  for (int r = base; r < end; ++r) {
    int g = batch[r];
    float4 v = bf4tof4(*(const ushort4*)&P[(size_t)r * Hc + c4]);
    v.x = fmaxf(fmaf(v.x, scv.x, bbv.x), 0.f); v.y = fmaxf(fmaf(v.y, scv.y, bbv.y), 0.f);
    v.z = fmaxf(fmaf(v.z, scv.z, bbv.z), 0.f); v.w = fmaxf(fmaf(v.w, scv.w, bbv.w), 0.f);
    if (g != curg) {
      float* d = &vnt[(size_t)curg * Hc + c4];
      atomicAdd(d, acc.x); atomicAdd(d + 1, acc.y); atomicAdd(d + 2, acc.z); atomicAdd(d + 3, acc.w);
      acc = make_float4(0.f, 0.f, 0.f, 0.f);
      curg = g;
    }
    acc.x += v.x; acc.y += v.y; acc.z += v.z; acc.w += v.w;
  }
  float* d = &vnt[(size_t)curg * Hc + c4];
  atomicAdd(d, acc.x); atomicAdd(d + 1, acc.y); atomicAdd(d + 2, acc.z); atomicAdd(d + 3, acc.w);
}

// ---- BN stats over fp32 rows (VN path; stats pre-zeroed) ----
__global__ __launch_bounds__(256) void k_bn_stats_f(const float* __restrict__ h, float* __restrict__ stats, int M) {
  int c = threadIdx.x;
  int r0 = blockIdx.x * 256;
  if (r0 >= M) return;
  int r1 = imin(r0 + 256, M);
  float s = 0.f, q = 0.f;
  for (int r = r0; r < r1; ++r) {
    float v = h[(size_t)r * Hc + c];
    s += v;
    q = fmaf(v, v, q);
  }
  atomicAdd(&stats[c], s);
  atomicAdd(&stats[Hc + c], q);
}

// ---- VN elementwise relu(bn(.)) fp32->fp32 ----
__global__ __launch_bounds__(256) void k_vn_relu(const float* __restrict__ in, float* __restrict__ out,
                                                 const float* __restrict__ stats,
                                                 const float* __restrict__ gamma, const float* __restrict__ beta,
                                                 float invM) {
  int idx = blockIdx.x * 256 + threadIdx.x;
  int c = idx & (Hc - 1);
  float mu = stats[c] * invM;
  float var = stats[Hc + c] * invM - mu * mu;
  float sc = rsqrtf(var + BN_EPS) * gamma[c];
  float bb = beta[c] - mu * sc;
  out[idx] = fmaxf(fmaf(in[idx], sc, bb), 0.f);
}

// ---- final bn + global_add_pool (out pre-zeroed). 1 wave / 64 rows.
__global__ __launch_bounds__(256) void k_bn_pool(const bf16* __restrict__ P, const int* __restrict__ batch,
                                                 float* __restrict__ out, const float* __restrict__ stats,
                                                 const float* __restrict__ gamma, const float* __restrict__ beta,
                                                 float invM) {
  int wave = threadIdx.x >> 6, lane = threadIdx.x & 63;
  int base = (blockIdx.x * 4 + wave) * 64;
  if (base >= Ncnt) return;
  int c4 = lane * 4;
  float4 sv = *(const float4*)&stats[c4];
  float4 qv = *(const float4*)&stats[Hc + c4];
  float4 gv = *(const float4*)&gamma[c4];
  float4 bv = *(const float4*)&beta[c4];
  float4 scv, bbv;
  float mu, var;
  mu = sv.x * invM; var = qv.x * invM - mu * mu; scv.x = rsqrtf(var + BN_EPS) * gv.x; bbv.x = bv.x - mu * scv.x;
  mu = sv.y * invM; var = qv.y * invM - mu * mu; scv.y = rsqrtf(var + BN_EPS) * gv.y; bbv.y = bv.y - mu * scv.y;
  mu = sv.z * invM; var = qv.z * invM - mu * mu; scv.z = rsqrtf(var + BN_EPS) * gv.z; bbv.z = bv.z - mu * scv.z;
  mu = sv.w * invM; var = qv.w * invM - mu * mu; scv.w = rsqrtf(var + BN_EPS) * gv.w; bbv.w = bv.w - mu * scv.w;
  int end = imin(base + 64, Ncnt);
  float4 acc = make_float4(0.f, 0.f, 0.f, 0.f);
  int curg = batch[base];
  for (int r = base; r < end; ++r) {
    int g = batch[r];
    float4 v = bf4tof4(*(const ushort4*)&P[(size_t)r * Hc + c4]);
    v.x = fmaf(v.x, scv.x, bbv.x); v.y = fmaf(v.y, scv.y, bbv.y);
    v.z = fmaf(v.z, scv.z, bbv.z); v.w = fmaf(v.w, scv.w, bbv.w);
    if (g != curg) {
      float* d = &out[(size_t)curg * Hc + c4];
      atomicAdd(d, acc.x); atomicAdd(d + 1, acc.y); atomicAdd(d + 2, acc.z); atomicAdd(d + 3, acc.w);
      acc = make_float4(0.f, 0.f, 0.f, 0.f);
      curg = g;
    }
    acc.x += v.x; acc.y += v.y; acc.z += v.z; acc.w += v.w;
  }
  float* d = &out[(size_t)curg * Hc + c4];
  atomicAdd(d, acc.x); atomicAdd(d + 1, acc.y); atomicAdd(d + 2, acc.z); atomicAdd(d + 3, acc.w);
}

// ---- MFMA node GEMM: C[M,256] = A @ (Whi+Wlo) + bias (+R), fused BN-stats.
// A: LDS-staged (global_load_lds w16, XOR swizzle, 16 KB). B: fragment-packed,
// coalesced direct-global (L2-resident, no barrier dep). Tile 128x128, 4 waves 2x2.
__global__ __launch_bounds__(256, 4) void k_gemm_mfma(const bf16* __restrict__ A, const bf16* __restrict__ Whi,
                                                      const bf16* __restrict__ Wlo, const float* __restrict__ bias,
                                                      const bf16* __restrict__ R, bf16* __restrict__ C,
                                                      float* __restrict__ stats, int M) {
  __shared__ __attribute__((aligned(16))) short As[128 * 64];
  int tid = threadIdx.x;
  int wave = tid >> 6, lane = tid & 63;
  int quad = lane >> 4, l15 = lane & 15;
  int wr = (wave & 1) * 64, wc = (wave >> 1) * 64;
  int ct = blockIdx.x;           // column tile (n0 = ct*128)
  int row0 = blockIdx.y * 128;
  int n0 = ct * 128;

  // A staging slots: s = i*256+tid; r=s>>3; LDS granule j=s&7 holds global granule j^(r&7)
  int sr[4], sjg[4];
#pragma unroll
  for (int i = 0; i < 4; ++i) {
    int s = i * 256 + tid;
    sr[i] = s >> 3;
    sjg[i] = (s & 7) ^ (sr[i] & 7);
  }

  f32x4 acc[4][4];
#pragma unroll
  for (int i = 0; i < 4; ++i)
#pragma unroll
    for (int j = 0; j < 4; ++j) acc[i][j] = (f32x4){0.f, 0.f, 0.f, 0.f};

  for (int kci = 0; kci < 4; ++kci) {
    int kc = kci * 64;
#pragma unroll
    for (int i = 0; i < 4; ++i) {
      int r = sr[i];
      int ar = row0 + r; if (ar >= M) ar = M - 1;  // clamp: garbage rows never stored
      gll16(A + (size_t)ar * Hc + kc + sjg[i] * 8, &As[(i * 256 + wave * 64) * 8]);
    }
    __syncthreads();
#pragma unroll
    for (int ks = 0; ks < 2; ++ks) {
      int kc8 = kci * 2 + ks;      // global 32-wide k-chunk index
      int g = ks * 4 + quad;       // granule within the 64-k LDS slab
      bf16x8 af[4];
#pragma unroll
      for (int mi = 0; mi < 4; ++mi) {
        int row = wr + mi * 16 + l15;
        af[mi] = *(const bf16x8*)&As[row * 64 + (g ^ (row & 7)) * 8];
      }
#pragma unroll
      for (int nii = 0; nii < 4; ++nii) {
        int niG = (wc >> 4) + nii;
        size_t fo = ((((size_t)(ct * 8 + niG)) * 8 + kc8) * 64 + lane) * 8;
        bf16x8 bh = *(const bf16x8*)&Whi[fo];
        bf16x8 bl = *(const bf16x8*)&Wlo[fo];
#pragma unroll
        for (int mi = 0; mi < 4; ++mi) {
          acc[mi][nii] = __builtin_amdgcn_mfma_f32_16x16x32_bf16(af[mi], bh, acc[mi][nii], 0, 0, 0);
          acc[mi][nii] = __builtin_amdgcn_mfma_f32_16x16x32_bf16(af[mi], bl, acc[mi][nii], 0, 0, 0);
        }
      }
    }
    __syncthreads();
  }

#pragma unroll
  for (int ni = 0; ni < 4; ++ni) {
    int col = n0 + wc + ni * 16 + l15;
    float bcol = bias[col];
    float ssum = 0.f, ssq = 0.f;
#pragma unroll
    for (int mi = 0; mi < 4; ++mi) {
#pragma unroll
      for (int j = 0; j < 4; ++j) {
        int row = row0 + wr + mi * 16 + quad * 4 + j;
        if (row < M) {
          float v = acc[mi][ni][j] + bcol;
          if (R) v += __bfloat162float(R[(size_t)row * Hc + col]);
          C[(size_t)row * Hc + col] = __float2bfloat16(v);
          ssum += v;
          ssq = fmaf(v, v, ssq);
        }
      }
    }
    ssum += __shfl_xor(ssum, 16); ssum += __shfl_xor(ssum, 32);
    ssq += __shfl_xor(ssq, 16); ssq += __shfl_xor(ssq, 32);
    if (quad == 0) {
      atomicAdd(&stats[col], ssum);
      atomicAdd(&stats[Hc + col], ssq);
    }
  }
}

// ---- fp32 SIMT GEMM for the VN MLP: C[M,256] = A @ W + bias. 64x64 tile. ----
__global__ __launch_bounds__(256) void k_gemm_f32(const float* __restrict__ A, const float* __restrict__ W,
                                                  const float* __restrict__ bias, float* __restrict__ C, int M) {
  __shared__ float As[64][68];
  __shared__ float Ws[64][68];
  int tid = threadIdx.x;
  int row0 = blockIdx.x * 64;
  int col0 = blockIdx.y * 64;
  int tx = tid & 15, ty = tid >> 4;
  float acc[4][4] = {{0.f}};
  for (int k0 = 0; k0 < 256; k0 += 64) {
#pragma unroll
    for (int i = 0; i < 4; ++i) {
      int lin = tid + i * 256;
      int r = lin >> 4;
      int c4 = (lin & 15) << 2;
      int gr = row0 + r;
      float4 v = make_float4(0.f, 0.f, 0.f, 0.f);
      if (gr < M) v = *(const float4*)&A[(size_t)gr * Hc + k0 + c4];
      As[r][c4] = v.x; As[r][c4 + 1] = v.y; As[r][c4 + 2] = v.z; As[r][c4 + 3] = v.w;
      float4 w = *(const float4*)&W[(size_t)(k0 + r) * Hc + col0 + c4];
      Ws[r][c4] = w.x; Ws[r][c4 + 1] = w.y; Ws[r][c4 + 2] = w.z; Ws[r][c4 + 3] = w.w;
    }
    __syncthreads();
#pragma unroll
    for (int k = 0; k < 64; ++k) {
      float a[4], w[4];
#pragma unroll
      for (int i = 0; i < 4; ++i) a[i] = As[ty * 4 + i][k];
#pragma unroll
      for (int j = 0; j < 4; ++j) w[j] = Ws[k][tx * 4 + j];
#pragma unroll
      for (int i = 0; i < 4; ++i)
#pragma unroll
        for (int j = 0; j < 4; ++j) acc[i][j] = fmaf(a[i], w[j], acc[i][j]);
    }
    __syncthreads();
  }
#pragma unroll
  for (int i = 0; i < 4; ++i) {
    int gr = row0 + ty * 4 + i;
    if (gr >= M) break;
#pragma unroll
    for (int j = 0; j < 4; ++j) {
      int gc = col0 + tx * 4 + j;
      C[(size_t)gr * Hc + gc] = acc[i][j] + bias[gc];
    }
  }
}

extern "C" void kernel_launch(void* const* d_in, const int* in_sizes, int n_in,
                              void* d_out, int out_size, void* d_ws, size_t ws_size,
                              hipStream_t stream) {
  const int* x = (const int*)d_in[0];
  const int* ei = (const int*)d_in[1];
  const int* ea = (const int*)d_in[2];
  const int* batch = (const int*)d_in[3];
  const float* aemb = (const float*)d_in[4];
  const float* bemb = (const float*)d_in[5];
  const float* vnw = (const float*)d_in[6];
  const float* conv_w = (const float*)d_in[7];
  const float* conv_b = (const float*)d_in[8];
  const float* ngamma = (const float*)d_in[9];
  const float* nbeta = (const float*)d_in[10];
  const float* vn_w = (const float*)d_in[11];
  const float* vn_b = (const float*)d_in[12];
  const float* vn_g = (const float*)d_in[13];
  const float* vn_be = (const float*)d_in[14];
  float* out = (float*)d_out;

  const size_t NODE = (size_t)Ncnt * Hc;
  const size_t GH = (size_t)Gcnt * Hc;
  const int nScanBlk = (Ncnt + 255) / 256;  // 586

  size_t off = 0;
  char* base = (char*)d_ws;
  auto take = [&](size_t bytes) { size_t o = off; off += (bytes + 15) & ~(size_t)15; return o; };
  float* vn = (float*)(base + take(GH * 4));
  float* vnt = (float*)(base + take(GH * 4));
  float* vnu = (float*)(base + take(GH * 4));
  float* vnv = (float*)(base + take(GH * 4));
  float* statsN = (float*)(base + take(2 * Hc * 4));
  float* statsV = (float*)(base + take(2 * Hc * 4));
  int* rowptr = (int*)(base + take((size_t)(Ncnt + 1) * 4));
  int* cursor = (int*)(base + take((size_t)Ncnt * 4));
  int* eidx = (int*)(base + take((size_t)Ecnt * 4));
  int* bsum = (int*)(base + take((size_t)nScanBlk * 4));
  bf16* P = (bf16*)(base + take(NODE * 2));
  bf16* T = (bf16*)(base + take(NODE * 2));
  bf16* WhiC = (bf16*)(base + take((size_t)Lcnt * 65536 * 2));
  bf16* WloC = (bf16*)(base + take((size_t)Lcnt * 65536 * 2));
  const size_t NEED = off;
  if (ws_size < NEED) {
    k_zero<<<(int)((GH + 255) / 256), 256, 0, stream>>>(out, (int)GH);
    k_diag<<<1, 1, 0, stream>>>(out, 100000.f + (float)(ws_size / (1024.0 * 1024.0)));
    return;
  }

  const int eBlk = (Ecnt + 255) / 256;
  const int nWaveBlk = (Ncnt + 3) / 4;
  const int segBlk = (Ncnt + 255) / 256;
  const int gBlk256 = (Gcnt + 255) / 256;
  const dim3 ggN(2, (Ncnt + 127) / 128);   // x = col tile (adjacent blocks share A rows)
  const dim3 gv(Gcnt / 64, 4);
  const float invN = 1.f / Ncnt;
  const float invG = 1.f / Gcnt;

  // CSR build (parallel scan)
  k_zero_int<<<nScanBlk, 256, 0, stream>>>(cursor, Ncnt);
  k_count<<<eBlk, 256, 0, stream>>>(ei, cursor);
  k_scan1<<<nScanBlk, 256, 0, stream>>>(cursor, rowptr, bsum, Ncnt);
  k_scan2<<<1, 1024, 0, stream>>>(bsum, nScanBlk);
  k_scan3<<<nScanBlk, 256, 0, stream>>>(rowptr, cursor, bsum, Ncnt);
  k_scatter<<<eBlk, 256, 0, stream>>>(ei, cursor, eidx);

  // conv weight prep (hi/lo, fragment-packed)
  k_prep_w<<<(Lcnt * 8192 + 255) / 256, 256, 0, stream>>>(conv_w, WhiC, WloC, Lcnt);

  // Encoders + conv0 (stats fused for layer-1 BN)
  k_atom_encode<<<nWaveBlk, 256, 0, stream>>>(x, aemb, vnw, P);
  k_init_vn<<<(int)(GH / 256), 256, 0, stream>>>(vn, vnw);
  k_agg<<<nWaveBlk, 256, 0, stream>>>(P, T, rowptr, eidx, ei, ea, bemb,
                                      nullptr, nullptr, nullptr, nullptr, nullptr, 0.f);
  k_zero<<<2, 256, 0, stream>>>(statsN, 2 * Hc);
  k_gemm_mfma<<<ggN, 256, 0, stream>>>(T, WhiC, WloC, conv_b, nullptr, P, statsN, Ncnt);

  for (int l = 1; l < Lcnt; ++l) {
    int p = l - 1;
    const float* g = ngamma + (size_t)p * Hc;
    const float* b = nbeta + (size_t)p * Hc;
    // vn_t = vn + segsum(relu(bn(P)))
    k_copy4<<<(int)(GH / 1024), 256, 0, stream>>>(vnt, vn, (int)(GH / 4));
    k_seg_vn<<<segBlk, 256, 0, stream>>>(P, batch, vnt, statsN, g, b, invN);
    // VN MLP j=0 (fp32 SIMT)
    k_gemm_f32<<<gv, 256, 0, stream>>>(vnt, vn_w + (size_t)(2 * p) * 65536,
                                       vn_b + (size_t)(2 * p) * Hc, vnu, Gcnt);
    k_zero<<<2, 256, 0, stream>>>(statsV, 2 * Hc);
    k_bn_stats_f<<<gBlk256, 256, 0, stream>>>(vnu, statsV, Gcnt);
    k_vn_relu<<<(int)(GH / 256), 256, 0, stream>>>(vnu, vnv, statsV,
                                                   vn_g + (size_t)(2 * p) * Hc,
                                                   vn_be + (size_t)(2 * p) * Hc, invG);
    // VN MLP j=1 -> vn
    k_gemm_f32<<<gv, 256, 0, stream>>>(vnv, vn_w + (size_t)(2 * p + 1) * 65536,
                                       vn_b + (size_t)(2 * p + 1) * Hc, vnu, Gcnt);
    k_zero<<<2, 256, 0, stream>>>(statsV, 2 * Hc);
    k_bn_stats_f<<<gBlk256, 256, 0, stream>>>(vnu, statsV, Gcnt);
    k_vn_relu<<<(int)(GH / 256), 256, 0, stream>>>(vnu, vn, statsV,
                                                   vn_g + (size_t)(2 * p + 1) * Hc,
                                                   vn_be + (size_t)(2 * p + 1) * Hc, invG);
    // T = h2 + agg(h2), h2 = relu(bn(P)) + vn[batch]
    k_agg<<<nWaveBlk, 256, 0, stream>>>(P, T, rowptr, eidx, ei, ea, bemb, vn, batch, statsN, g, b, invN);
    // P = T @ W + bias + P (stats fused for next BN)
    k_zero<<<2, 256, 0, stream>>>(statsN, 2 * Hc);
    k_gemm_mfma<<<ggN, 256, 0, stream>>>(T, WhiC + (size_t)l * 65536, WloC + (size_t)l * 65536,
                                         conv_b + (size_t)l * Hc, P, P, statsN, Ncnt);
  }

  // Final BN + global add pool
  k_zero<<<(int)((GH + 255) / 256), 256, 0, stream>>>(out, (int)GH);
  k_bn_pool<<<segBlk, 256, 0, stream>>>(P, batch, out, statsN,
                                        ngamma + (size_t)(Lcnt - 1) * Hc, nbeta + (size_t)(Lcnt - 1) * Hc,
                                        invN);
}

// Round 9
// 2533.620 us; speedup vs baseline: 1.9696x; 1.5013x over previous
//
#include <hip/hip_runtime.h>
#include <hip/hip_bf16.h>

// DeeperGCN on MI355X — round 9: 256-wide MFMA GEMM (single A fetch) with
// LDS-transposed coalesced epilogue (R read + C write ushort8), fused BN stats.
// VN MLP: stats + input-BN fused into the fp32 SIMT GEMM.
// N=150000, E=300000, G=4096, H=256, L=7.

#define Ncnt 150000
#define Ecnt 300000
#define Gcnt 4096
#define Hc 256
#define Lcnt 7
#define BN_EPS 1e-5f
#define MSG_EPS 1e-7f

typedef __hip_bfloat16 bf16;
typedef __attribute__((ext_vector_type(8))) short bf16x8;
typedef __attribute__((ext_vector_type(8))) unsigned short u16x8;
typedef __attribute__((ext_vector_type(4))) float f32x4;

static __device__ __forceinline__ int imin(int a, int b) { return a < b ? a : b; }

static __device__ __forceinline__ float bs2f(unsigned short s) {
  unsigned u = ((unsigned)s) << 16;
  union { unsigned u; float f; } c; c.u = u; return c.f;
}
static __device__ __forceinline__ unsigned short f2bs(float f) {
  bf16 h = __float2bfloat16(f);
  union { bf16 h; unsigned short s; } c; c.h = h; return c.s;
}
static __device__ __forceinline__ float4 bf4tof4(ushort4 u) {
  float4 r; r.x = bs2f(u.x); r.y = bs2f(u.y); r.z = bs2f(u.z); r.w = bs2f(u.w); return r;
}
static __device__ __forceinline__ ushort4 f4tobf4(float4 v) {
  ushort4 u; u.x = f2bs(v.x); u.y = f2bs(v.y); u.z = f2bs(v.z); u.w = f2bs(v.w); return u;
}

// async global->LDS, 16B per lane; lds dst must be the wave-uniform chunk base.
static __device__ __forceinline__ void gll16(const bf16* g, const short* l) {
  __builtin_amdgcn_global_load_lds((const __attribute__((address_space(1))) void*)g,
                                   (__attribute__((address_space(3))) void*)l, 16, 0, 0);
}

__global__ __launch_bounds__(256) void k_zero(float* __restrict__ p, int n) {
  int i = blockIdx.x * 256 + threadIdx.x;
  if (i < n) p[i] = 0.f;
}
__global__ __launch_bounds__(256) void k_zero_int(int* __restrict__ p, int n) {
  int i = blockIdx.x * 256 + threadIdx.x;
  if (i < n) p[i] = 0;
}
__global__ __launch_bounds__(256) void k_copy4(float* __restrict__ dst, const float* __restrict__ src, int n4) {
  int i = blockIdx.x * 256 + threadIdx.x;
  if (i < n4) ((float4*)dst)[i] = ((const float4*)src)[i];
}
__global__ void k_diag(float* __restrict__ out, float v) { out[0] = v; }

// ---- CSR build (counting sort by dst) ----
__global__ __launch_bounds__(256) void k_count(const int* __restrict__ ei, int* __restrict__ cnt) {
  int e = blockIdx.x * 256 + threadIdx.x;
  if (e < Ecnt) atomicAdd(&cnt[ei[Ecnt + e]], 1);
}
__global__ __launch_bounds__(256) void k_scan1(const int* __restrict__ cnt, int* __restrict__ rowptr,
                                               int* __restrict__ bsum, int n) {
  __shared__ int sh[256];
  int t = threadIdx.x;
  int i = blockIdx.x * 256 + t;
  int v = (i < n) ? cnt[i] : 0;
  sh[t] = v;
  __syncthreads();
#pragma unroll
  for (int off = 1; off < 256; off <<= 1) {
    int u = (t >= off) ? sh[t - off] : 0;
    __syncthreads();
    sh[t] += u;
    __syncthreads();
  }
  if (i < n) rowptr[i] = sh[t] - v;
  if (t == 255) bsum[blockIdx.x] = sh[255];
}
__global__ __launch_bounds__(1024) void k_scan2(int* __restrict__ bsum, int nb) {
  __shared__ int sh[1024];
  int t = threadIdx.x;
  int v = (t < nb) ? bsum[t] : 0;
  sh[t] = v;
  __syncthreads();
#pragma unroll
  for (int off = 1; off < 1024; off <<= 1) {
    int u = (t >= off) ? sh[t - off] : 0;
    __syncthreads();
    sh[t] += u;
    __syncthreads();
  }
  if (t < nb) bsum[t] = sh[t] - v;
}
__global__ __launch_bounds__(256) void k_scan3(int* __restrict__ rowptr, int* __restrict__ cursor,
                                               const int* __restrict__ bsum, int n) {
  int i = blockIdx.x * 256 + threadIdx.x;
  if (i < n) {
    int v = rowptr[i] + bsum[blockIdx.x];
    rowptr[i] = v;
    cursor[i] = v;
  }
  if (i == 0) rowptr[n] = Ecnt;
}
__global__ __launch_bounds__(256) void k_scatter(const int* __restrict__ ei, int* __restrict__ cursor,
                                                 int* __restrict__ eidx) {
  int e = blockIdx.x * 256 + threadIdx.x;
  if (e < Ecnt) {
    int d = ei[Ecnt + e];
    int pos = atomicAdd(&cursor[d], 1);
    eidx[pos] = e;
  }
}

// ---- weight prep: conv W[k][n] fp32 -> fragment-packed bf16 hi/lo.
// Chunk c = ((m*16 + nt)*8 + kc8)*64 + lane; lane: l15=col-in-tile, quad*8+j=k-in-chunk.
__global__ __launch_bounds__(256) void k_prep_w(const float* __restrict__ W, bf16* __restrict__ hi,
                                                bf16* __restrict__ lo, int nmats) {
  int c = blockIdx.x * 256 + threadIdx.x;
  if (c >= nmats * 8192) return;
  int lane = c & 63;
  int t = c >> 6;
  int kc8 = t & 7;
  int nt = (t >> 3) & 15;
  int m = t >> 7;
  int n = nt * 16 + (lane & 15);
  int k0 = kc8 * 32 + (lane >> 4) * 8;
  bf16x8 hv, lv;
#pragma unroll
  for (int j = 0; j < 8; ++j) {
    float w = W[(size_t)m * 65536 + (size_t)(k0 + j) * 256 + n];
    unsigned short h = f2bs(w);
    float res = w - bs2f(h);
    hv[j] = (short)h;
    lv[j] = (short)f2bs(res);
  }
  *(bf16x8*)&hi[(size_t)c * 8] = hv;
  *(bf16x8*)&lo[(size_t)c * 8] = lv;
}

// ---- encoders (1 wave per node, 4 ch/lane) ----
__global__ __launch_bounds__(256) void k_atom_encode(const int* __restrict__ x,
                                                     const float* __restrict__ aemb,
                                                     const float* __restrict__ vnw,
                                                     bf16* __restrict__ P) {
  int wave = threadIdx.x >> 6, lane = threadIdx.x & 63;
  int r = blockIdx.x * 4 + wave;
  if (r >= Ncnt) return;
  int c4 = lane * 4;
  const int* xr = x + (size_t)r * 9;
  float4 v = *(const float4*)&vnw[c4];
#pragma unroll
  for (int f = 0; f < 9; ++f) {
    float4 e = *(const float4*)&aemb[(size_t)((f << 6) + xr[f]) * Hc + c4];
    v.x += e.x; v.y += e.y; v.z += e.z; v.w += e.w;
  }
  *(ushort4*)&P[(size_t)r * Hc + c4] = f4tobf4(v);
}

__global__ __launch_bounds__(256) void k_init_vn(float* __restrict__ vn, const float* __restrict__ vnw) {
  int idx = blockIdx.x * 256 + threadIdx.x;  // G*Hc total
  vn[idx] = vnw[idx & (Hc - 1)];
}

// ---- aggregation: T[r] = h2(r) + sum_{e: dst=r} (relu(h2(src)+bond_emb)+eps)
// h2(n) = P[n] (stats==null) or relu(bn(P[n]))+vn[batch[n]].  1 wave/node.
__global__ __launch_bounds__(256) void k_agg(const bf16* __restrict__ P, bf16* __restrict__ T,
                                             const int* __restrict__ rowptr, const int* __restrict__ eidx,
                                             const int* __restrict__ ei, const int* __restrict__ ea,
                                             const float* __restrict__ bemb,
                                             const float* __restrict__ vn, const int* __restrict__ batch,
                                             const float* __restrict__ stats,
                                             const float* __restrict__ gamma, const float* __restrict__ beta,
                                             float invM) {
  int wave = threadIdx.x >> 6, lane = threadIdx.x & 63;
  int r = blockIdx.x * 4 + wave;
  if (r >= Ncnt) return;
  int c4 = lane * 4;
  bool hasbn = (stats != nullptr);
  float4 scv = make_float4(1.f, 1.f, 1.f, 1.f), bbv = make_float4(0.f, 0.f, 0.f, 0.f);
  if (hasbn) {
    float4 sv = *(const float4*)&stats[c4];
    float4 qv = *(const float4*)&stats[Hc + c4];
    float4 gv = *(const float4*)&gamma[c4];
    float4 bv = *(const float4*)&beta[c4];
    float mu, var;
    mu = sv.x * invM; var = qv.x * invM - mu * mu; scv.x = rsqrtf(var + BN_EPS) * gv.x; bbv.x = bv.x - mu * scv.x;
    mu = sv.y * invM; var = qv.y * invM - mu * mu; scv.y = rsqrtf(var + BN_EPS) * gv.y; bbv.y = bv.y - mu * scv.y;
    mu = sv.z * invM; var = qv.z * invM - mu * mu; scv.z = rsqrtf(var + BN_EPS) * gv.z; bbv.z = bv.z - mu * scv.z;
    mu = sv.w * invM; var = qv.w * invM - mu * mu; scv.w = rsqrtf(var + BN_EPS) * gv.w; bbv.w = bv.w - mu * scv.w;
  }
  float4 acc;
  {
    float4 v = bf4tof4(*(const ushort4*)&P[(size_t)r * Hc + c4]);
    if (hasbn) {
      v.x = fmaxf(fmaf(v.x, scv.x, bbv.x), 0.f); v.y = fmaxf(fmaf(v.y, scv.y, bbv.y), 0.f);
      v.z = fmaxf(fmaf(v.z, scv.z, bbv.z), 0.f); v.w = fmaxf(fmaf(v.w, scv.w, bbv.w), 0.f);
      const float4 w = *(const float4*)&vn[(size_t)batch[r] * Hc + c4];
      v.x += w.x; v.y += w.y; v.z += w.z; v.w += w.w;
    }
    acc = v;
  }
  int j1 = rowptr[r + 1];
  for (int j = rowptr[r]; j < j1; ++j) {
    int e = eidx[j];
    int s = ei[e];
    int a0 = ea[e * 3], a1 = ea[e * 3 + 1], a2 = ea[e * 3 + 2];
    float4 em = *(const float4*)&bemb[(size_t)a0 * Hc + c4];
    float4 e1 = *(const float4*)&bemb[(size_t)(8 + a1) * Hc + c4];
    float4 e2 = *(const float4*)&bemb[(size_t)(16 + a2) * Hc + c4];
    em.x += e1.x + e2.x; em.y += e1.y + e2.y; em.z += e1.z + e2.z; em.w += e1.w + e2.w;
    float4 v = bf4tof4(*(const ushort4*)&P[(size_t)s * Hc + c4]);
    if (hasbn) {
      v.x = fmaxf(fmaf(v.x, scv.x, bbv.x), 0.f); v.y = fmaxf(fmaf(v.y, scv.y, bbv.y), 0.f);
      v.z = fmaxf(fmaf(v.z, scv.z, bbv.z), 0.f); v.w = fmaxf(fmaf(v.w, scv.w, bbv.w), 0.f);
      const float4 w = *(const float4*)&vn[(size_t)batch[s] * Hc + c4];
      v.x += w.x; v.y += w.y; v.z += w.z; v.w += w.w;
    }
    acc.x += fmaxf(v.x + em.x, 0.f) + MSG_EPS;
    acc.y += fmaxf(v.y + em.y, 0.f) + MSG_EPS;
    acc.z += fmaxf(v.z + em.z, 0.f) + MSG_EPS;
    acc.w += fmaxf(v.w + em.w, 0.f) + MSG_EPS;
  }
  *(ushort4*)&T[(size_t)r * Hc + c4] = f4tobf4(acc);
}

// ---- segment-sum of relu(bn(P)) by sorted batch into vnt (pre-init with vn). 1 wave / 64 rows.
__global__ __launch_bounds__(256) void k_seg_vn(const bf16* __restrict__ P, const int* __restrict__ batch,
                                                float* __restrict__ vnt, const float* __restrict__ stats,
                                                const float* __restrict__ gamma, const float* __restrict__ beta,
                                                float invM) {
  int wave = threadIdx.x >> 6, lane = threadIdx.x & 63;
  int base = (blockIdx.x * 4 + wave) * 64;
  if (base >= Ncnt) return;
  int c4 = lane * 4;
  float4 sv = *(const float4*)&stats[c4];
  float4 qv = *(const float4*)&stats[Hc + c4];
  float4 gv = *(const float4*)&gamma[c4];
  float4 bv = *(const float4*)&beta[c4];
  float4 scv, bbv;
  float mu, var;
  mu = sv.x * invM; var = qv.x * invM - mu * mu; scv.x = rsqrtf(var + BN_EPS) * gv.x; bbv.x = bv.x - mu * scv.x;
  mu = sv.y * invM; var = qv.y * invM - mu * mu; scv.y = rsqrtf(var + BN_EPS) * gv.y; bbv.y = bv.y - mu * scv.y;
  mu = sv.z * invM; var = qv.z * invM - mu * mu; scv.z = rsqrtf(var + BN_EPS) * gv.z; bbv.z = bv.z - mu * scv.z;
  mu = sv.w * invM; var = qv.w * invM - mu * mu; scv.w = rsqrtf(var + BN_EPS) * gv.w; bbv.w = bv.w - mu * scv.w;
  int end = imin(base + 64, Ncnt);
  float4 acc = make_float4(0.f, 0.f, 0.f, 0.f);
  int curg = batch[base];
  for (int r = base; r < end; ++r) {
    int g = batch[r];
    float4 v = bf4tof4(*(const ushort4*)&P[(size_t)r * Hc + c4]);
    v.x = fmaxf(fmaf(v.x, scv.x, bbv.x), 0.f); v.y = fmaxf(fmaf(v.y, scv.y, bbv.y), 0.f);
    v.z = fmaxf(fmaf(v.z, scv.z, bbv.z), 0.f); v.w = fmaxf(fmaf(v.w, scv.w, bbv.w), 0.f);
    if (g != curg) {
      float* d = &vnt[(size_t)curg * Hc + c4];
      atomicAdd(d, acc.x); atomicAdd(d + 1, acc.y); atomicAdd(d + 2, acc.z); atomicAdd(d + 3, acc.w);
      acc = make_float4(0.f, 0.f, 0.f, 0.f);
      curg = g;
    }
    acc.x += v.x; acc.y += v.y; acc.z += v.z; acc.w += v.w;
  }
  float* d = &vnt[(size_t)curg * Hc + c4];
  atomicAdd(d, acc.x); atomicAdd(d + 1, acc.y); atomicAdd(d + 2, acc.z); atomicAdd(d + 3, acc.w);
}

// ---- VN elementwise relu(bn(.)) fp32->fp32 ----
__global__ __launch_bounds__(256) void k_vn_relu(const float* __restrict__ in, float* __restrict__ out,
                                                 const float* __restrict__ stats,
                                                 const float* __restrict__ gamma, const float* __restrict__ beta,
                                                 float invM) {
  int idx = blockIdx.x * 256 + threadIdx.x;
  int c = idx & (Hc - 1);
  float mu = stats[c] * invM;
  float var = stats[Hc + c] * invM - mu * mu;
  float sc = rsqrtf(var + BN_EPS) * gamma[c];
  float bb = beta[c] - mu * sc;
  out[idx] = fmaxf(fmaf(in[idx], sc, bb), 0.f);
}

// ---- final bn + global_add_pool (out pre-zeroed). 1 wave / 64 rows.
__global__ __launch_bounds__(256) void k_bn_pool(const bf16* __restrict__ P, const int* __restrict__ batch,
                                                 float* __restrict__ out, const float* __restrict__ stats,
                                                 const float* __restrict__ gamma, const float* __restrict__ beta,
                                                 float invM) {
  int wave = threadIdx.x >> 6, lane = threadIdx.x & 63;
  int base = (blockIdx.x * 4 + wave) * 64;
  if (base >= Ncnt) return;
  int c4 = lane * 4;
  float4 sv = *(const float4*)&stats[c4];
  float4 qv = *(const float4*)&stats[Hc + c4];
  float4 gv = *(const float4*)&gamma[c4];
  float4 bv = *(const float4*)&beta[c4];
  float4 scv, bbv;
  float mu, var;
  mu = sv.x * invM; var = qv.x * invM - mu * mu; scv.x = rsqrtf(var + BN_EPS) * gv.x; bbv.x = bv.x - mu * scv.x;
  mu = sv.y * invM; var = qv.y * invM - mu * mu; scv.y = rsqrtf(var + BN_EPS) * gv.y; bbv.y = bv.y - mu * scv.y;
  mu = sv.z * invM; var = qv.z * invM - mu * mu; scv.z = rsqrtf(var + BN_EPS) * gv.z; bbv.z = bv.z - mu * scv.z;
  mu = sv.w * invM; var = qv.w * invM - mu * mu; scv.w = rsqrtf(var + BN_EPS) * gv.w; bbv.w = bv.w - mu * scv.w;
  int end = imin(base + 64, Ncnt);
  float4 acc = make_float4(0.f, 0.f, 0.f, 0.f);
  int curg = batch[base];
  for (int r = base; r < end; ++r) {
    int g = batch[r];
    float4 v = bf4tof4(*(const ushort4*)&P[(size_t)r * Hc + c4]);
    v.x = fmaf(v.x, scv.x, bbv.x); v.y = fmaf(v.y, scv.y, bbv.y);
    v.z = fmaf(v.z, scv.z, bbv.z); v.w = fmaf(v.w, scv.w, bbv.w);
    if (g != curg) {
      float* d = &out[(size_t)curg * Hc + c4];
      atomicAdd(d, acc.x); atomicAdd(d + 1, acc.y); atomicAdd(d + 2, acc.z); atomicAdd(d + 3, acc.w);
      acc = make_float4(0.f, 0.f, 0.f, 0.f);
      curg = g;
    }
    acc.x += v.x; acc.y += v.y; acc.z += v.z; acc.w += v.w;
  }
  float* d = &out[(size_t)curg * Hc + c4];
  atomicAdd(d, acc.x); atomicAdd(d + 1, acc.y); atomicAdd(d + 2, acc.z); atomicAdd(d + 3, acc.w);
}

// ---- MFMA node GEMM: C[M,256] = A @ (Whi+Wlo) + bias (+R), fused BN-stats.
// 256-wide tile (A fetched once). A: LDS-staged (gll16, XOR swizzle). B: fragment-packed
// direct-global (L2-resident). Epilogue: fragments -> fp32 LDS tile -> coalesced
// R-add + ushort8 C store + per-thread 8-col stats -> LDS reduce -> global atomics.
__global__ __launch_bounds__(256, 2) void k_gemm_mfma(const bf16* __restrict__ A, const bf16* __restrict__ Whi,
                                                      const bf16* __restrict__ Wlo, const float* __restrict__ bias,
                                                      const bf16* __restrict__ R, bf16* __restrict__ C,
                                                      float* __restrict__ stats, int M) {
  __shared__ __attribute__((aligned(16))) short As[128 * 64];
  __shared__ __attribute__((aligned(16))) float Cs[32 * 258];
  __shared__ float lsum[256], lsq[256];
  int tid = threadIdx.x;
  int wave = tid >> 6, lane = tid & 63;
  int quad = lane >> 4, l15 = lane & 15;
  int wr = (wave & 1) * 64;       // row half
  int wc = (wave >> 1) * 128;     // col half
  int row0 = blockIdx.x * 128;

  lsum[tid] = 0.f;
  lsq[tid] = 0.f;

  int sr[4], sjg[4];
#pragma unroll
  for (int i = 0; i < 4; ++i) {
    int s = i * 256 + tid;
    sr[i] = s >> 3;
    sjg[i] = (s & 7) ^ (sr[i] & 7);
  }

  f32x4 acc[4][8];
#pragma unroll
  for (int i = 0; i < 4; ++i)
#pragma unroll
    for (int j = 0; j < 8; ++j) acc[i][j] = (f32x4){0.f, 0.f, 0.f, 0.f};

  for (int kci = 0; kci < 4; ++kci) {
    int kc = kci * 64;
#pragma unroll
    for (int i = 0; i < 4; ++i) {
      int ar = row0 + sr[i]; if (ar >= M) ar = M - 1;  // clamp: garbage rows never stored
      gll16(A + (size_t)ar * Hc + kc + sjg[i] * 8, &As[(i * 256 + wave * 64) * 8]);
    }
    __syncthreads();
#pragma unroll
    for (int ks = 0; ks < 2; ++ks) {
      int kc8 = kci * 2 + ks;
      int g = ks * 4 + quad;
      bf16x8 af[4];
#pragma unroll
      for (int mi = 0; mi < 4; ++mi) {
        int row = wr + mi * 16 + l15;
        af[mi] = *(const bf16x8*)&As[row * 64 + (g ^ (row & 7)) * 8];
      }
#pragma unroll
      for (int nii = 0; nii < 8; ++nii) {
        int nt = (wave >> 1) * 8 + nii;
        size_t fo = (((size_t)nt * 8 + kc8) * 64 + lane) * 8;
        bf16x8 bh = *(const bf16x8*)&Whi[fo];
        bf16x8 bl = *(const bf16x8*)&Wlo[fo];
#pragma unroll
        for (int mi = 0; mi < 4; ++mi) {
          acc[mi][nii] = __builtin_amdgcn_mfma_f32_16x16x32_bf16(af[mi], bh, acc[mi][nii], 0, 0, 0);
          acc[mi][nii] = __builtin_amdgcn_mfma_f32_16x16x32_bf16(af[mi], bl, acc[mi][nii], 0, 0, 0);
        }
      }
    }
    __syncthreads();
  }

  // ---- epilogue: 4 passes of 32 rows (16 from each row-half) ----
  float s8[8], q8[8];
#pragma unroll
  for (int k = 0; k < 8; ++k) { s8[k] = 0.f; q8[k] = 0.f; }
  int c8 = (tid & 31) * 8;

  for (int p = 0; p < 4; ++p) {
    int lr0 = (wave & 1) * 16 + quad * 4;
#pragma unroll
    for (int ni = 0; ni < 8; ++ni) {
      int col = wc + ni * 16 + l15;
      float bcol = bias[col];
#pragma unroll
      for (int j = 0; j < 4; ++j)
        Cs[(lr0 + j) * 258 + col] = acc[p][ni][j] + bcol;
    }
    __syncthreads();
#pragma unroll
    for (int i = 0; i < 4; ++i) {
      int gsl = i * 256 + tid;
      int lr = gsl >> 5;
      int grow = row0 + ((lr < 16) ? p * 16 + lr : 48 + p * 16 + lr);
      if (grow < M) {
        const float* src = &Cs[lr * 258 + c8];
        float v[8];
#pragma unroll
        for (int k = 0; k < 8; ++k) v[k] = src[k];
        if (R) {
          u16x8 rv = *(const u16x8*)&R[(size_t)grow * Hc + c8];
#pragma unroll
          for (int k = 0; k < 8; ++k) v[k] += bs2f(rv[k]);
        }
        u16x8 ov;
#pragma unroll
        for (int k = 0; k < 8; ++k) {
          ov[k] = f2bs(v[k]);
          s8[k] += v[k];
          q8[k] = fmaf(v[k], v[k], q8[k]);
        }
        *(u16x8*)&C[(size_t)grow * Hc + c8] = ov;
      }
    }
    __syncthreads();
  }

#pragma unroll
  for (int k = 0; k < 8; ++k) {
    atomicAdd(&lsum[c8 + k], s8[k]);
    atomicAdd(&lsq[c8 + k], q8[k]);
  }
  __syncthreads();
  atomicAdd(&stats[tid], lsum[tid]);
  atomicAdd(&stats[Hc + tid], lsq[tid]);
}

// ---- fp32 SIMT GEMM for VN MLP: C[M,256] = act(A) @ W + bias, fused stats.
// act(A) = relu(bn(A)) via statsIn/gIn/bIn if statsIn != null, else identity.
__global__ __launch_bounds__(256) void k_gemm_f32(const float* __restrict__ A, const float* __restrict__ W,
                                                  const float* __restrict__ bias, float* __restrict__ C,
                                                  float* __restrict__ statsOut,
                                                  const float* __restrict__ statsIn,
                                                  const float* __restrict__ gIn, const float* __restrict__ bIn,
                                                  float invM, int M) {
  __shared__ float As[64][68];
  __shared__ float Ws[64][68];
  __shared__ float lsum[64], lsq[64];
  int tid = threadIdx.x;
  int row0 = blockIdx.x * 64;
  int col0 = blockIdx.y * 64;
  int tx = tid & 15, ty = tid >> 4;
  if (tid < 64) { lsum[tid] = 0.f; lsq[tid] = 0.f; }
  float acc[4][4] = {{0.f}};
  for (int k0 = 0; k0 < 256; k0 += 64) {
#pragma unroll
    for (int i = 0; i < 4; ++i) {
      int lin = tid + i * 256;
      int r = lin >> 4;
      int c4 = (lin & 15) << 2;
      int gr = row0 + r;
      float4 v = make_float4(0.f, 0.f, 0.f, 0.f);
      if (gr < M) v = *(const float4*)&A[(size_t)gr * Hc + k0 + c4];
      if (statsIn) {
        float4 sv = *(const float4*)&statsIn[k0 + c4];
        float4 qv = *(const float4*)&statsIn[Hc + k0 + c4];
        float4 gv = *(const float4*)&gIn[k0 + c4];
        float4 bv = *(const float4*)&bIn[k0 + c4];
        float mu, var, sc, bb;
        mu = sv.x * invM; var = qv.x * invM - mu * mu; sc = rsqrtf(var + BN_EPS) * gv.x; bb = bv.x - mu * sc;
        v.x = fmaxf(fmaf(v.x, sc, bb), 0.f);
        mu = sv.y * invM; var = qv.y * invM - mu * mu; sc = rsqrtf(var + BN_EPS) * gv.y; bb = bv.y - mu * sc;
        v.y = fmaxf(fmaf(v.y, sc, bb), 0.f);
        mu = sv.z * invM; var = qv.z * invM - mu * mu; sc = rsqrtf(var + BN_EPS) * gv.z; bb = bv.z - mu * sc;
        v.z = fmaxf(fmaf(v.z, sc, bb), 0.f);
        mu = sv.w * invM; var = qv.w * invM - mu * mu; sc = rsqrtf(var + BN_EPS) * gv.w; bb = bv.w - mu * sc;
        v.w = fmaxf(fmaf(v.w, sc, bb), 0.f);
      }
      As[r][c4] = v.x; As[r][c4 + 1] = v.y; As[r][c4 + 2] = v.z; As[r][c4 + 3] = v.w;
      float4 w = *(const float4*)&W[(size_t)(k0 + r) * Hc + col0 + c4];
      Ws[r][c4] = w.x; Ws[r][c4 + 1] = w.y; Ws[r][c4 + 2] = w.z; Ws[r][c4 + 3] = w.w;
    }
    __syncthreads();
#pragma unroll
    for (int k = 0; k < 64; ++k) {
      float a[4], w[4];
#pragma unroll
      for (int i = 0; i < 4; ++i) a[i] = As[ty * 4 + i][k];
#pragma unroll
      for (int j = 0; j < 4; ++j) w[j] = Ws[k][tx * 4 + j];
#pragma unroll
      for (int i = 0; i < 4; ++i)
#pragma unroll
        for (int j = 0; j < 4; ++j) acc[i][j] = fmaf(a[i], w[j], acc[i][j]);
    }
    __syncthreads();
  }
  float cs[4] = {0.f, 0.f, 0.f, 0.f}, cq[4] = {0.f, 0.f, 0.f, 0.f};
#pragma unroll
  for (int i = 0; i < 4; ++i) {
    int gr = row0 + ty * 4 + i;
    if (gr >= M) break;
#pragma unroll
    for (int j = 0; j < 4; ++j) {
      int gc = col0 + tx * 4 + j;
      float v = acc[i][j] + bias[gc];
      C[(size_t)gr * Hc + gc] = v;
      cs[j] += v;
      cq[j] = fmaf(v, v, cq[j]);
    }
  }
#pragma unroll
  for (int j = 0; j < 4; ++j) {
    atomicAdd(&lsum[tx * 4 + j], cs[j]);
    atomicAdd(&lsq[tx * 4 + j], cq[j]);
  }
  __syncthreads();
  if (tid < 64) {
    atomicAdd(&statsOut[col0 + tid], lsum[tid]);
    atomicAdd(&statsOut[Hc + col0 + tid], lsq[tid]);
  }
}

extern "C" void kernel_launch(void* const* d_in, const int* in_sizes, int n_in,
                              void* d_out, int out_size, void* d_ws, size_t ws_size,
                              hipStream_t stream) {
  const int* x = (const int*)d_in[0];
  const int* ei = (const int*)d_in[1];
  const int* ea = (const int*)d_in[2];
  const int* batch = (const int*)d_in[3];
  const float* aemb = (const float*)d_in[4];
  const float* bemb = (const float*)d_in[5];
  const float* vnw = (const float*)d_in[6];
  const float* conv_w = (const float*)d_in[7];
  const float* conv_b = (const float*)d_in[8];
  const float* ngamma = (const float*)d_in[9];
  const float* nbeta = (const float*)d_in[10];
  const float* vn_w = (const float*)d_in[11];
  const float* vn_b = (const float*)d_in[12];
  const float* vn_g = (const float*)d_in[13];
  const float* vn_be = (const float*)d_in[14];
  float* out = (float*)d_out;

  const size_t NODE = (size_t)Ncnt * Hc;
  const size_t GH = (size_t)Gcnt * Hc;
  const int nScanBlk = (Ncnt + 255) / 256;  // 586

  size_t off = 0;
  char* base = (char*)d_ws;
  auto take = [&](size_t bytes) { size_t o = off; off += (bytes + 15) & ~(size_t)15; return o; };
  float* vn = (float*)(base + take(GH * 4));
  float* vnt = (float*)(base + take(GH * 4));
  float* vnu = (float*)(base + take(GH * 4));
  float* vnv = (float*)(base + take(GH * 4));
  float* statsN = (float*)(base + take(2 * Hc * 4));
  float* statsV1 = (float*)(base + take(2 * Hc * 4));
  float* statsV2 = (float*)(base + take(2 * Hc * 4));
  int* rowptr = (int*)(base + take((size_t)(Ncnt + 1) * 4));
  int* cursor = (int*)(base + take((size_t)Ncnt * 4));
  int* eidx = (int*)(base + take((size_t)Ecnt * 4));
  int* bsum = (int*)(base + take((size_t)nScanBlk * 4));
  bf16* P = (bf16*)(base + take(NODE * 2));
  bf16* T = (bf16*)(base + take(NODE * 2));
  bf16* WhiC = (bf16*)(base + take((size_t)Lcnt * 65536 * 2));
  bf16* WloC = (bf16*)(base + take((size_t)Lcnt * 65536 * 2));
  const size_t NEED = off;
  if (ws_size < NEED) {
    k_zero<<<(int)((GH + 255) / 256), 256, 0, stream>>>(out, (int)GH);
    k_diag<<<1, 1, 0, stream>>>(out, 100000.f + (float)(ws_size / (1024.0 * 1024.0)));
    return;
  }

  const int eBlk = (Ecnt + 255) / 256;
  const int nWaveBlk = (Ncnt + 3) / 4;
  const int segBlk = (Ncnt + 255) / 256;
  const int ggN = (Ncnt + 127) / 128;      // 1172, 1-D
  const dim3 gv(Gcnt / 64, 4);
  const float invN = 1.f / Ncnt;
  const float invG = 1.f / Gcnt;

  // CSR build (parallel scan)
  k_zero_int<<<nScanBlk, 256, 0, stream>>>(cursor, Ncnt);
  k_count<<<eBlk, 256, 0, stream>>>(ei, cursor);
  k_scan1<<<nScanBlk, 256, 0, stream>>>(cursor, rowptr, bsum, Ncnt);
  k_scan2<<<1, 1024, 0, stream>>>(bsum, nScanBlk);
  k_scan3<<<nScanBlk, 256, 0, stream>>>(rowptr, cursor, bsum, Ncnt);
  k_scatter<<<eBlk, 256, 0, stream>>>(ei, cursor, eidx);

  // conv weight prep (hi/lo, fragment-packed)
  k_prep_w<<<(Lcnt * 8192 + 255) / 256, 256, 0, stream>>>(conv_w, WhiC, WloC, Lcnt);

  // Encoders + conv0 (stats fused for layer-1 BN)
  k_atom_encode<<<nWaveBlk, 256, 0, stream>>>(x, aemb, vnw, P);
  k_init_vn<<<(int)(GH / 256), 256, 0, stream>>>(vn, vnw);
  k_agg<<<nWaveBlk, 256, 0, stream>>>(P, T, rowptr, eidx, ei, ea, bemb,
                                      nullptr, nullptr, nullptr, nullptr, nullptr, 0.f);
  k_zero<<<2, 256, 0, stream>>>(statsN, 2 * Hc);
  k_gemm_mfma<<<ggN, 256, 0, stream>>>(T, WhiC, WloC, conv_b, nullptr, P, statsN, Ncnt);

  for (int l = 1; l < Lcnt; ++l) {
    int p = l - 1;
    const float* g = ngamma + (size_t)p * Hc;
    const float* b = nbeta + (size_t)p * Hc;
    // vn_t = vn + segsum(relu(bn(P)))
    k_copy4<<<(int)(GH / 1024), 256, 0, stream>>>(vnt, vn, (int)(GH / 4));
    k_seg_vn<<<segBlk, 256, 0, stream>>>(P, batch, vnt, statsN, g, b, invN);
    // VN MLP j=0: vnu = vnt @ w0 + b0 (stats -> V1)
    k_zero<<<2, 256, 0, stream>>>(statsV1, 2 * Hc);
    k_gemm_f32<<<gv, 256, 0, stream>>>(vnt, vn_w + (size_t)(2 * p) * 65536,
                                       vn_b + (size_t)(2 * p) * Hc, vnu, statsV1,
                                       nullptr, nullptr, nullptr, invG, Gcnt);
    // VN MLP j=1: vnv = relu(bnV1(vnu)) @ w1 + b1 (stats -> V2)
    k_zero<<<2, 256, 0, stream>>>(statsV2, 2 * Hc);
    k_gemm_f32<<<gv, 256, 0, stream>>>(vnu, vn_w + (size_t)(2 * p + 1) * 65536,
                                       vn_b + (size_t)(2 * p + 1) * Hc, vnv, statsV2,
                                       statsV1, vn_g + (size_t)(2 * p) * Hc,
                                       vn_be + (size_t)(2 * p) * Hc, invG, Gcnt);
    // vn = relu(bnV2(vnv))
    k_vn_relu<<<(int)(GH / 256), 256, 0, stream>>>(vnv, vn, statsV2,
                                                   vn_g + (size_t)(2 * p + 1) * Hc,
                                                   vn_be + (size_t)(2 * p + 1) * Hc, invG);
    // T = h2 + agg(h2), h2 = relu(bn(P)) + vn[batch]
    k_agg<<<nWaveBlk, 256, 0, stream>>>(P, T, rowptr, eidx, ei, ea, bemb, vn, batch, statsN, g, b, invN);
    // P = T @ W + bias + P (stats fused for next BN)
    k_zero<<<2, 256, 0, stream>>>(statsN, 2 * Hc);
    k_gemm_mfma<<<ggN, 256, 0, stream>>>(T, WhiC + (size_t)l * 65536, WloC + (size_t)l * 65536,
                                         conv_b + (size_t)l * Hc, P, P, statsN, Ncnt);
  }

  // Final BN + global add pool
  k_zero<<<(int)((GH + 255) / 256), 256, 0, stream>>>(out, (int)GH);
  k_bn_pool<<<segBlk, 256, 0, stream>>>(P, batch, out, statsN,
                                        ngamma + (size_t)(Lcnt - 1) * Hc, nbeta + (size_t)(Lcnt - 1) * Hc,
                                        invN);
}

// Round 10
// 2290.860 us; speedup vs baseline: 2.1783x; 1.1060x over previous
//
#include <hip/hip_runtime.h>
#include <hip/hip_bf16.h>

// DeeperGCN on MI355X — round 10: k_agg rewrite — packed edge records (src+attrs+graph
// in one int2, 2-level gather chain), half-wave per node (32 lanes x ushort8),
// precomputed BN scale/bias (k_bnprep). GEMMs unchanged from round 9.
// N=150000, E=300000, G=4096, H=256, L=7.

#define Ncnt 150000
#define Ecnt 300000
#define Gcnt 4096
#define Hc 256
#define Lcnt 7
#define BN_EPS 1e-5f
#define MSG_EPS 1e-7f

typedef __hip_bfloat16 bf16;
typedef __attribute__((ext_vector_type(8))) short bf16x8;
typedef __attribute__((ext_vector_type(8))) unsigned short u16x8;
typedef __attribute__((ext_vector_type(4))) float f32x4;

static __device__ __forceinline__ int imin(int a, int b) { return a < b ? a : b; }

static __device__ __forceinline__ float bs2f(unsigned short s) {
  unsigned u = ((unsigned)s) << 16;
  union { unsigned u; float f; } c; c.u = u; return c.f;
}
static __device__ __forceinline__ unsigned short f2bs(float f) {
  bf16 h = __float2bfloat16(f);
  union { bf16 h; unsigned short s; } c; c.h = h; return c.s;
}
static __device__ __forceinline__ float4 bf4tof4(ushort4 u) {
  float4 r; r.x = bs2f(u.x); r.y = bs2f(u.y); r.z = bs2f(u.z); r.w = bs2f(u.w); return r;
}
static __device__ __forceinline__ ushort4 f4tobf4(float4 v) {
  ushort4 u; u.x = f2bs(v.x); u.y = f2bs(v.y); u.z = f2bs(v.z); u.w = f2bs(v.w); return u;
}

// async global->LDS, 16B per lane; lds dst must be the wave-uniform chunk base.
static __device__ __forceinline__ void gll16(const bf16* g, const short* l) {
  __builtin_amdgcn_global_load_lds((const __attribute__((address_space(1))) void*)g,
                                   (__attribute__((address_space(3))) void*)l, 16, 0, 0);
}

__global__ __launch_bounds__(256) void k_zero(float* __restrict__ p, int n) {
  int i = blockIdx.x * 256 + threadIdx.x;
  if (i < n) p[i] = 0.f;
}
__global__ __launch_bounds__(256) void k_zero_int(int* __restrict__ p, int n) {
  int i = blockIdx.x * 256 + threadIdx.x;
  if (i < n) p[i] = 0;
}
__global__ __launch_bounds__(256) void k_copy4(float* __restrict__ dst, const float* __restrict__ src, int n4) {
  int i = blockIdx.x * 256 + threadIdx.x;
  if (i < n4) ((float4*)dst)[i] = ((const float4*)src)[i];
}
__global__ void k_diag(float* __restrict__ out, float v) { out[0] = v; }

// ---- BN scale/bias precompute: scb = rsqrt(var+eps)*gamma, bbb = beta - mu*scb ----
__global__ __launch_bounds__(256) void k_bnprep(const float* __restrict__ stats,
                                                const float* __restrict__ gamma, const float* __restrict__ beta,
                                                float* __restrict__ scb, float* __restrict__ bbb, float invM) {
  int c = threadIdx.x;
  float mu = stats[c] * invM;
  float var = stats[Hc + c] * invM - mu * mu;
  float sc = rsqrtf(var + BN_EPS) * gamma[c];
  scb[c] = sc;
  bbb[c] = beta[c] - mu * sc;
}

// ---- CSR build (counting sort by dst) ----
__global__ __launch_bounds__(256) void k_count(const int* __restrict__ ei, int* __restrict__ cnt) {
  int e = blockIdx.x * 256 + threadIdx.x;
  if (e < Ecnt) atomicAdd(&cnt[ei[Ecnt + e]], 1);
}
__global__ __launch_bounds__(256) void k_scan1(const int* __restrict__ cnt, int* __restrict__ rowptr,
                                               int* __restrict__ bsum, int n) {
  __shared__ int sh[256];
  int t = threadIdx.x;
  int i = blockIdx.x * 256 + t;
  int v = (i < n) ? cnt[i] : 0;
  sh[t] = v;
  __syncthreads();
#pragma unroll
  for (int off = 1; off < 256; off <<= 1) {
    int u = (t >= off) ? sh[t - off] : 0;
    __syncthreads();
    sh[t] += u;
    __syncthreads();
  }
  if (i < n) rowptr[i] = sh[t] - v;
  if (t == 255) bsum[blockIdx.x] = sh[255];
}
__global__ __launch_bounds__(1024) void k_scan2(int* __restrict__ bsum, int nb) {
  __shared__ int sh[1024];
  int t = threadIdx.x;
  int v = (t < nb) ? bsum[t] : 0;
  sh[t] = v;
  __syncthreads();
#pragma unroll
  for (int off = 1; off < 1024; off <<= 1) {
    int u = (t >= off) ? sh[t - off] : 0;
    __syncthreads();
    sh[t] += u;
    __syncthreads();
  }
  if (t < nb) bsum[t] = sh[t] - v;
}
__global__ __launch_bounds__(256) void k_scan3(int* __restrict__ rowptr, int* __restrict__ cursor,
                                               const int* __restrict__ bsum, int n) {
  int i = blockIdx.x * 256 + threadIdx.x;
  if (i < n) {
    int v = rowptr[i] + bsum[blockIdx.x];
    rowptr[i] = v;
    cursor[i] = v;
  }
  if (i == 0) rowptr[n] = Ecnt;
}
// scatter packed edge records: erec[pos] = (src, a0 | a1<<3 | a2<<6 | batch[src]<<9)
__global__ __launch_bounds__(256) void k_scatter(const int* __restrict__ ei, const int* __restrict__ ea,
                                                 const int* __restrict__ batch, int* __restrict__ cursor,
                                                 int2* __restrict__ erec) {
  int e = blockIdx.x * 256 + threadIdx.x;
  if (e < Ecnt) {
    int d = ei[Ecnt + e];
    int s = ei[e];
    int packed = ea[e * 3] | (ea[e * 3 + 1] << 3) | (ea[e * 3 + 2] << 6) | (batch[s] << 9);
    int pos = atomicAdd(&cursor[d], 1);
    erec[pos] = make_int2(s, packed);
  }
}

// ---- weight prep: conv W[k][n] fp32 -> fragment-packed bf16 hi/lo. ----
__global__ __launch_bounds__(256) void k_prep_w(const float* __restrict__ W, bf16* __restrict__ hi,
                                                bf16* __restrict__ lo, int nmats) {
  int c = blockIdx.x * 256 + threadIdx.x;
  if (c >= nmats * 8192) return;
  int lane = c & 63;
  int t = c >> 6;
  int kc8 = t & 7;
  int nt = (t >> 3) & 15;
  int m = t >> 7;
  int n = nt * 16 + (lane & 15);
  int k0 = kc8 * 32 + (lane >> 4) * 8;
  bf16x8 hv, lv;
#pragma unroll
  for (int j = 0; j < 8; ++j) {
    float w = W[(size_t)m * 65536 + (size_t)(k0 + j) * 256 + n];
    unsigned short h = f2bs(w);
    float res = w - bs2f(h);
    hv[j] = (short)h;
    lv[j] = (short)f2bs(res);
  }
  *(bf16x8*)&hi[(size_t)c * 8] = hv;
  *(bf16x8*)&lo[(size_t)c * 8] = lv;
}

// ---- encoders (1 wave per node, 4 ch/lane) ----
__global__ __launch_bounds__(256) void k_atom_encode(const int* __restrict__ x,
                                                     const float* __restrict__ aemb,
                                                     const float* __restrict__ vnw,
                                                     bf16* __restrict__ P) {
  int wave = threadIdx.x >> 6, lane = threadIdx.x & 63;
  int r = blockIdx.x * 4 + wave;
  if (r >= Ncnt) return;
  int c4 = lane * 4;
  const int* xr = x + (size_t)r * 9;
  float4 v = *(const float4*)&vnw[c4];
#pragma unroll
  for (int f = 0; f < 9; ++f) {
    float4 e = *(const float4*)&aemb[(size_t)((f << 6) + xr[f]) * Hc + c4];
    v.x += e.x; v.y += e.y; v.z += e.z; v.w += e.w;
  }
  *(ushort4*)&P[(size_t)r * Hc + c4] = f4tobf4(v);
}

__global__ __launch_bounds__(256) void k_init_vn(float* __restrict__ vn, const float* __restrict__ vnw) {
  int idx = blockIdx.x * 256 + threadIdx.x;  // G*Hc total
  vn[idx] = vnw[idx & (Hc - 1)];
}

// ---- aggregation: T[r] = h2(r) + sum_{e: dst=r} (relu(h2(src)+bond_emb)+eps)
// h2(n) = P[n] (scb==null) or relu(bn(P[n]))+vn[batch[n]].  Half-wave (32 lanes) per node, 8 ch/lane.
__global__ __launch_bounds__(256) void k_agg(const bf16* __restrict__ P, bf16* __restrict__ T,
                                             const int* __restrict__ rowptr, const int2* __restrict__ erec,
                                             const float* __restrict__ bemb,
                                             const float* __restrict__ vn, const int* __restrict__ batch,
                                             const float* __restrict__ scb, const float* __restrict__ bbb) {
  int hw = threadIdx.x >> 5, lane = threadIdx.x & 31;
  int r = blockIdx.x * 8 + hw;
  if (r >= Ncnt) return;
  int c8 = lane * 8;
  bool hasbn = (scb != nullptr);
  float sc[8], bb[8];
  if (hasbn) {
    float4 s0 = *(const float4*)&scb[c8], s1 = *(const float4*)&scb[c8 + 4];
    float4 b0 = *(const float4*)&bbb[c8], b1 = *(const float4*)&bbb[c8 + 4];
    sc[0] = s0.x; sc[1] = s0.y; sc[2] = s0.z; sc[3] = s0.w;
    sc[4] = s1.x; sc[5] = s1.y; sc[6] = s1.z; sc[7] = s1.w;
    bb[0] = b0.x; bb[1] = b0.y; bb[2] = b0.z; bb[3] = b0.w;
    bb[4] = b1.x; bb[5] = b1.y; bb[6] = b1.z; bb[7] = b1.w;
  }
  float acc[8];
  {
    u16x8 pv = *(const u16x8*)&P[(size_t)r * Hc + c8];
    if (hasbn) {
      const float* vr = &vn[(size_t)batch[r] * Hc + c8];
      float4 w0 = *(const float4*)vr, w1 = *(const float4*)(vr + 4);
      float w[8] = {w0.x, w0.y, w0.z, w0.w, w1.x, w1.y, w1.z, w1.w};
#pragma unroll
      for (int k = 0; k < 8; ++k) acc[k] = fmaxf(fmaf(bs2f(pv[k]), sc[k], bb[k]), 0.f) + w[k];
    } else {
#pragma unroll
      for (int k = 0; k < 8; ++k) acc[k] = bs2f(pv[k]);
    }
  }
  int j0 = rowptr[r], j1 = rowptr[r + 1];
  if (j0 < j1) {
    int2 er = erec[j0];
    for (int j = j0; j < j1; ++j) {
      int2 ern = (j + 1 < j1) ? erec[j + 1] : er;  // prefetch next record
      int s = er.x;
      int a0 = er.y & 7, a1 = (er.y >> 3) & 7, a2 = (er.y >> 6) & 7, g = er.y >> 9;
      u16x8 sv = *(const u16x8*)&P[(size_t)s * Hc + c8];
      const float* e0 = &bemb[(size_t)a0 * Hc + c8];
      const float* e1 = &bemb[(size_t)(8 + a1) * Hc + c8];
      const float* e2 = &bemb[(size_t)(16 + a2) * Hc + c8];
      float4 e0a = *(const float4*)e0, e0b = *(const float4*)(e0 + 4);
      float4 e1a = *(const float4*)e1, e1b = *(const float4*)(e1 + 4);
      float4 e2a = *(const float4*)e2, e2b = *(const float4*)(e2 + 4);
      float em[8] = {e0a.x + e1a.x + e2a.x, e0a.y + e1a.y + e2a.y,
                     e0a.z + e1a.z + e2a.z, e0a.w + e1a.w + e2a.w,
                     e0b.x + e1b.x + e2b.x, e0b.y + e1b.y + e2b.y,
                     e0b.z + e1b.z + e2b.z, e0b.w + e1b.w + e2b.w};
      if (hasbn) {
        const float* vr = &vn[(size_t)g * Hc + c8];
        float4 w0 = *(const float4*)vr, w1 = *(const float4*)(vr + 4);
        float w[8] = {w0.x, w0.y, w0.z, w0.w, w1.x, w1.y, w1.z, w1.w};
#pragma unroll
        for (int k = 0; k < 8; ++k) {
          float v = fmaxf(fmaf(bs2f(sv[k]), sc[k], bb[k]), 0.f) + w[k];
          acc[k] += fmaxf(v + em[k], 0.f) + MSG_EPS;
        }
      } else {
#pragma unroll
        for (int k = 0; k < 8; ++k)
          acc[k] += fmaxf(bs2f(sv[k]) + em[k], 0.f) + MSG_EPS;
      }
      er = ern;
    }
  }
  u16x8 ov;
#pragma unroll
  for (int k = 0; k < 8; ++k) ov[k] = f2bs(acc[k]);
  *(u16x8*)&T[(size_t)r * Hc + c8] = ov;
}

// ---- segment-sum of relu(bn(P)) by sorted batch into vnt (pre-init with vn). 1 wave / 64 rows.
__global__ __launch_bounds__(256) void k_seg_vn(const bf16* __restrict__ P, const int* __restrict__ batch,
                                                float* __restrict__ vnt,
                                                const float* __restrict__ scb, const float* __restrict__ bbb) {
  int wave = threadIdx.x >> 6, lane = threadIdx.x & 63;
  int base = (blockIdx.x * 4 + wave) * 64;
  if (base >= Ncnt) return;
  int c4 = lane * 4;
  float4 scv = *(const float4*)&scb[c4];
  float4 bbv = *(const float4*)&bbb[c4];
  int end = imin(base + 64, Ncnt);
  float4 acc = make_float4(0.f, 0.f, 0.f, 0.f);
  int curg = batch[base];
  for (int r = base; r < end; ++r) {
    int g = batch[r];
    float4 v = bf4tof4(*(const ushort4*)&P[(size_t)r * Hc + c4]);
    v.x = fmaxf(fmaf(v.x, scv.x, bbv.x), 0.f); v.y = fmaxf(fmaf(v.y, scv.y, bbv.y), 0.f);
    v.z = fmaxf(fmaf(v.z, scv.z, bbv.z), 0.f); v.w = fmaxf(fmaf(v.w, scv.w, bbv.w), 0.f);
    if (g != curg) {
      float* d = &vnt[(size_t)curg * Hc + c4];
      atomicAdd(d, acc.x); atomicAdd(d + 1, acc.y); atomicAdd(d + 2, acc.z); atomicAdd(d + 3, acc.w);
      acc = make_float4(0.f, 0.f, 0.f, 0.f);
      curg = g;
    }
    acc.x += v.x; acc.y += v.y; acc.z += v.z; acc.w += v.w;
  }
  float* d = &vnt[(size_t)curg * Hc + c4];
  atomicAdd(d, acc.x); atomicAdd(d + 1, acc.y); atomicAdd(d + 2, acc.z); atomicAdd(d + 3, acc.w);
}

// ---- VN elementwise relu(bn(.)) fp32->fp32 ----
__global__ __launch_bounds__(256) void k_vn_relu(const float* __restrict__ in, float* __restrict__ out,
                                                 const float* __restrict__ stats,
                                                 const float* __restrict__ gamma, const float* __restrict__ beta,
                                                 float invM) {
  int idx = blockIdx.x * 256 + threadIdx.x;
  int c = idx & (Hc - 1);
  float mu = stats[c] * invM;
  float var = stats[Hc + c] * invM - mu * mu;
  float sc = rsqrtf(var + BN_EPS) * gamma[c];
  float bb = beta[c] - mu * sc;
  out[idx] = fmaxf(fmaf(in[idx], sc, bb), 0.f);
}

// ---- final bn + global_add_pool (out pre-zeroed). 1 wave / 64 rows.
__global__ __launch_bounds__(256) void k_bn_pool(const bf16* __restrict__ P, const int* __restrict__ batch,
                                                 float* __restrict__ out,
                                                 const float* __restrict__ scb, const float* __restrict__ bbb) {
  int wave = threadIdx.x >> 6, lane = threadIdx.x & 63;
  int base = (blockIdx.x * 4 + wave) * 64;
  if (base >= Ncnt) return;
  int c4 = lane * 4;
  float4 scv = *(const float4*)&scb[c4];
  float4 bbv = *(const float4*)&bbb[c4];
  int end = imin(base + 64, Ncnt);
  float4 acc = make_float4(0.f, 0.f, 0.f, 0.f);
  int curg = batch[base];
  for (int r = base; r < end; ++r) {
    int g = batch[r];
    float4 v = bf4tof4(*(const ushort4*)&P[(size_t)r * Hc + c4]);
    v.x = fmaf(v.x, scv.x, bbv.x); v.y = fmaf(v.y, scv.y, bbv.y);
    v.z = fmaf(v.z, scv.z, bbv.z); v.w = fmaf(v.w, scv.w, bbv.w);
    if (g != curg) {
      float* d = &out[(size_t)curg * Hc + c4];
      atomicAdd(d, acc.x); atomicAdd(d + 1, acc.y); atomicAdd(d + 2, acc.z); atomicAdd(d + 3, acc.w);
      acc = make_float4(0.f, 0.f, 0.f, 0.f);
      curg = g;
    }
    acc.x += v.x; acc.y += v.y; acc.z += v.z; acc.w += v.w;
  }
  float* d = &out[(size_t)curg * Hc + c4];
  atomicAdd(d, acc.x); atomicAdd(d + 1, acc.y); atomicAdd(d + 2, acc.z); atomicAdd(d + 3, acc.w);
}

// ---- MFMA node GEMM (round-9, unchanged): C[M,256] = A @ (Whi+Wlo) + bias (+R), fused BN-stats.
__global__ __launch_bounds__(256, 2) void k_gemm_mfma(const bf16* __restrict__ A, const bf16* __restrict__ Whi,
                                                      const bf16* __restrict__ Wlo, const float* __restrict__ bias,
                                                      const bf16* __restrict__ R, bf16* __restrict__ C,
                                                      float* __restrict__ stats, int M) {
  __shared__ __attribute__((aligned(16))) short As[128 * 64];
  __shared__ __attribute__((aligned(16))) float Cs[32 * 258];
  __shared__ float lsum[256], lsq[256];
  int tid = threadIdx.x;
  int wave = tid >> 6, lane = tid & 63;
  int quad = lane >> 4, l15 = lane & 15;
  int wr = (wave & 1) * 64;       // row half
  int wc = (wave >> 1) * 128;     // col half
  int row0 = blockIdx.x * 128;

  lsum[tid] = 0.f;
  lsq[tid] = 0.f;

  int sr[4], sjg[4];
#pragma unroll
  for (int i = 0; i < 4; ++i) {
    int s = i * 256 + tid;
    sr[i] = s >> 3;
    sjg[i] = (s & 7) ^ (sr[i] & 7);
  }

  f32x4 acc[4][8];
#pragma unroll
  for (int i = 0; i < 4; ++i)
#pragma unroll
    for (int j = 0; j < 8; ++j) acc[i][j] = (f32x4){0.f, 0.f, 0.f, 0.f};

  for (int kci = 0; kci < 4; ++kci) {
    int kc = kci * 64;
#pragma unroll
    for (int i = 0; i < 4; ++i) {
      int ar = row0 + sr[i]; if (ar >= M) ar = M - 1;
      gll16(A + (size_t)ar * Hc + kc + sjg[i] * 8, &As[(i * 256 + wave * 64) * 8]);
    }
    __syncthreads();
#pragma unroll
    for (int ks = 0; ks < 2; ++ks) {
      int kc8 = kci * 2 + ks;
      int g = ks * 4 + quad;
      bf16x8 af[4];
#pragma unroll
      for (int mi = 0; mi < 4; ++mi) {
        int row = wr + mi * 16 + l15;
        af[mi] = *(const bf16x8*)&As[row * 64 + (g ^ (row & 7)) * 8];
      }
#pragma unroll
      for (int nii = 0; nii < 8; ++nii) {
        int nt = (wave >> 1) * 8 + nii;
        size_t fo = (((size_t)nt * 8 + kc8) * 64 + lane) * 8;
        bf16x8 bh = *(const bf16x8*)&Whi[fo];
        bf16x8 bl = *(const bf16x8*)&Wlo[fo];
#pragma unroll
        for (int mi = 0; mi < 4; ++mi) {
          acc[mi][nii] = __builtin_amdgcn_mfma_f32_16x16x32_bf16(af[mi], bh, acc[mi][nii], 0, 0, 0);
          acc[mi][nii] = __builtin_amdgcn_mfma_f32_16x16x32_bf16(af[mi], bl, acc[mi][nii], 0, 0, 0);
        }
      }
    }
    __syncthreads();
  }

  float s8[8], q8[8];
#pragma unroll
  for (int k = 0; k < 8; ++k) { s8[k] = 0.f; q8[k] = 0.f; }
  int c8 = (tid & 31) * 8;

  for (int p = 0; p < 4; ++p) {
    int lr0 = (wave & 1) * 16 + quad * 4;
#pragma unroll
    for (int ni = 0; ni < 8; ++ni) {
      int col = wc + ni * 16 + l15;
      float bcol = bias[col];
#pragma unroll
      for (int j = 0; j < 4; ++j)
        Cs[(lr0 + j) * 258 + col] = acc[p][ni][j] + bcol;
    }
    __syncthreads();
#pragma unroll
    for (int i = 0; i < 4; ++i) {
      int gsl = i * 256 + tid;
      int lr = gsl >> 5;
      int grow = row0 + ((lr < 16) ? p * 16 + lr : 48 + p * 16 + lr);
      if (grow < M) {
        const float* src = &Cs[lr * 258 + c8];
        float v[8];
#pragma unroll
        for (int k = 0; k < 8; ++k) v[k] = src[k];
        if (R) {
          u16x8 rv = *(const u16x8*)&R[(size_t)grow * Hc + c8];
#pragma unroll
          for (int k = 0; k < 8; ++k) v[k] += bs2f(rv[k]);
        }
        u16x8 ov;
#pragma unroll
        for (int k = 0; k < 8; ++k) {
          ov[k] = f2bs(v[k]);
          s8[k] += v[k];
          q8[k] = fmaf(v[k], v[k], q8[k]);
        }
        *(u16x8*)&C[(size_t)grow * Hc + c8] = ov;
      }
    }
    __syncthreads();
  }

#pragma unroll
  for (int k = 0; k < 8; ++k) {
    atomicAdd(&lsum[c8 + k], s8[k]);
    atomicAdd(&lsq[c8 + k], q8[k]);
  }
  __syncthreads();
  atomicAdd(&stats[tid], lsum[tid]);
  atomicAdd(&stats[Hc + tid], lsq[tid]);
}

// ---- fp32 SIMT GEMM for VN MLP (round-9, unchanged) ----
__global__ __launch_bounds__(256) void k_gemm_f32(const float* __restrict__ A, const float* __restrict__ W,
                                                  const float* __restrict__ bias, float* __restrict__ C,
                                                  float* __restrict__ statsOut,
                                                  const float* __restrict__ statsIn,
                                                  const float* __restrict__ gIn, const float* __restrict__ bIn,
                                                  float invM, int M) {
  __shared__ float As[64][68];
  __shared__ float Ws[64][68];
  __shared__ float lsum[64], lsq[64];
  int tid = threadIdx.x;
  int row0 = blockIdx.x * 64;
  int col0 = blockIdx.y * 64;
  int tx = tid & 15, ty = tid >> 4;
  if (tid < 64) { lsum[tid] = 0.f; lsq[tid] = 0.f; }
  float acc[4][4] = {{0.f}};
  for (int k0 = 0; k0 < 256; k0 += 64) {
#pragma unroll
    for (int i = 0; i < 4; ++i) {
      int lin = tid + i * 256;
      int r = lin >> 4;
      int c4 = (lin & 15) << 2;
      int gr = row0 + r;
      float4 v = make_float4(0.f, 0.f, 0.f, 0.f);
      if (gr < M) v = *(const float4*)&A[(size_t)gr * Hc + k0 + c4];
      if (statsIn) {
        float4 sv = *(const float4*)&statsIn[k0 + c4];
        float4 qv = *(const float4*)&statsIn[Hc + k0 + c4];
        float4 gv = *(const float4*)&gIn[k0 + c4];
        float4 bv = *(const float4*)&bIn[k0 + c4];
        float mu, var, sc, bb;
        mu = sv.x * invM; var = qv.x * invM - mu * mu; sc = rsqrtf(var + BN_EPS) * gv.x; bb = bv.x - mu * sc;
        v.x = fmaxf(fmaf(v.x, sc, bb), 0.f);
        mu = sv.y * invM; var = qv.y * invM - mu * mu; sc = rsqrtf(var + BN_EPS) * gv.y; bb = bv.y - mu * sc;
        v.y = fmaxf(fmaf(v.y, sc, bb), 0.f);
        mu = sv.z * invM; var = qv.z * invM - mu * mu; sc = rsqrtf(var + BN_EPS) * gv.z; bb = bv.z - mu * sc;
        v.z = fmaxf(fmaf(v.z, sc, bb), 0.f);
        mu = sv.w * invM; var = qv.w * invM - mu * mu; sc = rsqrtf(var + BN_EPS) * gv.w; bb = bv.w - mu * sc;
        v.w = fmaxf(fmaf(v.w, sc, bb), 0.f);
      }
      As[r][c4] = v.x; As[r][c4 + 1] = v.y; As[r][c4 + 2] = v.z; As[r][c4 + 3] = v.w;
      float4 w = *(const float4*)&W[(size_t)(k0 + r) * Hc + col0 + c4];
      Ws[r][c4] = w.x; Ws[r][c4 + 1] = w.y; Ws[r][c4 + 2] = w.z; Ws[r][c4 + 3] = w.w;
    }
    __syncthreads();
#pragma unroll
    for (int k = 0; k < 64; ++k) {
      float a[4], w[4];
#pragma unroll
      for (int i = 0; i < 4; ++i) a[i] = As[ty * 4 + i][k];
#pragma unroll
      for (int j = 0; j < 4; ++j) w[j] = Ws[k][tx * 4 + j];
#pragma unroll
      for (int i = 0; i < 4; ++i)
#pragma unroll
        for (int j = 0; j < 4; ++j) acc[i][j] = fmaf(a[i], w[j], acc[i][j]);
    }
    __syncthreads();
  }
  float cs[4] = {0.f, 0.f, 0.f, 0.f}, cq[4] = {0.f, 0.f, 0.f, 0.f};
#pragma unroll
  for (int i = 0; i < 4; ++i) {
    int gr = row0 + ty * 4 + i;
    if (gr >= M) break;
#pragma unroll
    for (int j = 0; j < 4; ++j) {
      int gc = col0 + tx * 4 + j;
      float v = acc[i][j] + bias[gc];
      C[(size_t)gr * Hc + gc] = v;
      cs[j] += v;
      cq[j] = fmaf(v, v, cq[j]);
    }
  }
#pragma unroll
  for (int j = 0; j < 4; ++j) {
    atomicAdd(&lsum[tx * 4 + j], cs[j]);
    atomicAdd(&lsq[tx * 4 + j], cq[j]);
  }
  __syncthreads();
  if (tid < 64) {
    atomicAdd(&statsOut[col0 + tid], lsum[tid]);
    atomicAdd(&statsOut[Hc + col0 + tid], lsq[tid]);
  }
}

extern "C" void kernel_launch(void* const* d_in, const int* in_sizes, int n_in,
                              void* d_out, int out_size, void* d_ws, size_t ws_size,
                              hipStream_t stream) {
  const int* x = (const int*)d_in[0];
  const int* ei = (const int*)d_in[1];
  const int* ea = (const int*)d_in[2];
  const int* batch = (const int*)d_in[3];
  const float* aemb = (const float*)d_in[4];
  const float* bemb = (const float*)d_in[5];
  const float* vnw = (const float*)d_in[6];
  const float* conv_w = (const float*)d_in[7];
  const float* conv_b = (const float*)d_in[8];
  const float* ngamma = (const float*)d_in[9];
  const float* nbeta = (const float*)d_in[10];
  const float* vn_w = (const float*)d_in[11];
  const float* vn_b = (const float*)d_in[12];
  const float* vn_g = (const float*)d_in[13];
  const float* vn_be = (const float*)d_in[14];
  float* out = (float*)d_out;

  const size_t NODE = (size_t)Ncnt * Hc;
  const size_t GH = (size_t)Gcnt * Hc;
  const int nScanBlk = (Ncnt + 255) / 256;  // 586

  size_t off = 0;
  char* base = (char*)d_ws;
  auto take = [&](size_t bytes) { size_t o = off; off += (bytes + 15) & ~(size_t)15; return o; };
  float* vn = (float*)(base + take(GH * 4));
  float* vnt = (float*)(base + take(GH * 4));
  float* vnu = (float*)(base + take(GH * 4));
  float* vnv = (float*)(base + take(GH * 4));
  float* statsN = (float*)(base + take(2 * Hc * 4));
  float* statsV1 = (float*)(base + take(2 * Hc * 4));
  float* statsV2 = (float*)(base + take(2 * Hc * 4));
  float* scbN = (float*)(base + take(Hc * 4));
  float* bbbN = (float*)(base + take(Hc * 4));
  int* rowptr = (int*)(base + take((size_t)(Ncnt + 1) * 4));
  int* cursor = (int*)(base + take((size_t)Ncnt * 4));
  int2* erec = (int2*)(base + take((size_t)Ecnt * 8));
  int* bsum = (int*)(base + take((size_t)nScanBlk * 4));
  bf16* P = (bf16*)(base + take(NODE * 2));
  bf16* T = (bf16*)(base + take(NODE * 2));
  bf16* WhiC = (bf16*)(base + take((size_t)Lcnt * 65536 * 2));
  bf16* WloC = (bf16*)(base + take((size_t)Lcnt * 65536 * 2));
  const size_t NEED = off;
  if (ws_size < NEED) {
    k_zero<<<(int)((GH + 255) / 256), 256, 0, stream>>>(out, (int)GH);
    k_diag<<<1, 1, 0, stream>>>(out, 100000.f + (float)(ws_size / (1024.0 * 1024.0)));
    return;
  }

  const int eBlk = (Ecnt + 255) / 256;
  const int nWaveBlk = (Ncnt + 3) / 4;
  const int aggBlk = (Ncnt + 7) / 8;       // half-wave per node
  const int segBlk = (Ncnt + 255) / 256;
  const int ggN = (Ncnt + 127) / 128;      // 1172, 1-D
  const dim3 gv(Gcnt / 64, 4);
  const float invN = 1.f / Ncnt;
  const float invG = 1.f / Gcnt;

  // CSR build (parallel scan) + packed edge records
  k_zero_int<<<nScanBlk, 256, 0, stream>>>(cursor, Ncnt);
  k_count<<<eBlk, 256, 0, stream>>>(ei, cursor);
  k_scan1<<<nScanBlk, 256, 0, stream>>>(cursor, rowptr, bsum, Ncnt);
  k_scan2<<<1, 1024, 0, stream>>>(bsum, nScanBlk);
  k_scan3<<<nScanBlk, 256, 0, stream>>>(rowptr, cursor, bsum, Ncnt);
  k_scatter<<<eBlk, 256, 0, stream>>>(ei, ea, batch, cursor, erec);

  // conv weight prep (hi/lo, fragment-packed)
  k_prep_w<<<(Lcnt * 8192 + 255) / 256, 256, 0, stream>>>(conv_w, WhiC, WloC, Lcnt);

  // Encoders + conv0 (stats fused for layer-1 BN)
  k_atom_encode<<<nWaveBlk, 256, 0, stream>>>(x, aemb, vnw, P);
  k_init_vn<<<(int)(GH / 256), 256, 0, stream>>>(vn, vnw);
  k_agg<<<aggBlk, 256, 0, stream>>>(P, T, rowptr, erec, bemb, nullptr, nullptr, nullptr, nullptr);
  k_zero<<<2, 256, 0, stream>>>(statsN, 2 * Hc);
  k_gemm_mfma<<<ggN, 256, 0, stream>>>(T, WhiC, WloC, conv_b, nullptr, P, statsN, Ncnt);

  for (int l = 1; l < Lcnt; ++l) {
    int p = l - 1;
    // BN constants for this layer's node BN
    k_bnprep<<<1, 256, 0, stream>>>(statsN, ngamma + (size_t)p * Hc, nbeta + (size_t)p * Hc,
                                    scbN, bbbN, invN);
    // vn_t = vn + segsum(relu(bn(P)))
    k_copy4<<<(int)(GH / 1024), 256, 0, stream>>>(vnt, vn, (int)(GH / 4));
    k_seg_vn<<<segBlk, 256, 0, stream>>>(P, batch, vnt, scbN, bbbN);
    // VN MLP j=0: vnu = vnt @ w0 + b0 (stats -> V1)
    k_zero<<<2, 256, 0, stream>>>(statsV1, 2 * Hc);
    k_gemm_f32<<<gv, 256, 0, stream>>>(vnt, vn_w + (size_t)(2 * p) * 65536,
                                       vn_b + (size_t)(2 * p) * Hc, vnu, statsV1,
                                       nullptr, nullptr, nullptr, invG, Gcnt);
    // VN MLP j=1: vnv = relu(bnV1(vnu)) @ w1 + b1 (stats -> V2)
    k_zero<<<2, 256, 0, stream>>>(statsV2, 2 * Hc);
    k_gemm_f32<<<gv, 256, 0, stream>>>(vnu, vn_w + (size_t)(2 * p + 1) * 65536,
                                       vn_b + (size_t)(2 * p + 1) * Hc, vnv, statsV2,
                                       statsV1, vn_g + (size_t)(2 * p) * Hc,
                                       vn_be + (size_t)(2 * p) * Hc, invG, Gcnt);
    // vn = relu(bnV2(vnv))
    k_vn_relu<<<(int)(GH / 256), 256, 0, stream>>>(vnv, vn, statsV2,
                                                   vn_g + (size_t)(2 * p + 1) * Hc,
                                                   vn_be + (size_t)(2 * p + 1) * Hc, invG);
    // T = h2 + agg(h2), h2 = relu(bn(P)) + vn[batch]
    k_agg<<<aggBlk, 256, 0, stream>>>(P, T, rowptr, erec, bemb, vn, batch, scbN, bbbN);
    // P = T @ W + bias + P (stats fused for next BN)
    k_zero<<<2, 256, 0, stream>>>(statsN, 2 * Hc);
    k_gemm_mfma<<<ggN, 256, 0, stream>>>(T, WhiC + (size_t)l * 65536, WloC + (size_t)l * 65536,
                                         conv_b + (size_t)l * Hc, P, P, statsN, Ncnt);
  }

  // Final BN + global add pool
  k_bnprep<<<1, 256, 0, stream>>>(statsN, ngamma + (size_t)(Lcnt - 1) * Hc,
                                  nbeta + (size_t)(Lcnt - 1) * Hc, scbN, bbbN, invN);
  k_zero<<<(int)((GH + 255) / 256), 256, 0, stream>>>(out, (int)GH);
  k_bn_pool<<<segBlk, 256, 0, stream>>>(P, batch, out, scbN, bbbN);
}

// Round 11
// 2268.945 us; speedup vs baseline: 2.1993x; 1.0097x over previous
//
#include <hip/hip_runtime.h>
#include <hip/hip_bf16.h>

// DeeperGCN on MI355X — round 11: GEMM epilogue LDS tile in bf16 (34.8 KB total LDS
// -> 4 blocks/CU), launch-count diet (bnprep zeroes stats, vn_relu dual-store kills
// copy, merged stat zeroes). k_agg/others unchanged from round 10.
// N=150000, E=300000, G=4096, H=256, L=7.

#define Ncnt 150000
#define Ecnt 300000
#define Gcnt 4096
#define Hc 256
#define Lcnt 7
#define BN_EPS 1e-5f
#define MSG_EPS 1e-7f

typedef __hip_bfloat16 bf16;
typedef __attribute__((ext_vector_type(8))) short bf16x8;
typedef __attribute__((ext_vector_type(8))) unsigned short u16x8;
typedef __attribute__((ext_vector_type(4))) float f32x4;

static __device__ __forceinline__ int imin(int a, int b) { return a < b ? a : b; }

static __device__ __forceinline__ float bs2f(unsigned short s) {
  unsigned u = ((unsigned)s) << 16;
  union { unsigned u; float f; } c; c.u = u; return c.f;
}
static __device__ __forceinline__ unsigned short f2bs(float f) {
  bf16 h = __float2bfloat16(f);
  union { bf16 h; unsigned short s; } c; c.h = h; return c.s;
}
static __device__ __forceinline__ float4 bf4tof4(ushort4 u) {
  float4 r; r.x = bs2f(u.x); r.y = bs2f(u.y); r.z = bs2f(u.z); r.w = bs2f(u.w); return r;
}
static __device__ __forceinline__ ushort4 f4tobf4(float4 v) {
  ushort4 u; u.x = f2bs(v.x); u.y = f2bs(v.y); u.z = f2bs(v.z); u.w = f2bs(v.w); return u;
}

// async global->LDS, 16B per lane; lds dst must be the wave-uniform chunk base.
static __device__ __forceinline__ void gll16(const bf16* g, const short* l) {
  __builtin_amdgcn_global_load_lds((const __attribute__((address_space(1))) void*)g,
                                   (__attribute__((address_space(3))) void*)l, 16, 0, 0);
}

__global__ __launch_bounds__(256) void k_zero(float* __restrict__ p, int n) {
  int i = blockIdx.x * 256 + threadIdx.x;
  if (i < n) p[i] = 0.f;
}
__global__ __launch_bounds__(256) void k_zero_int(int* __restrict__ p, int n) {
  int i = blockIdx.x * 256 + threadIdx.x;
  if (i < n) p[i] = 0;
}
__global__ void k_diag(float* __restrict__ out, float v) { out[0] = v; }

// ---- BN scale/bias precompute + stats recycle (zeroed for next accumulation) ----
__global__ __launch_bounds__(256) void k_bnprep(float* __restrict__ stats,
                                                const float* __restrict__ gamma, const float* __restrict__ beta,
                                                float* __restrict__ scb, float* __restrict__ bbb, float invM) {
  int c = threadIdx.x;
  float mu = stats[c] * invM;
  float var = stats[Hc + c] * invM - mu * mu;
  float sc = rsqrtf(var + BN_EPS) * gamma[c];
  scb[c] = sc;
  bbb[c] = beta[c] - mu * sc;
  stats[c] = 0.f;
  stats[Hc + c] = 0.f;
}

// ---- CSR build (counting sort by dst) ----
__global__ __launch_bounds__(256) void k_count(const int* __restrict__ ei, int* __restrict__ cnt) {
  int e = blockIdx.x * 256 + threadIdx.x;
  if (e < Ecnt) atomicAdd(&cnt[ei[Ecnt + e]], 1);
}
__global__ __launch_bounds__(256) void k_scan1(const int* __restrict__ cnt, int* __restrict__ rowptr,
                                               int* __restrict__ bsum, int n) {
  __shared__ int sh[256];
  int t = threadIdx.x;
  int i = blockIdx.x * 256 + t;
  int v = (i < n) ? cnt[i] : 0;
  sh[t] = v;
  __syncthreads();
#pragma unroll
  for (int off = 1; off < 256; off <<= 1) {
    int u = (t >= off) ? sh[t - off] : 0;
    __syncthreads();
    sh[t] += u;
    __syncthreads();
  }
  if (i < n) rowptr[i] = sh[t] - v;
  if (t == 255) bsum[blockIdx.x] = sh[255];
}
__global__ __launch_bounds__(1024) void k_scan2(int* __restrict__ bsum, int nb) {
  __shared__ int sh[1024];
  int t = threadIdx.x;
  int v = (t < nb) ? bsum[t] : 0;
  sh[t] = v;
  __syncthreads();
#pragma unroll
  for (int off = 1; off < 1024; off <<= 1) {
    int u = (t >= off) ? sh[t - off] : 0;
    __syncthreads();
    sh[t] += u;
    __syncthreads();
  }
  if (t < nb) bsum[t] = sh[t] - v;
}
__global__ __launch_bounds__(256) void k_scan3(int* __restrict__ rowptr, int* __restrict__ cursor,
                                               const int* __restrict__ bsum, int n) {
  int i = blockIdx.x * 256 + threadIdx.x;
  if (i < n) {
    int v = rowptr[i] + bsum[blockIdx.x];
    rowptr[i] = v;
    cursor[i] = v;
  }
  if (i == 0) rowptr[n] = Ecnt;
}
// scatter packed edge records: erec[pos] = (src, a0 | a1<<3 | a2<<6 | batch[src]<<9)
__global__ __launch_bounds__(256) void k_scatter(const int* __restrict__ ei, const int* __restrict__ ea,
                                                 const int* __restrict__ batch, int* __restrict__ cursor,
                                                 int2* __restrict__ erec) {
  int e = blockIdx.x * 256 + threadIdx.x;
  if (e < Ecnt) {
    int d = ei[Ecnt + e];
    int s = ei[e];
    int packed = ea[e * 3] | (ea[e * 3 + 1] << 3) | (ea[e * 3 + 2] << 6) | (batch[s] << 9);
    int pos = atomicAdd(&cursor[d], 1);
    erec[pos] = make_int2(s, packed);
  }
}

// ---- weight prep: conv W[k][n] fp32 -> fragment-packed bf16 hi/lo. ----
__global__ __launch_bounds__(256) void k_prep_w(const float* __restrict__ W, bf16* __restrict__ hi,
                                                bf16* __restrict__ lo, int nmats) {
  int c = blockIdx.x * 256 + threadIdx.x;
  if (c >= nmats * 8192) return;
  int lane = c & 63;
  int t = c >> 6;
  int kc8 = t & 7;
  int nt = (t >> 3) & 15;
  int m = t >> 7;
  int n = nt * 16 + (lane & 15);
  int k0 = kc8 * 32 + (lane >> 4) * 8;
  bf16x8 hv, lv;
#pragma unroll
  for (int j = 0; j < 8; ++j) {
    float w = W[(size_t)m * 65536 + (size_t)(k0 + j) * 256 + n];
    unsigned short h = f2bs(w);
    float res = w - bs2f(h);
    hv[j] = (short)h;
    lv[j] = (short)f2bs(res);
  }
  *(bf16x8*)&hi[(size_t)c * 8] = hv;
  *(bf16x8*)&lo[(size_t)c * 8] = lv;
}

// ---- encoders (1 wave per node, 4 ch/lane) ----
__global__ __launch_bounds__(256) void k_atom_encode(const int* __restrict__ x,
                                                     const float* __restrict__ aemb,
                                                     const float* __restrict__ vnw,
                                                     bf16* __restrict__ P) {
  int wave = threadIdx.x >> 6, lane = threadIdx.x & 63;
  int r = blockIdx.x * 4 + wave;
  if (r >= Ncnt) return;
  int c4 = lane * 4;
  const int* xr = x + (size_t)r * 9;
  float4 v = *(const float4*)&vnw[c4];
#pragma unroll
  for (int f = 0; f < 9; ++f) {
    float4 e = *(const float4*)&aemb[(size_t)((f << 6) + xr[f]) * Hc + c4];
    v.x += e.x; v.y += e.y; v.z += e.z; v.w += e.w;
  }
  *(ushort4*)&P[(size_t)r * Hc + c4] = f4tobf4(v);
}

__global__ __launch_bounds__(256) void k_init_vn(float* __restrict__ vn, float* __restrict__ vnt,
                                                 const float* __restrict__ vnw) {
  int idx = blockIdx.x * 256 + threadIdx.x;  // G*Hc total
  float v = vnw[idx & (Hc - 1)];
  vn[idx] = v;
  vnt[idx] = v;
}

// ---- aggregation: T[r] = h2(r) + sum_{e: dst=r} (relu(h2(src)+bond_emb)+eps)
// h2(n) = P[n] (scb==null) or relu(bn(P[n]))+vn[batch[n]].  Half-wave (32 lanes) per node, 8 ch/lane.
__global__ __launch_bounds__(256) void k_agg(const bf16* __restrict__ P, bf16* __restrict__ T,
                                             const int* __restrict__ rowptr, const int2* __restrict__ erec,
                                             const float* __restrict__ bemb,
                                             const float* __restrict__ vn, const int* __restrict__ batch,
                                             const float* __restrict__ scb, const float* __restrict__ bbb) {
  int hw = threadIdx.x >> 5, lane = threadIdx.x & 31;
  int r = blockIdx.x * 8 + hw;
  if (r >= Ncnt) return;
  int c8 = lane * 8;
  bool hasbn = (scb != nullptr);
  float sc[8], bb[8];
  if (hasbn) {
    float4 s0 = *(const float4*)&scb[c8], s1 = *(const float4*)&scb[c8 + 4];
    float4 b0 = *(const float4*)&bbb[c8], b1 = *(const float4*)&bbb[c8 + 4];
    sc[0] = s0.x; sc[1] = s0.y; sc[2] = s0.z; sc[3] = s0.w;
    sc[4] = s1.x; sc[5] = s1.y; sc[6] = s1.z; sc[7] = s1.w;
    bb[0] = b0.x; bb[1] = b0.y; bb[2] = b0.z; bb[3] = b0.w;
    bb[4] = b1.x; bb[5] = b1.y; bb[6] = b1.z; bb[7] = b1.w;
  }
  float acc[8];
  {
    u16x8 pv = *(const u16x8*)&P[(size_t)r * Hc + c8];
    if (hasbn) {
      const float* vr = &vn[(size_t)batch[r] * Hc + c8];
      float4 w0 = *(const float4*)vr, w1 = *(const float4*)(vr + 4);
      float w[8] = {w0.x, w0.y, w0.z, w0.w, w1.x, w1.y, w1.z, w1.w};
#pragma unroll
      for (int k = 0; k < 8; ++k) acc[k] = fmaxf(fmaf(bs2f(pv[k]), sc[k], bb[k]), 0.f) + w[k];
    } else {
#pragma unroll
      for (int k = 0; k < 8; ++k) acc[k] = bs2f(pv[k]);
    }
  }
  int j0 = rowptr[r], j1 = rowptr[r + 1];
  if (j0 < j1) {
    int2 er = erec[j0];
    for (int j = j0; j < j1; ++j) {
      int2 ern = (j + 1 < j1) ? erec[j + 1] : er;  // prefetch next record
      int s = er.x;
      int a0 = er.y & 7, a1 = (er.y >> 3) & 7, a2 = (er.y >> 6) & 7, g = er.y >> 9;
      u16x8 sv = *(const u16x8*)&P[(size_t)s * Hc + c8];
      const float* e0 = &bemb[(size_t)a0 * Hc + c8];
      const float* e1 = &bemb[(size_t)(8 + a1) * Hc + c8];
      const float* e2 = &bemb[(size_t)(16 + a2) * Hc + c8];
      float4 e0a = *(const float4*)e0, e0b = *(const float4*)(e0 + 4);
      float4 e1a = *(const float4*)e1, e1b = *(const float4*)(e1 + 4);
      float4 e2a = *(const float4*)e2, e2b = *(const float4*)(e2 + 4);
      float em[8] = {e0a.x + e1a.x + e2a.x, e0a.y + e1a.y + e2a.y,
                     e0a.z + e1a.z + e2a.z, e0a.w + e1a.w + e2a.w,
                     e0b.x + e1b.x + e2b.x, e0b.y + e1b.y + e2b.y,
                     e0b.z + e1b.z + e2b.z, e0b.w + e1b.w + e2b.w};
      if (hasbn) {
        const float* vr = &vn[(size_t)g * Hc + c8];
        float4 w0 = *(const float4*)vr, w1 = *(const float4*)(vr + 4);
        float w[8] = {w0.x, w0.y, w0.z, w0.w, w1.x, w1.y, w1.z, w1.w};
#pragma unroll
        for (int k = 0; k < 8; ++k) {
          float v = fmaxf(fmaf(bs2f(sv[k]), sc[k], bb[k]), 0.f) + w[k];
          acc[k] += fmaxf(v + em[k], 0.f) + MSG_EPS;
        }
      } else {
#pragma unroll
        for (int k = 0; k < 8; ++k)
          acc[k] += fmaxf(bs2f(sv[k]) + em[k], 0.f) + MSG_EPS;
      }
      er = ern;
    }
  }
  u16x8 ov;
#pragma unroll
  for (int k = 0; k < 8; ++k) ov[k] = f2bs(acc[k]);
  *(u16x8*)&T[(size_t)r * Hc + c8] = ov;
}

// ---- segment-sum of relu(bn(P)) by sorted batch into vnt (pre-init with vn). 1 wave / 64 rows.
__global__ __launch_bounds__(256) void k_seg_vn(const bf16* __restrict__ P, const int* __restrict__ batch,
                                                float* __restrict__ vnt,
                                                const float* __restrict__ scb, const float* __restrict__ bbb) {
  int wave = threadIdx.x >> 6, lane = threadIdx.x & 63;
  int base = (blockIdx.x * 4 + wave) * 64;
  if (base >= Ncnt) return;
  int c4 = lane * 4;
  float4 scv = *(const float4*)&scb[c4];
  float4 bbv = *(const float4*)&bbb[c4];
  int end = imin(base + 64, Ncnt);
  float4 acc = make_float4(0.f, 0.f, 0.f, 0.f);
  int curg = batch[base];
  for (int r = base; r < end; ++r) {
    int g = batch[r];
    float4 v = bf4tof4(*(const ushort4*)&P[(size_t)r * Hc + c4]);
    v.x = fmaxf(fmaf(v.x, scv.x, bbv.x), 0.f); v.y = fmaxf(fmaf(v.y, scv.y, bbv.y), 0.f);
    v.z = fmaxf(fmaf(v.z, scv.z, bbv.z), 0.f); v.w = fmaxf(fmaf(v.w, scv.w, bbv.w), 0.f);
    if (g != curg) {
      float* d = &vnt[(size_t)curg * Hc + c4];
      atomicAdd(d, acc.x); atomicAdd(d + 1, acc.y); atomicAdd(d + 2, acc.z); atomicAdd(d + 3, acc.w);
      acc = make_float4(0.f, 0.f, 0.f, 0.f);
      curg = g;
    }
    acc.x += v.x; acc.y += v.y; acc.z += v.z; acc.w += v.w;
  }
  float* d = &vnt[(size_t)curg * Hc + c4];
  atomicAdd(d, acc.x); atomicAdd(d + 1, acc.y); atomicAdd(d + 2, acc.z); atomicAdd(d + 3, acc.w);
}

// ---- VN elementwise relu(bn(.)) fp32 -> vn AND vnt (next layer's seg base) ----
__global__ __launch_bounds__(256) void k_vn_relu(const float* __restrict__ in, float* __restrict__ out,
                                                 float* __restrict__ out2,
                                                 const float* __restrict__ stats,
                                                 const float* __restrict__ gamma, const float* __restrict__ beta,
                                                 float invM) {
  int idx = blockIdx.x * 256 + threadIdx.x;
  int c = idx & (Hc - 1);
  float mu = stats[c] * invM;
  float var = stats[Hc + c] * invM - mu * mu;
  float sc = rsqrtf(var + BN_EPS) * gamma[c];
  float bb = beta[c] - mu * sc;
  float v = fmaxf(fmaf(in[idx], sc, bb), 0.f);
  out[idx] = v;
  out2[idx] = v;
}

// ---- final bn + global_add_pool (out pre-zeroed). 1 wave / 64 rows.
__global__ __launch_bounds__(256) void k_bn_pool(const bf16* __restrict__ P, const int* __restrict__ batch,
                                                 float* __restrict__ out,
                                                 const float* __restrict__ scb, const float* __restrict__ bbb) {
  int wave = threadIdx.x >> 6, lane = threadIdx.x & 63;
  int base = (blockIdx.x * 4 + wave) * 64;
  if (base >= Ncnt) return;
  int c4 = lane * 4;
  float4 scv = *(const float4*)&scb[c4];
  float4 bbv = *(const float4*)&bbb[c4];
  int end = imin(base + 64, Ncnt);
  float4 acc = make_float4(0.f, 0.f, 0.f, 0.f);
  int curg = batch[base];
  for (int r = base; r < end; ++r) {
    int g = batch[r];
    float4 v = bf4tof4(*(const ushort4*)&P[(size_t)r * Hc + c4]);
    v.x = fmaf(v.x, scv.x, bbv.x); v.y = fmaf(v.y, scv.y, bbv.y);
    v.z = fmaf(v.z, scv.z, bbv.z); v.w = fmaf(v.w, scv.w, bbv.w);
    if (g != curg) {
      float* d = &out[(size_t)curg * Hc + c4];
      atomicAdd(d, acc.x); atomicAdd(d + 1, acc.y); atomicAdd(d + 2, acc.z); atomicAdd(d + 3, acc.w);
      acc = make_float4(0.f, 0.f, 0.f, 0.f);
      curg = g;
    }
    acc.x += v.x; acc.y += v.y; acc.z += v.z; acc.w += v.w;
  }
  float* d = &out[(size_t)curg * Hc + c4];
  atomicAdd(d, acc.x); atomicAdd(d + 1, acc.y); atomicAdd(d + 2, acc.z); atomicAdd(d + 3, acc.w);
}

// ---- MFMA node GEMM: C[M,256] = A @ (Whi+Wlo) + bias (+R), fused BN-stats.
// A: LDS-staged (gll16, XOR swizzle, 16 KB). B: fragment-packed direct-global.
// Epilogue: fragments -> bf16 LDS tile (16.5 KB, stride 264 u16, rows 16B-aligned)
// -> coalesced R-add + u16x8 C store + stats. Total LDS ~34.8 KB -> 4 blocks/CU.
__global__ __launch_bounds__(256, 2) void k_gemm_mfma(const bf16* __restrict__ A, const bf16* __restrict__ Whi,
                                                      const bf16* __restrict__ Wlo, const float* __restrict__ bias,
                                                      const bf16* __restrict__ R, bf16* __restrict__ C,
                                                      float* __restrict__ stats, int M) {
  __shared__ __attribute__((aligned(16))) short As[128 * 64];
  __shared__ __attribute__((aligned(16))) unsigned short Cs[32 * 264];
  __shared__ float lsum[256], lsq[256];
  int tid = threadIdx.x;
  int wave = tid >> 6, lane = tid & 63;
  int quad = lane >> 4, l15 = lane & 15;
  int wr = (wave & 1) * 64;       // row half
  int wc = (wave >> 1) * 128;     // col half
  int row0 = blockIdx.x * 128;

  lsum[tid] = 0.f;
  lsq[tid] = 0.f;

  int sr[4], sjg[4];
#pragma unroll
  for (int i = 0; i < 4; ++i) {
    int s = i * 256 + tid;
    sr[i] = s >> 3;
    sjg[i] = (s & 7) ^ (sr[i] & 7);
  }

  f32x4 acc[4][8];
#pragma unroll
  for (int i = 0; i < 4; ++i)
#pragma unroll
    for (int j = 0; j < 8; ++j) acc[i][j] = (f32x4){0.f, 0.f, 0.f, 0.f};

  for (int kci = 0; kci < 4; ++kci) {
    int kc = kci * 64;
#pragma unroll
    for (int i = 0; i < 4; ++i) {
      int ar = row0 + sr[i]; if (ar >= M) ar = M - 1;  // clamp: garbage rows never stored
      gll16(A + (size_t)ar * Hc + kc + sjg[i] * 8, &As[(i * 256 + wave * 64) * 8]);
    }
    __syncthreads();
#pragma unroll
    for (int ks = 0; ks < 2; ++ks) {
      int kc8 = kci * 2 + ks;
      int g = ks * 4 + quad;
      bf16x8 af[4];
#pragma unroll
      for (int mi = 0; mi < 4; ++mi) {
        int row = wr + mi * 16 + l15;
        af[mi] = *(const bf16x8*)&As[row * 64 + (g ^ (row & 7)) * 8];
      }
#pragma unroll
      for (int nii = 0; nii < 8; ++nii) {
        int nt = (wave >> 1) * 8 + nii;
        size_t fo = (((size_t)nt * 8 + kc8) * 64 + lane) * 8;
        bf16x8 bh = *(const bf16x8*)&Whi[fo];
        bf16x8 bl = *(const bf16x8*)&Wlo[fo];
#pragma unroll
        for (int mi = 0; mi < 4; ++mi) {
          acc[mi][nii] = __builtin_amdgcn_mfma_f32_16x16x32_bf16(af[mi], bh, acc[mi][nii], 0, 0, 0);
          acc[mi][nii] = __builtin_amdgcn_mfma_f32_16x16x32_bf16(af[mi], bl, acc[mi][nii], 0, 0, 0);
        }
      }
    }
    __syncthreads();
  }

  // ---- epilogue: 4 passes of 32 rows (16 from each row-half), via bf16 LDS tile ----
  float s8[8], q8[8];
#pragma unroll
  for (int k = 0; k < 8; ++k) { s8[k] = 0.f; q8[k] = 0.f; }
  int c8 = (tid & 31) * 8;

  for (int p = 0; p < 4; ++p) {
    int lr0 = (wave & 1) * 16 + quad * 4;
#pragma unroll
    for (int ni = 0; ni < 8; ++ni) {
      int col = wc + ni * 16 + l15;
      float bcol = bias[col];
#pragma unroll
      for (int j = 0; j < 4; ++j)
        Cs[(lr0 + j) * 264 + col] = f2bs(acc[p][ni][j] + bcol);
    }
    __syncthreads();
#pragma unroll
    for (int i = 0; i < 4; ++i) {
      int gsl = i * 256 + tid;
      int lr = gsl >> 5;
      int grow = row0 + ((lr < 16) ? p * 16 + lr : 48 + p * 16 + lr);
      if (grow < M) {
        u16x8 cv = *(const u16x8*)&Cs[lr * 264 + c8];
        float v[8];
#pragma unroll
        for (int k = 0; k < 8; ++k) v[k] = bs2f(cv[k]);
        if (R) {
          u16x8 rv = *(const u16x8*)&R[(size_t)grow * Hc + c8];
#pragma unroll
          for (int k = 0; k < 8; ++k) v[k] += bs2f(rv[k]);
        }
        u16x8 ov;
#pragma unroll
        for (int k = 0; k < 8; ++k) {
          ov[k] = f2bs(v[k]);
          s8[k] += v[k];
          q8[k] = fmaf(v[k], v[k], q8[k]);
        }
        *(u16x8*)&C[(size_t)grow * Hc + c8] = ov;
      }
    }
    __syncthreads();
  }

#pragma unroll
  for (int k = 0; k < 8; ++k) {
    atomicAdd(&lsum[c8 + k], s8[k]);
    atomicAdd(&lsq[c8 + k], q8[k]);
  }
  __syncthreads();
  atomicAdd(&stats[tid], lsum[tid]);
  atomicAdd(&stats[Hc + tid], lsq[tid]);
}

// ---- fp32 SIMT GEMM for VN MLP: C[M,256] = act(A) @ W + bias, fused stats. ----
__global__ __launch_bounds__(256) void k_gemm_f32(const float* __restrict__ A, const float* __restrict__ W,
                                                  const float* __restrict__ bias, float* __restrict__ C,
                                                  float* __restrict__ statsOut,
                                                  const float* __restrict__ statsIn,
                                                  const float* __restrict__ gIn, const float* __restrict__ bIn,
                                                  float invM, int M) {
  __shared__ float As[64][68];
  __shared__ float Ws[64][68];
  __shared__ float lsum[64], lsq[64];
  int tid = threadIdx.x;
  int row0 = blockIdx.x * 64;
  int col0 = blockIdx.y * 64;
  int tx = tid & 15, ty = tid >> 4;
  if (tid < 64) { lsum[tid] = 0.f; lsq[tid] = 0.f; }
  float acc[4][4] = {{0.f}};
  for (int k0 = 0; k0 < 256; k0 += 64) {
#pragma unroll
    for (int i = 0; i < 4; ++i) {
      int lin = tid + i * 256;
      int r = lin >> 4;
      int c4 = (lin & 15) << 2;
      int gr = row0 + r;
      float4 v = make_float4(0.f, 0.f, 0.f, 0.f);
      if (gr < M) v = *(const float4*)&A[(size_t)gr * Hc + k0 + c4];
      if (statsIn) {
        float4 sv = *(const float4*)&statsIn[k0 + c4];
        float4 qv = *(const float4*)&statsIn[Hc + k0 + c4];
        float4 gv = *(const float4*)&gIn[k0 + c4];
        float4 bv = *(const float4*)&bIn[k0 + c4];
        float mu, var, sc, bb;
        mu = sv.x * invM; var = qv.x * invM - mu * mu; sc = rsqrtf(var + BN_EPS) * gv.x; bb = bv.x - mu * sc;
        v.x = fmaxf(fmaf(v.x, sc, bb), 0.f);
        mu = sv.y * invM; var = qv.y * invM - mu * mu; sc = rsqrtf(var + BN_EPS) * gv.y; bb = bv.y - mu * sc;
        v.y = fmaxf(fmaf(v.y, sc, bb), 0.f);
        mu = sv.z * invM; var = qv.z * invM - mu * mu; sc = rsqrtf(var + BN_EPS) * gv.z; bb = bv.z - mu * sc;
        v.z = fmaxf(fmaf(v.z, sc, bb), 0.f);
        mu = sv.w * invM; var = qv.w * invM - mu * mu; sc = rsqrtf(var + BN_EPS) * gv.w; bb = bv.w - mu * sc;
        v.w = fmaxf(fmaf(v.w, sc, bb), 0.f);
      }
      As[r][c4] = v.x; As[r][c4 + 1] = v.y; As[r][c4 + 2] = v.z; As[r][c4 + 3] = v.w;
      float4 w = *(const float4*)&W[(size_t)(k0 + r) * Hc + col0 + c4];
      Ws[r][c4] = w.x; Ws[r][c4 + 1] = w.y; Ws[r][c4 + 2] = w.z; Ws[r][c4 + 3] = w.w;
    }
    __syncthreads();
#pragma unroll
    for (int k = 0; k < 64; ++k) {
      float a[4], w[4];
#pragma unroll
      for (int i = 0; i < 4; ++i) a[i] = As[ty * 4 + i][k];
#pragma unroll
      for (int j = 0; j < 4; ++j) w[j] = Ws[k][tx * 4 + j];
#pragma unroll
      for (int i = 0; i < 4; ++i)
#pragma unroll
        for (int j = 0; j < 4; ++j) acc[i][j] = fmaf(a[i], w[j], acc[i][j]);
    }
    __syncthreads();
  }
  float cs[4] = {0.f, 0.f, 0.f, 0.f}, cq[4] = {0.f, 0.f, 0.f, 0.f};
#pragma unroll
  for (int i = 0; i < 4; ++i) {
    int gr = row0 + ty * 4 + i;
    if (gr >= M) break;
#pragma unroll
    for (int j = 0; j < 4; ++j) {
      int gc = col0 + tx * 4 + j;
      float v = acc[i][j] + bias[gc];
      C[(size_t)gr * Hc + gc] = v;
      cs[j] += v;
      cq[j] = fmaf(v, v, cq[j]);
    }
  }
#pragma unroll
  for (int j = 0; j < 4; ++j) {
    atomicAdd(&lsum[tx * 4 + j], cs[j]);
    atomicAdd(&lsq[tx * 4 + j], cq[j]);
  }
  __syncthreads();
  if (tid < 64) {
    atomicAdd(&statsOut[col0 + tid], lsum[tid]);
    atomicAdd(&statsOut[Hc + col0 + tid], lsq[tid]);
  }
}

extern "C" void kernel_launch(void* const* d_in, const int* in_sizes, int n_in,
                              void* d_out, int out_size, void* d_ws, size_t ws_size,
                              hipStream_t stream) {
  const int* x = (const int*)d_in[0];
  const int* ei = (const int*)d_in[1];
  const int* ea = (const int*)d_in[2];
  const int* batch = (const int*)d_in[3];
  const float* aemb = (const float*)d_in[4];
  const float* bemb = (const float*)d_in[5];
  const float* vnw = (const float*)d_in[6];
  const float* conv_w = (const float*)d_in[7];
  const float* conv_b = (const float*)d_in[8];
  const float* ngamma = (const float*)d_in[9];
  const float* nbeta = (const float*)d_in[10];
  const float* vn_w = (const float*)d_in[11];
  const float* vn_b = (const float*)d_in[12];
  const float* vn_g = (const float*)d_in[13];
  const float* vn_be = (const float*)d_in[14];
  float* out = (float*)d_out;

  const size_t NODE = (size_t)Ncnt * Hc;
  const size_t GH = (size_t)Gcnt * Hc;
  const int nScanBlk = (Ncnt + 255) / 256;  // 586

  size_t off = 0;
  char* base = (char*)d_ws;
  auto take = [&](size_t bytes) { size_t o = off; off += (bytes + 15) & ~(size_t)15; return o; };
  float* vn = (float*)(base + take(GH * 4));
  float* vnt = (float*)(base + take(GH * 4));
  float* vnu = (float*)(base + take(GH * 4));
  float* vnv = (float*)(base + take(GH * 4));
  float* statsN = (float*)(base + take(2 * Hc * 4));
  float* statsV1 = (float*)(base + take(2 * Hc * 4));
  float* statsV2 = (float*)(base + take(2 * Hc * 4));
  float* scbN = (float*)(base + take(Hc * 4));
  float* bbbN = (float*)(base + take(Hc * 4));
  int* rowptr = (int*)(base + take((size_t)(Ncnt + 1) * 4));
  int* cursor = (int*)(base + take((size_t)Ncnt * 4));
  int2* erec = (int2*)(base + take((size_t)Ecnt * 8));
  int* bsum = (int*)(base + take((size_t)nScanBlk * 4));
  bf16* P = (bf16*)(base + take(NODE * 2));
  bf16* T = (bf16*)(base + take(NODE * 2));
  bf16* WhiC = (bf16*)(base + take((size_t)Lcnt * 65536 * 2));
  bf16* WloC = (bf16*)(base + take((size_t)Lcnt * 65536 * 2));
  const size_t NEED = off;
  if (ws_size < NEED) {
    k_zero<<<(int)((GH + 255) / 256), 256, 0, stream>>>(out, (int)GH);
    k_diag<<<1, 1, 0, stream>>>(out, 100000.f + (float)(ws_size / (1024.0 * 1024.0)));
    return;
  }

  const int eBlk = (Ecnt + 255) / 256;
  const int nWaveBlk = (Ncnt + 3) / 4;
  const int aggBlk = (Ncnt + 7) / 8;       // half-wave per node
  const int segBlk = (Ncnt + 255) / 256;
  const int ggN = (Ncnt + 127) / 128;      // 1172, 1-D
  const dim3 gv(Gcnt / 64, 4);
  const float invN = 1.f / Ncnt;
  const float invG = 1.f / Gcnt;

  // CSR build (parallel scan) + packed edge records
  k_zero_int<<<nScanBlk, 256, 0, stream>>>(cursor, Ncnt);
  k_count<<<eBlk, 256, 0, stream>>>(ei, cursor);
  k_scan1<<<nScanBlk, 256, 0, stream>>>(cursor, rowptr, bsum, Ncnt);
  k_scan2<<<1, 1024, 0, stream>>>(bsum, nScanBlk);
  k_scan3<<<nScanBlk, 256, 0, stream>>>(rowptr, cursor, bsum, Ncnt);
  k_scatter<<<eBlk, 256, 0, stream>>>(ei, ea, batch, cursor, erec);

  // conv weight prep (hi/lo, fragment-packed)
  k_prep_w<<<(Lcnt * 8192 + 255) / 256, 256, 0, stream>>>(conv_w, WhiC, WloC, Lcnt);

  // Encoders + conv0 (stats fused for layer-1 BN)
  k_atom_encode<<<nWaveBlk, 256, 0, stream>>>(x, aemb, vnw, P);
  k_init_vn<<<(int)(GH / 256), 256, 0, stream>>>(vn, vnt, vnw);
  k_agg<<<aggBlk, 256, 0, stream>>>(P, T, rowptr, erec, bemb, nullptr, nullptr, nullptr, nullptr);
  k_zero<<<2, 256, 0, stream>>>(statsN, 2 * Hc);
  k_gemm_mfma<<<ggN, 256, 0, stream>>>(T, WhiC, WloC, conv_b, nullptr, P, statsN, Ncnt);

  for (int l = 1; l < Lcnt; ++l) {
    int p = l - 1;
    // BN constants for this layer's node BN (also zeroes statsN for next GEMM)
    k_bnprep<<<1, 256, 0, stream>>>(statsN, ngamma + (size_t)p * Hc, nbeta + (size_t)p * Hc,
                                    scbN, bbbN, invN);
    // vnt already = vn (dual-store); add segsum(relu(bn(P)))
    k_seg_vn<<<segBlk, 256, 0, stream>>>(P, batch, vnt, scbN, bbbN);
    // zero both VN stats buffers (adjacent) in one launch
    k_zero<<<4, 256, 0, stream>>>(statsV1, 4 * Hc);
    // VN MLP j=0: vnu = vnt @ w0 + b0 (stats -> V1)
    k_gemm_f32<<<gv, 256, 0, stream>>>(vnt, vn_w + (size_t)(2 * p) * 65536,
                                       vn_b + (size_t)(2 * p) * Hc, vnu, statsV1,
                                       nullptr, nullptr, nullptr, invG, Gcnt);
    // VN MLP j=1: vnv = relu(bnV1(vnu)) @ w1 + b1 (stats -> V2)
    k_gemm_f32<<<gv, 256, 0, stream>>>(vnu, vn_w + (size_t)(2 * p + 1) * 65536,
                                       vn_b + (size_t)(2 * p + 1) * Hc, vnv, statsV2,
                                       statsV1, vn_g + (size_t)(2 * p) * Hc,
                                       vn_be + (size_t)(2 * p) * Hc, invG, Gcnt);
    // vn = relu(bnV2(vnv)); also seeds vnt for next layer
    k_vn_relu<<<(int)(GH / 256), 256, 0, stream>>>(vnv, vn, vnt, statsV2,
                                                   vn_g + (size_t)(2 * p + 1) * Hc,
                                                   vn_be + (size_t)(2 * p + 1) * Hc, invG);
    // T = h2 + agg(h2), h2 = relu(bn(P)) + vn[batch]
    k_agg<<<aggBlk, 256, 0, stream>>>(P, T, rowptr, erec, bemb, vn, batch, scbN, bbbN);
    // P = T @ W + bias + P (stats fused for next BN; statsN was zeroed by k_bnprep)
    k_gemm_mfma<<<ggN, 256, 0, stream>>>(T, WhiC + (size_t)l * 65536, WloC + (size_t)l * 65536,
                                         conv_b + (size_t)l * Hc, P, P, statsN, Ncnt);
  }

  // Final BN + global add pool
  k_bnprep<<<1, 256, 0, stream>>>(statsN, ngamma + (size_t)(Lcnt - 1) * Hc,
                                  nbeta + (size_t)(Lcnt - 1) * Hc, scbN, bbbN, invN);
  k_zero<<<(int)((GH + 255) / 256), 256, 0, stream>>>(out, (int)GH);
  k_bn_pool<<<segBlk, 256, 0, stream>>>(P, batch, out, scbN, bbbN);
}